// Round 3
// baseline (902.384 us; speedup 1.0000x reference)
//
#include <hip/hip_runtime.h>
#include <hip/hip_bf16.h>
#include <math.h>

typedef unsigned short u16;
typedef __attribute__((ext_vector_type(8))) short short8;
typedef __attribute__((ext_vector_type(4))) float f32x4;

#define DEVINL static __device__ __forceinline__

DEVINL float b2f(u16 x) {
    union { unsigned u; float f; } v; v.u = ((unsigned)x) << 16; return v.f;
}
DEVINL u16 f2b(float f) {
    union { unsigned u; float f; } v; v.f = f;
    unsigned u = v.u;
    return (u16)((u + 0x7fffu + ((u >> 16) & 1u)) >> 16);
}
DEVINL float silu(float x) { return x / (1.f + __expf(-x)); }

// dual-mode scalar load: input tensors may be f32 or bf16 (runtime-detected)
template<bool F32> DEVINL float LDs(const void* p, size_t i) {
    if constexpr (F32) return ((const float*)p)[i];
    else               return b2f(((const u16*)p)[i]);
}
// dual-mode 8-element fragment load (for MFMA B operands from input weights)
template<bool F32> DEVINL short8 LD8(const void* p, size_t i) {
    if constexpr (F32) {
        const float* f = (const float*)p + i;
        short8 r;
#pragma unroll
        for (int j = 0; j < 8; ++j) r[j] = (short)f2b(f[j]);
        return r;
    } else {
        return *reinterpret_cast<const short8*>((const u16*)p + i);
    }
}

// ---------------------------------------------------------------------------
// dtype detection: count |bf16-view| > 1e3 (or NaN/inf) over first 2M u16 of
// resnet_feat. bf16 N(0,1) data -> 0. f32 data -> low-half u16s trigger ~46%.
// ---------------------------------------------------------------------------
__global__ __launch_bounds__(256) void k_detect1(const u16* __restrict__ raw,
                                                 int* __restrict__ partial)
{
    int tid = threadIdx.x, bid = blockIdx.x;
    int cnt = 0;
    for (size_t i = (size_t)bid * 256 + tid; i < 2097152; i += 64 * 256) {
        float v = b2f(raw[i]);
        if (!(fabsf(v) <= 1e3f)) cnt++;
    }
#pragma unroll
    for (int off = 1; off < 64; off <<= 1) cnt += __shfl_xor(cnt, off);
    __shared__ int s4[4];
    if ((tid & 63) == 0) s4[tid >> 6] = cnt;
    __syncthreads();
    if (tid == 0) partial[bid] = s4[0] + s4[1] + s4[2] + s4[3];
}

__global__ __launch_bounds__(64) void k_detect2(const int* __restrict__ partial,
                                                int* __restrict__ flag)
{
    int c = partial[threadIdx.x];
#pragma unroll
    for (int off = 1; off < 64; off <<= 1) c += __shfl_xor(c, off);
    if (threadIdx.x == 0) flag[0] = (c > 0) ? 1 : 0;
}

// ---------------------------------------------------------------------------
// K0: scp 1x1 conv + BN -> sp16 [b][p=h*32+w][o] bf16
// grid (32 o-tiles, 4 p-tiles, B), block 256 (thread = position)
// ---------------------------------------------------------------------------
template<bool F32> DEVINL void scp_body(
    const void* scp, const void* W, const void* g, const void* bb,
    const void* m, const void* v, u16* sp16)
{
    int tid = threadIdx.x;
    int ot  = blockIdx.x;
    int p   = blockIdx.y * 256 + tid;
    int b   = blockIdx.z;
    float acc[8];
#pragma unroll
    for (int j = 0; j < 8; ++j) acc[j] = 0.f;
    size_t fbase = (size_t)b * 512 * 1024 + p;
    size_t wbase = (size_t)ot * 8 * 512;
#pragma unroll 4
    for (int c = 0; c < 512; ++c) {
        float f = LDs<F32>(scp, fbase + (size_t)c * 1024);
#pragma unroll
        for (int j = 0; j < 8; ++j) acc[j] += f * LDs<F32>(W, wbase + j * 512 + c);
    }
#pragma unroll
    for (int j = 0; j < 8; ++j) {
        int o = ot * 8 + j;
        float inv = LDs<F32>(g, o) * rsqrtf(LDs<F32>(v, o) + 1e-5f);
        float sh  = LDs<F32>(bb, o) - LDs<F32>(m, o) * inv;
        sp16[((size_t)b * 1024 + p) * 256 + o] = f2b(acc[j] * inv + sh);
    }
}
__global__ __launch_bounds__(256) void k_scp(const int* flag,
    const void* scp, const void* W, const void* g, const void* bb,
    const void* m, const void* v, u16* sp16)
{
    if (*flag) scp_body<true>(scp, W, g, bb, m, v, sp16);
    else       scp_body<false>(scp, W, g, bb, m, v, sp16);
}

// ---------------------------------------------------------------------------
// K1: res-BN + bilinear upsample + add (in regs) -> LayerNorm -> xn bf16
// grid (L=4096, B), block 256 (thread = channel). fused NOT stored.
// ---------------------------------------------------------------------------
template<bool F32> DEVINL void ln_body(
    const void* resnet, const void* rg, const void* rb, const void* rm,
    const void* rv, const void* lg, const void* lb,
    const u16* sp16, u16* xn)
{
    int c = threadIdx.x, l = blockIdx.x, b = blockIdx.y;
    int h = l >> 6, w = l & 63;
    float rr  = LDs<F32>(resnet, ((size_t)b * 256 + c) * 4096 + l);
    float inv = LDs<F32>(rg, c) * rsqrtf(LDs<F32>(rv, c) + 1e-5f);
    float rn  = rr * inv + (LDs<F32>(rb, c) - LDs<F32>(rm, c) * inv);

    float xh = 0.5f * h - 0.25f; int jh = (int)floorf(xh); float fh = xh - jh;
    float xw = 0.5f * w - 0.25f; int jw = (int)floorf(xw); float fw = xw - jw;
    int h0 = jh < 0 ? 0 : jh, h1 = jh + 1 > 31 ? 31 : jh + 1;
    int w0 = jw < 0 ? 0 : jw, w1 = jw + 1 > 31 ? 31 : jw + 1;
    const u16* spb = sp16 + (size_t)b * 1024 * 256 + c;
    float v00 = b2f(spb[(size_t)(h0 * 32 + w0) * 256]), v01 = b2f(spb[(size_t)(h0 * 32 + w1) * 256]);
    float v10 = b2f(spb[(size_t)(h1 * 32 + w0) * 256]), v11 = b2f(spb[(size_t)(h1 * 32 + w1) * 256]);
    float sp = (1.f - fh) * ((1.f - fw) * v00 + fw * v01)
             + fh * ((1.f - fw) * v10 + fw * v11);
    float fv = rn + sp;

    __shared__ float red[8];
    float s = fv, s2 = fv * fv;
#pragma unroll
    for (int off = 1; off < 64; off <<= 1) {
        s  += __shfl_xor(s, off);
        s2 += __shfl_xor(s2, off);
    }
    int wv = c >> 6;
    if ((c & 63) == 0) { red[wv] = s; red[4 + wv] = s2; }
    __syncthreads();
    float S  = red[0] + red[1] + red[2] + red[3];
    float S2 = red[4] + red[5] + red[6] + red[7];
    float mu   = S * (1.f / 256.f);
    float var  = S2 * (1.f / 256.f) - mu * mu;
    float rstd = rsqrtf(var + 1e-5f);
    float xnv  = (fv - mu) * rstd * LDs<F32>(lg, c) + LDs<F32>(lb, c);
    xn[((size_t)b * 4096 + l) * 256 + c] = f2b(xnv);
}
__global__ __launch_bounds__(256) void k_ln(const int* flag,
    const void* resnet, const void* rg, const void* rb, const void* rm,
    const void* rv, const void* lg, const void* lb,
    const u16* sp16, u16* xn)
{
    if (*flag) ln_body<true>(resnet, rg, rb, rm, rv, lg, lb, sp16, xn);
    else       ln_body<false>(resnet, rg, rb, rm, rv, lg, lb, sp16, xn);
}

// ---------------------------------------------------------------------------
// in_proj GEMM (xm half): xm[row][n] = sum_k xn[row][k]*W[woff + n*K + k]
// M=8192, N=512, K=256. grid (128, 8), block 256.
// ---------------------------------------------------------------------------
template<bool F32> DEVINL void gemm_in_body(
    const u16* A, const void* W, size_t woff, u16* Out)
{
    const int N = 512, K = 256;
    int tid = threadIdx.x, lane = tid & 63, wid = tid >> 6;
    int ln = lane & 15, q = lane >> 4;
    int m0 = blockIdx.x * 64 + (wid & 1) * 32;
    int n0 = blockIdx.y * 64 + (wid >> 1) * 32;
    f32x4 acc00 = {0.f,0.f,0.f,0.f}, acc01 = acc00, acc10 = acc00, acc11 = acc00;
    const u16* Ap0 = A + (size_t)(m0 + ln) * K + q * 8;
    const u16* Ap1 = Ap0 + (size_t)16 * K;
#pragma unroll 4
    for (int k0 = 0; k0 < K; k0 += 32) {
        int kk = k0 + q * 8;
        short8 a0 = *reinterpret_cast<const short8*>(Ap0 + k0);
        short8 a1 = *reinterpret_cast<const short8*>(Ap1 + k0);
        short8 b0 = LD8<F32>(W, woff + (size_t)(n0 + ln) * K + kk);
        short8 b1 = LD8<F32>(W, woff + (size_t)(n0 + ln + 16) * K + kk);
        acc00 = __builtin_amdgcn_mfma_f32_16x16x32_bf16(a0, b0, acc00, 0, 0, 0);
        acc01 = __builtin_amdgcn_mfma_f32_16x16x32_bf16(a0, b1, acc01, 0, 0, 0);
        acc10 = __builtin_amdgcn_mfma_f32_16x16x32_bf16(a1, b0, acc10, 0, 0, 0);
        acc11 = __builtin_amdgcn_mfma_f32_16x16x32_bf16(a1, b1, acc11, 0, 0, 0);
    }
    int r0 = m0 + q * 4, c0 = n0 + ln;
#pragma unroll
    for (int r = 0; r < 4; ++r) {
        Out[(size_t)(r0 + r) * N + c0]           = f2b(acc00[r]);
        Out[(size_t)(r0 + r) * N + c0 + 16]      = f2b(acc01[r]);
        Out[(size_t)(r0 + 16 + r) * N + c0]      = f2b(acc10[r]);
        Out[(size_t)(r0 + 16 + r) * N + c0 + 16] = f2b(acc11[r]);
    }
}
__global__ __launch_bounds__(256) void k_gemm_in(const int* flag,
    const u16* A, const void* W, u16* Out)
{
    if (*flag) gemm_in_body<true>(A, W, 0, Out);
    else       gemm_in_body<false>(A, W, 0, Out);
}

// ---------------------------------------------------------------------------
// z-GEMM + gating (runs AFTER scan3): z = xn @ inw[512:].T ; y *= silu(z)
// in place over yraw. Same tiling as k_gemm_in.
// ---------------------------------------------------------------------------
template<bool F32> DEVINL void gate_body(
    const u16* A, const void* W, u16* Y)
{
    const int K = 256;
    int tid = threadIdx.x, lane = tid & 63, wid = tid >> 6;
    int ln = lane & 15, q = lane >> 4;
    int m0 = blockIdx.x * 64 + (wid & 1) * 32;
    int n0 = blockIdx.y * 64 + (wid >> 1) * 32;
    f32x4 acc00 = {0.f,0.f,0.f,0.f}, acc01 = acc00, acc10 = acc00, acc11 = acc00;
    const size_t woff = 512 * 256;   // second half of in_proj_w (element offset)
    const u16* Ap0 = A + (size_t)(m0 + ln) * K + q * 8;
    const u16* Ap1 = Ap0 + (size_t)16 * K;
#pragma unroll 4
    for (int k0 = 0; k0 < K; k0 += 32) {
        int kk = k0 + q * 8;
        short8 a0 = *reinterpret_cast<const short8*>(Ap0 + k0);
        short8 a1 = *reinterpret_cast<const short8*>(Ap1 + k0);
        short8 b0 = LD8<F32>(W, woff + (size_t)(n0 + ln) * K + kk);
        short8 b1 = LD8<F32>(W, woff + (size_t)(n0 + ln + 16) * K + kk);
        acc00 = __builtin_amdgcn_mfma_f32_16x16x32_bf16(a0, b0, acc00, 0, 0, 0);
        acc01 = __builtin_amdgcn_mfma_f32_16x16x32_bf16(a0, b1, acc01, 0, 0, 0);
        acc10 = __builtin_amdgcn_mfma_f32_16x16x32_bf16(a1, b0, acc10, 0, 0, 0);
        acc11 = __builtin_amdgcn_mfma_f32_16x16x32_bf16(a1, b1, acc11, 0, 0, 0);
    }
    int r0 = m0 + q * 4, c0 = n0 + ln;
#pragma unroll
    for (int r = 0; r < 4; ++r) {
        {
            size_t i = (size_t)(r0 + r) * 512 + c0;
            float zv = acc00[r]; Y[i] = f2b(b2f(Y[i]) * silu(zv));
        }
        {
            size_t i = (size_t)(r0 + r) * 512 + c0 + 16;
            float zv = acc01[r]; Y[i] = f2b(b2f(Y[i]) * silu(zv));
        }
        {
            size_t i = (size_t)(r0 + 16 + r) * 512 + c0;
            float zv = acc10[r]; Y[i] = f2b(b2f(Y[i]) * silu(zv));
        }
        {
            size_t i = (size_t)(r0 + 16 + r) * 512 + c0 + 16;
            float zv = acc11[r]; Y[i] = f2b(b2f(Y[i]) * silu(zv));
        }
    }
}
__global__ __launch_bounds__(256) void k_gate(const int* flag,
    const u16* A, const void* W, u16* Y)
{
    if (*flag) gate_body<true>(A, W, Y);
    else       gate_body<false>(A, W, Y);
}

// ---------------------------------------------------------------------------
// on-the-fly u fragment: u[row][kk0..kk0+8) = silu(causal conv3 of xm)
// ---------------------------------------------------------------------------
template<bool F32> DEVINL short8 u_frag(
    const u16* xm, int row, int kk0, const void* cw, const void* cb)
{
    int l = row & 4095;
    const u16* p = xm + (size_t)row * 512 + kk0;
    short8 zz = {0,0,0,0,0,0,0,0};
    short8 x0 = *reinterpret_cast<const short8*>(p);
    short8 x1 = (l >= 1) ? *reinterpret_cast<const short8*>(p - 512)  : zz;
    short8 x2 = (l >= 2) ? *reinterpret_cast<const short8*>(p - 1024) : zz;
    short8 r;
#pragma unroll
    for (int j = 0; j < 8; ++j) {
        int d = kk0 + j;
        float acc = LDs<F32>(cb, d)
                  + b2f((u16)x2[j]) * LDs<F32>(cw, d * 3)
                  + b2f((u16)x1[j]) * LDs<F32>(cw, d * 3 + 1)
                  + b2f((u16)x0[j]) * LDs<F32>(cw, d * 3 + 2);
        r[j] = (short)f2b(silu(acc));
    }
    return r;
}

// ---------------------------------------------------------------------------
// x_proj GEMM with conv-on-the-fly A: xd16[row][n] (bf16), N=48, K=512.
// grid (64), block 256 (4 waves stacked in m; 128 rows/block).
// ---------------------------------------------------------------------------
template<bool F32> DEVINL void xproj_body(
    const u16* xm, const void* xpw, const void* cw, const void* cb, u16* xd16)
{
    int tid = threadIdx.x, lane = tid & 63, wid = tid >> 6;
    int ln = lane & 15, q = lane >> 4;
    int m0 = blockIdx.x * 128 + wid * 32;
    f32x4 acc[2][3];
#pragma unroll
    for (int i = 0; i < 2; ++i)
#pragma unroll
        for (int j = 0; j < 3; ++j) acc[i][j] = {0.f,0.f,0.f,0.f};
    for (int k0 = 0; k0 < 512; k0 += 32) {
        int kk0 = k0 + q * 8;
        short8 a0 = u_frag<F32>(xm, m0 + ln,      kk0, cw, cb);
        short8 a1 = u_frag<F32>(xm, m0 + ln + 16, kk0, cw, cb);
#pragma unroll
        for (int j = 0; j < 3; ++j) {
            short8 bj = LD8<F32>(xpw, (size_t)(16 * j + ln) * 512 + kk0);
            acc[0][j] = __builtin_amdgcn_mfma_f32_16x16x32_bf16(a0, bj, acc[0][j], 0, 0, 0);
            acc[1][j] = __builtin_amdgcn_mfma_f32_16x16x32_bf16(a1, bj, acc[1][j], 0, 0, 0);
        }
    }
#pragma unroll
    for (int i = 0; i < 2; ++i)
#pragma unroll
        for (int j = 0; j < 3; ++j)
#pragma unroll
            for (int r = 0; r < 4; ++r)
                xd16[(size_t)(m0 + 16 * i + q * 4 + r) * 48 + 16 * j + ln] = f2b(acc[i][j][r]);
}
__global__ __launch_bounds__(256) void k_xproj(const int* flag,
    const u16* xm, const void* xpw, const void* cw, const void* cb, u16* xd16)
{
    if (*flag) xproj_body<true>(xm, xpw, cw, cb, xd16);
    else       xproj_body<false>(xm, xpw, cw, cb, xd16);
}

// ---------------------------------------------------------------------------
// halo copy: rows l0-2, l0-1 of each chunk (needed because scan3 overwrites
// xm in place). halo[b][ck][t][d], zeros for ck==0. grid (16,2), block 512.
// ---------------------------------------------------------------------------
__global__ __launch_bounds__(512) void k_halo(const u16* __restrict__ xm,
                                              u16* __restrict__ halo)
{
    int d = threadIdx.x, ck = blockIdx.x, b = blockIdx.y;
#pragma unroll
    for (int t = 0; t < 2; ++t) {
        int l = ck * 256 - 2 + t;
        u16 val = (l >= 0) ? xm[((size_t)b * 4096 + l) * 512 + d] : (u16)0;
        halo[(((size_t)b * 16 + ck) * 2 + t) * 512 + d] = val;
    }
}

// dt = softplus(dot(xd[0:16], wdt) + bias)
DEVINL float dt_of(const u16* xd, const float* wdt, float bias) {
    float acc = bias;
#pragma unroll
    for (int r = 0; r < 16; ++r) acc += b2f(xd[r]) * wdt[r];
    return acc > 15.f ? acc : log1pf(__expf(acc));
}

// ---------------------------------------------------------------------------
// scan1: per-chunk local scan (conv-on-the-fly u). CL=256, NC=16.
// grid (16, 2), block 512 (thread = d). -> cA, cH bf16 [b][ck][s][512]
// ---------------------------------------------------------------------------
template<bool F32> DEVINL void scan1_body(
    const u16* xm, const u16* halo, const u16* xd16,
    const void* alog, const void* dtw, const void* dtb,
    const void* cw, const void* cb, u16* cA, u16* cH)
{
    int d = threadIdx.x, ck = blockIdx.x, b = blockIdx.y;
    float wdt[16], a[16], h[16], ap[16];
#pragma unroll
    for (int s = 0; s < 16; ++s) {
        wdt[s] = LDs<F32>(dtw, d * 16 + s);
        a[s] = -__expf(LDs<F32>(alog, d * 16 + s));
        h[s] = 0.f; ap[s] = 1.f;
    }
    float bias = LDs<F32>(dtb, d);
    float cw0 = LDs<F32>(cw, d * 3), cw1 = LDs<F32>(cw, d * 3 + 1),
          cw2 = LDs<F32>(cw, d * 3 + 2), cbv = LDs<F32>(cb, d);
    size_t hb = (((size_t)b * 16 + ck) * 2) * 512 + d;
    float x2 = b2f(halo[hb]), x1 = b2f(halo[hb + 512]);
    int l0 = ck * 256;
    for (int il = 0; il < 256; ++il) {
        size_t row = (size_t)b * 4096 + l0 + il;
        float x0 = b2f(xm[row * 512 + d]);
        float uc = cbv + cw0 * x2 + cw1 * x1 + cw2 * x0;
        float uv = silu(uc);
        const u16* xd = xd16 + row * 48;
        float dtv = dt_of(xd, wdt, bias);
        float du = dtv * uv;
#pragma unroll
        for (int s = 0; s < 16; ++s) {
            float dA = __expf(dtv * a[s]);
            h[s]  = dA * h[s] + du * b2f(xd[16 + s]);
            ap[s] *= dA;
        }
        x2 = x1; x1 = x0;
    }
    size_t base = (((size_t)b * 16 + ck) * 16) * 512 + d;
#pragma unroll
    for (int s = 0; s < 16; ++s) {
        cA[base + (size_t)s * 512] = f2b(ap[s]);
        cH[base + (size_t)s * 512] = f2b(h[s]);
    }
}
__global__ __launch_bounds__(512) void k_scan1(const int* flag,
    const u16* xm, const u16* halo, const u16* xd16,
    const void* alog, const void* dtw, const void* dtb,
    const void* cw, const void* cb, u16* cA, u16* cH)
{
    if (*flag) scan1_body<true>(xm, halo, xd16, alog, dtw, dtb, cw, cb, cA, cH);
    else       scan1_body<false>(xm, halo, xd16, alog, dtw, dtb, cw, cb, cA, cH);
}

// ---------------------------------------------------------------------------
// scan2: cross-chunk recurrence; cH[ck] := h_in(ck). grid (16=s, 2), block 512
// ---------------------------------------------------------------------------
__global__ __launch_bounds__(512) void k_scan2(const u16* __restrict__ cA,
                                               u16* __restrict__ cH)
{
    int d = threadIdx.x, s = blockIdx.x, b = blockIdx.y;
    float h = 0.f;
    for (int ck = 0; ck < 16; ++ck) {
        size_t idx = (((size_t)b * 16 + ck) * 16 + s) * 512 + d;
        float aP = b2f(cA[idx]), hE = b2f(cH[idx]);
        cH[idx] = f2b(h);
        h = aP * h + hE;
    }
}

// ---------------------------------------------------------------------------
// scan3: replay chunk from h_in; yraw = h.C + u*D written IN PLACE over xm.
// grid (16, 2), block 512.
// ---------------------------------------------------------------------------
template<bool F32> DEVINL void scan3_body(
    u16* xm, const u16* halo, const u16* xd16,
    const void* alog, const void* dtw, const void* dtb,
    const void* cw, const void* cb, const void* Dw, const u16* cH)
{
    int d = threadIdx.x, ck = blockIdx.x, b = blockIdx.y;
    float wdt[16], a[16], h[16];
    size_t base = (((size_t)b * 16 + ck) * 16) * 512 + d;
#pragma unroll
    for (int s = 0; s < 16; ++s) {
        wdt[s] = LDs<F32>(dtw, d * 16 + s);
        a[s] = -__expf(LDs<F32>(alog, d * 16 + s));
        h[s] = b2f(cH[base + (size_t)s * 512]);
    }
    float bias = LDs<F32>(dtb, d);
    float Dv = LDs<F32>(Dw, d);
    float cw0 = LDs<F32>(cw, d * 3), cw1 = LDs<F32>(cw, d * 3 + 1),
          cw2 = LDs<F32>(cw, d * 3 + 2), cbv = LDs<F32>(cb, d);
    size_t hb = (((size_t)b * 16 + ck) * 2) * 512 + d;
    float x2 = b2f(halo[hb]), x1 = b2f(halo[hb + 512]);
    int l0 = ck * 256;
    for (int il = 0; il < 256; ++il) {
        size_t row = (size_t)b * 4096 + l0 + il;
        float x0 = b2f(xm[row * 512 + d]);
        float uc = cbv + cw0 * x2 + cw1 * x1 + cw2 * x0;
        float uv = silu(uc);
        const u16* xd = xd16 + row * 48;
        float dtv = dt_of(xd, wdt, bias);
        float du = dtv * uv;
        float yv = 0.f;
#pragma unroll
        for (int s = 0; s < 16; ++s) {
            float dA = __expf(dtv * a[s]);
            h[s] = dA * h[s] + du * b2f(xd[16 + s]);
            yv += h[s] * b2f(xd[32 + s]);
        }
        yv += uv * Dv;
        xm[row * 512 + d] = f2b(yv);   // in-place yraw (x0 already consumed)
        x2 = x1; x1 = x0;
    }
}
__global__ __launch_bounds__(512) void k_scan3(const int* flag,
    u16* xm, const u16* halo, const u16* xd16,
    const void* alog, const void* dtw, const void* dtb,
    const void* cw, const void* cb, const void* Dw, const u16* cH)
{
    if (*flag) scan3_body<true>(xm, halo, xd16, alog, dtw, dtb, cw, cb, Dw, cH);
    else       scan3_body<false>(xm, halo, xd16, alog, dtw, dtb, cw, cb, Dw, cH);
}

// ---------------------------------------------------------------------------
// out_proj GEMM + fused-recompute epilogue + transposed dual store.
// A = y (8192x512 bf16), W = opw (256x512), out[b][c][h][w].
// grid (128, 4), block 256.
// ---------------------------------------------------------------------------
template<bool F32> DEVINL void out_body(
    const u16* Y, const void* opw,
    const void* resnet, const void* rg, const void* rb, const void* rm,
    const void* rv, const u16* sp16, void* outp)
{
    const int K = 512;
    int tid = threadIdx.x, lane = tid & 63, wid = tid >> 6;
    int ln = lane & 15, q = lane >> 4;
    int m0 = blockIdx.x * 64 + (wid & 1) * 32;
    int n0 = blockIdx.y * 64 + (wid >> 1) * 32;
    f32x4 acc[2][2];
    acc[0][0] = {0.f,0.f,0.f,0.f}; acc[0][1] = acc[0][0];
    acc[1][0] = acc[0][0]; acc[1][1] = acc[0][0];
    const u16* Ap0 = Y + (size_t)(m0 + ln) * K + q * 8;
    const u16* Ap1 = Ap0 + (size_t)16 * K;
#pragma unroll 4
    for (int k0 = 0; k0 < K; k0 += 32) {
        int kk = k0 + q * 8;
        short8 a0 = *reinterpret_cast<const short8*>(Ap0 + k0);
        short8 a1 = *reinterpret_cast<const short8*>(Ap1 + k0);
        short8 b0 = LD8<F32>(opw, (size_t)(n0 + ln) * K + kk);
        short8 b1 = LD8<F32>(opw, (size_t)(n0 + ln + 16) * K + kk);
        acc[0][0] = __builtin_amdgcn_mfma_f32_16x16x32_bf16(a0, b0, acc[0][0], 0, 0, 0);
        acc[0][1] = __builtin_amdgcn_mfma_f32_16x16x32_bf16(a0, b1, acc[0][1], 0, 0, 0);
        acc[1][0] = __builtin_amdgcn_mfma_f32_16x16x32_bf16(a1, b0, acc[1][0], 0, 0, 0);
        acc[1][1] = __builtin_amdgcn_mfma_f32_16x16x32_bf16(a1, b1, acc[1][1], 0, 0, 0);
    }
    int r0 = m0 + q * 4, c0 = n0 + ln;
#pragma unroll
    for (int cg = 0; cg < 2; ++cg) {
        int c = c0 + 16 * cg;
        float inv = LDs<F32>(rg, c) * rsqrtf(LDs<F32>(rv, c) + 1e-5f);
        float sh  = LDs<F32>(rb, c) - LDs<F32>(rm, c) * inv;
#pragma unroll
        for (int rg2 = 0; rg2 < 2; ++rg2) {
#pragma unroll
            for (int r = 0; r < 4; ++r) {
                int row = r0 + 16 * rg2 + r;
                int b = row >> 12, l = row & 4095;
                float accv = acc[rg2][cg][r];
                float rr = LDs<F32>(resnet, ((size_t)b * 256 + c) * 4096 + l);
                float rn = rr * inv + sh;
                int hh = l >> 6, w = l & 63;
                float xh = 0.5f * hh - 0.25f; int jh = (int)floorf(xh); float fh = xh - jh;
                float xw = 0.5f * w - 0.25f;  int jw = (int)floorf(xw); float fw = xw - jw;
                int h0 = jh < 0 ? 0 : jh, h1 = jh + 1 > 31 ? 31 : jh + 1;
                int w0 = jw < 0 ? 0 : jw, w1 = jw + 1 > 31 ? 31 : jw + 1;
                const u16* spb = sp16 + (size_t)b * 1024 * 256 + c;
                float v00 = b2f(spb[(size_t)(h0 * 32 + w0) * 256]);
                float v01 = b2f(spb[(size_t)(h0 * 32 + w1) * 256]);
                float v10 = b2f(spb[(size_t)(h1 * 32 + w0) * 256]);
                float v11 = b2f(spb[(size_t)(h1 * 32 + w1) * 256]);
                float sp = (1.f - fh) * ((1.f - fw) * v00 + fw * v01)
                         + fh * ((1.f - fw) * v10 + fw * v11);
                float val = accv + rn + sp;
                size_t oi = ((size_t)b * 256 + c) * 4096 + l;
                if constexpr (F32) ((float*)outp)[oi] = val;
                else               ((u16*)outp)[oi]  = f2b(val);
            }
        }
    }
}
__global__ __launch_bounds__(256) void k_out(const int* flag,
    const u16* Y, const void* opw,
    const void* resnet, const void* rg, const void* rb, const void* rm,
    const void* rv, const u16* sp16, void* outp)
{
    if (*flag) out_body<true>(Y, opw, resnet, rg, rb, rm, rv, sp16, outp);
    else       out_body<false>(Y, opw, resnet, rg, rb, rm, rv, sp16, outp);
}

// ---------------------------------------------------------------------------
extern "C" void kernel_launch(void* const* d_in, const int* in_sizes, int n_in,
                              void* d_out, int out_size, void* d_ws, size_t ws_size,
                              hipStream_t stream)
{
    const void* resnet = d_in[0];
    const void* scp    = d_in[1];
    const void* spw    = d_in[2];
    const void* sg     = d_in[3];
    const void* sb     = d_in[4];
    const void* sm     = d_in[5];
    const void* sv     = d_in[6];
    const void* rg     = d_in[7];
    const void* rb     = d_in[8];
    const void* rm     = d_in[9];
    const void* rv     = d_in[10];
    const void* lg     = d_in[11];
    const void* lb     = d_in[12];
    const void* inw    = d_in[13];
    const void* cw     = d_in[14];
    const void* cb     = d_in[15];
    const void* xpw    = d_in[16];
    const void* dtw    = d_in[17];
    const void* dtb    = d_in[18];
    const void* alog   = d_in[19];
    const void* Dw     = d_in[20];
    const void* opw    = d_in[21];

    // Workspace layout — 15,536,128 B total (~14.82 MiB)
    char* ws = (char*)d_ws;
    int*  flag    = (int*)(ws);                       // [0,4)
    int*  partial = (int*)(ws + 128);                 // 64 ints
    u16*  sp16    = (u16*)(ws + 4096);                //  1.00 MiB
    u16*  xn      = (u16*)(ws + 1052672);             //  4.00 MiB
    u16*  xm      = (u16*)(ws + 5246976);             //  8.00 MiB (becomes yraw/y)
    u16*  xd16    = (u16*)(ws + 13635584);            //  0.75 MiB
    u16*  cA      = (u16*)(ws + 14422016);            //  0.50 MiB
    u16*  cH      = (u16*)(ws + 14946304);            //  0.50 MiB
    u16*  halo    = (u16*)(ws + 15470592);            //  64 KiB

    k_detect1<<<dim3(64), 256, 0, stream>>>((const u16*)resnet, partial);
    k_detect2<<<dim3(1), 64, 0, stream>>>(partial, flag);
    k_scp<<<dim3(32, 4, 2), 256, 0, stream>>>(flag, scp, spw, sg, sb, sm, sv, sp16);
    k_ln<<<dim3(4096, 2), 256, 0, stream>>>(flag, resnet, rg, rb, rm, rv, lg, lb, sp16, xn);
    k_gemm_in<<<dim3(128, 8), 256, 0, stream>>>(flag, xn, inw, xm);
    k_halo<<<dim3(16, 2), 512, 0, stream>>>(xm, halo);
    k_xproj<<<dim3(64), 256, 0, stream>>>(flag, xm, xpw, cw, cb, xd16);
    k_scan1<<<dim3(16, 2), 512, 0, stream>>>(flag, xm, halo, xd16, alog, dtw, dtb, cw, cb, cA, cH);
    k_scan2<<<dim3(16, 2), 512, 0, stream>>>(cA, cH);
    k_scan3<<<dim3(16, 2), 512, 0, stream>>>(flag, xm, halo, xd16, alog, dtw, dtb, cw, cb, Dw, cH);
    k_gate<<<dim3(128, 8), 256, 0, stream>>>(flag, xn, inw, xm);
    k_out<<<dim3(128, 4), 256, 0, stream>>>(flag, xm, opw, resnet, rg, rb, rm, rv, sp16, d_out);
}

// Round 4
// 395.458 us; speedup vs baseline: 2.2819x; 2.2819x over previous
//
#include <hip/hip_runtime.h>
#include <hip/hip_bf16.h>
#include <math.h>

typedef unsigned short u16;
typedef __attribute__((ext_vector_type(8))) short short8;
typedef __attribute__((ext_vector_type(4))) float f32x4;

#define DEVINL static __device__ __forceinline__

DEVINL float b2f(u16 x) {
    union { unsigned u; float f; } v; v.u = ((unsigned)x) << 16; return v.f;
}
DEVINL u16 f2b(float f) {
    union { unsigned u; float f; } v; v.f = f;
    unsigned u = v.u;
    return (u16)((u + 0x7fffu + ((u >> 16) & 1u)) >> 16);
}
DEVINL float silu(float x) { return x / (1.f + __expf(-x)); }

// dual-mode scalar load: input tensors may be f32 or bf16 (runtime-detected)
template<bool F32> DEVINL float LDs(const void* p, size_t i) {
    if constexpr (F32) return ((const float*)p)[i];
    else               return b2f(((const u16*)p)[i]);
}
// dual-mode 8-element fragment load (for MFMA B operands from input weights)
template<bool F32> DEVINL short8 LD8(const void* p, size_t i) {
    if constexpr (F32) {
        const float* f = (const float*)p + i;
        short8 r;
#pragma unroll
        for (int j = 0; j < 8; ++j) r[j] = (short)f2b(f[j]);
        return r;
    } else {
        return *reinterpret_cast<const short8*>((const u16*)p + i);
    }
}

// ---------------------------------------------------------------------------
// dtype detection: count |bf16-view| > 1e3 (or NaN/inf) over first 2M u16 of
// resnet_feat. bf16 N(0,1) data -> 0. f32 data -> low-half u16s trigger ~46%.
// ---------------------------------------------------------------------------
__global__ __launch_bounds__(256) void k_detect1(const u16* __restrict__ raw,
                                                 int* __restrict__ partial)
{
    int tid = threadIdx.x, bid = blockIdx.x;
    int cnt = 0;
    for (size_t i = (size_t)bid * 256 + tid; i < 2097152; i += 64 * 256) {
        float v = b2f(raw[i]);
        if (!(fabsf(v) <= 1e3f)) cnt++;
    }
#pragma unroll
    for (int off = 1; off < 64; off <<= 1) cnt += __shfl_xor(cnt, off);
    __shared__ int s4[4];
    if ((tid & 63) == 0) s4[tid >> 6] = cnt;
    __syncthreads();
    if (tid == 0) partial[bid] = s4[0] + s4[1] + s4[2] + s4[3];
}

__global__ __launch_bounds__(64) void k_detect2(const int* __restrict__ partial,
                                                int* __restrict__ flag)
{
    int c = partial[threadIdx.x];
#pragma unroll
    for (int off = 1; off < 64; off <<= 1) c += __shfl_xor(c, off);
    if (threadIdx.x == 0) flag[0] = (c > 0) ? 1 : 0;
}

// ---------------------------------------------------------------------------
// K0: scp 1x1 conv + BN -> sp16 [b][p=h*32+w][o] bf16
// grid (32 o-tiles, 4 p-tiles, B), block 256 (thread = position)
// ---------------------------------------------------------------------------
template<bool F32> DEVINL void scp_body(
    const void* scp, const void* W, const void* g, const void* bb,
    const void* m, const void* v, u16* sp16)
{
    int tid = threadIdx.x;
    int ot  = blockIdx.x;
    int p   = blockIdx.y * 256 + tid;
    int b   = blockIdx.z;
    float acc[8];
#pragma unroll
    for (int j = 0; j < 8; ++j) acc[j] = 0.f;
    size_t fbase = (size_t)b * 512 * 1024 + p;
    size_t wbase = (size_t)ot * 8 * 512;
#pragma unroll 4
    for (int c = 0; c < 512; ++c) {
        float f = LDs<F32>(scp, fbase + (size_t)c * 1024);
#pragma unroll
        for (int j = 0; j < 8; ++j) acc[j] += f * LDs<F32>(W, wbase + j * 512 + c);
    }
#pragma unroll
    for (int j = 0; j < 8; ++j) {
        int o = ot * 8 + j;
        float inv = LDs<F32>(g, o) * rsqrtf(LDs<F32>(v, o) + 1e-5f);
        float sh  = LDs<F32>(bb, o) - LDs<F32>(m, o) * inv;
        sp16[((size_t)b * 1024 + p) * 256 + o] = f2b(acc[j] * inv + sh);
    }
}
__global__ __launch_bounds__(256) void k_scp(const int* flag,
    const void* scp, const void* W, const void* g, const void* bb,
    const void* m, const void* v, u16* sp16)
{
    if (*flag) scp_body<true>(scp, W, g, bb, m, v, sp16);
    else       scp_body<false>(scp, W, g, bb, m, v, sp16);
}

// ---------------------------------------------------------------------------
// K1: res-BN + bilinear upsample + add (in regs) -> LayerNorm -> xn bf16
// grid (L=4096, B), block 256 (thread = channel). fused NOT stored.
// ---------------------------------------------------------------------------
template<bool F32> DEVINL void ln_body(
    const void* resnet, const void* rg, const void* rb, const void* rm,
    const void* rv, const void* lg, const void* lb,
    const u16* sp16, u16* xn)
{
    int c = threadIdx.x, l = blockIdx.x, b = blockIdx.y;
    int h = l >> 6, w = l & 63;
    float rr  = LDs<F32>(resnet, ((size_t)b * 256 + c) * 4096 + l);
    float inv = LDs<F32>(rg, c) * rsqrtf(LDs<F32>(rv, c) + 1e-5f);
    float rn  = rr * inv + (LDs<F32>(rb, c) - LDs<F32>(rm, c) * inv);

    float xh = 0.5f * h - 0.25f; int jh = (int)floorf(xh); float fh = xh - jh;
    float xw = 0.5f * w - 0.25f; int jw = (int)floorf(xw); float fw = xw - jw;
    int h0 = jh < 0 ? 0 : jh, h1 = jh + 1 > 31 ? 31 : jh + 1;
    int w0 = jw < 0 ? 0 : jw, w1 = jw + 1 > 31 ? 31 : jw + 1;
    const u16* spb = sp16 + (size_t)b * 1024 * 256 + c;
    float v00 = b2f(spb[(size_t)(h0 * 32 + w0) * 256]), v01 = b2f(spb[(size_t)(h0 * 32 + w1) * 256]);
    float v10 = b2f(spb[(size_t)(h1 * 32 + w0) * 256]), v11 = b2f(spb[(size_t)(h1 * 32 + w1) * 256]);
    float sp = (1.f - fh) * ((1.f - fw) * v00 + fw * v01)
             + fh * ((1.f - fw) * v10 + fw * v11);
    float fv = rn + sp;

    __shared__ float red[8];
    float s = fv, s2 = fv * fv;
#pragma unroll
    for (int off = 1; off < 64; off <<= 1) {
        s  += __shfl_xor(s, off);
        s2 += __shfl_xor(s2, off);
    }
    int wv = c >> 6;
    if ((c & 63) == 0) { red[wv] = s; red[4 + wv] = s2; }
    __syncthreads();
    float S  = red[0] + red[1] + red[2] + red[3];
    float S2 = red[4] + red[5] + red[6] + red[7];
    float mu   = S * (1.f / 256.f);
    float var  = S2 * (1.f / 256.f) - mu * mu;
    float rstd = rsqrtf(var + 1e-5f);
    float xnv  = (fv - mu) * rstd * LDs<F32>(lg, c) + LDs<F32>(lb, c);
    xn[((size_t)b * 4096 + l) * 256 + c] = f2b(xnv);
}
__global__ __launch_bounds__(256) void k_ln(const int* flag,
    const void* resnet, const void* rg, const void* rb, const void* rm,
    const void* rv, const void* lg, const void* lb,
    const u16* sp16, u16* xn)
{
    if (*flag) ln_body<true>(resnet, rg, rb, rm, rv, lg, lb, sp16, xn);
    else       ln_body<false>(resnet, rg, rb, rm, rv, lg, lb, sp16, xn);
}

// ---------------------------------------------------------------------------
// in_proj GEMM (xm half): xm[row][n] = sum_k xn[row][k]*W[n*K + k]
// M=8192, N=512, K=256. grid (128, 8), block 256.
// ---------------------------------------------------------------------------
template<bool F32> DEVINL void gemm_in_body(
    const u16* A, const void* W, u16* Out)
{
    const int N = 512, K = 256;
    int tid = threadIdx.x, lane = tid & 63, wid = tid >> 6;
    int ln = lane & 15, q = lane >> 4;
    int m0 = blockIdx.x * 64 + (wid & 1) * 32;
    int n0 = blockIdx.y * 64 + (wid >> 1) * 32;
    f32x4 acc00 = {0.f,0.f,0.f,0.f}, acc01 = acc00, acc10 = acc00, acc11 = acc00;
    const u16* Ap0 = A + (size_t)(m0 + ln) * K + q * 8;
    const u16* Ap1 = Ap0 + (size_t)16 * K;
#pragma unroll 4
    for (int k0 = 0; k0 < K; k0 += 32) {
        int kk = k0 + q * 8;
        short8 a0 = *reinterpret_cast<const short8*>(Ap0 + k0);
        short8 a1 = *reinterpret_cast<const short8*>(Ap1 + k0);
        short8 b0 = LD8<F32>(W, (size_t)(n0 + ln) * K + kk);
        short8 b1 = LD8<F32>(W, (size_t)(n0 + ln + 16) * K + kk);
        acc00 = __builtin_amdgcn_mfma_f32_16x16x32_bf16(a0, b0, acc00, 0, 0, 0);
        acc01 = __builtin_amdgcn_mfma_f32_16x16x32_bf16(a0, b1, acc01, 0, 0, 0);
        acc10 = __builtin_amdgcn_mfma_f32_16x16x32_bf16(a1, b0, acc10, 0, 0, 0);
        acc11 = __builtin_amdgcn_mfma_f32_16x16x32_bf16(a1, b1, acc11, 0, 0, 0);
    }
    int r0 = m0 + q * 4, c0 = n0 + ln;
#pragma unroll
    for (int r = 0; r < 4; ++r) {
        Out[(size_t)(r0 + r) * N + c0]           = f2b(acc00[r]);
        Out[(size_t)(r0 + r) * N + c0 + 16]      = f2b(acc01[r]);
        Out[(size_t)(r0 + 16 + r) * N + c0]      = f2b(acc10[r]);
        Out[(size_t)(r0 + 16 + r) * N + c0 + 16] = f2b(acc11[r]);
    }
}
__global__ __launch_bounds__(256) void k_gemm_in(const int* flag,
    const u16* A, const void* W, u16* Out)
{
    if (*flag) gemm_in_body<true>(A, W, Out);
    else       gemm_in_body<false>(A, W, Out);
}

// ---------------------------------------------------------------------------
// z-GEMM + gating (runs AFTER scan3): z = xn @ inw[512:].T ; y *= silu(z)
// in place over yraw. Same tiling as k_gemm_in.
// ---------------------------------------------------------------------------
template<bool F32> DEVINL void gate_body(
    const u16* A, const void* W, u16* Y)
{
    const int K = 256;
    int tid = threadIdx.x, lane = tid & 63, wid = tid >> 6;
    int ln = lane & 15, q = lane >> 4;
    int m0 = blockIdx.x * 64 + (wid & 1) * 32;
    int n0 = blockIdx.y * 64 + (wid >> 1) * 32;
    f32x4 acc00 = {0.f,0.f,0.f,0.f}, acc01 = acc00, acc10 = acc00, acc11 = acc00;
    const size_t woff = 512 * 256;   // second half of in_proj_w (element offset)
    const u16* Ap0 = A + (size_t)(m0 + ln) * K + q * 8;
    const u16* Ap1 = Ap0 + (size_t)16 * K;
#pragma unroll 4
    for (int k0 = 0; k0 < K; k0 += 32) {
        int kk = k0 + q * 8;
        short8 a0 = *reinterpret_cast<const short8*>(Ap0 + k0);
        short8 a1 = *reinterpret_cast<const short8*>(Ap1 + k0);
        short8 b0 = LD8<F32>(W, woff + (size_t)(n0 + ln) * K + kk);
        short8 b1 = LD8<F32>(W, woff + (size_t)(n0 + ln + 16) * K + kk);
        acc00 = __builtin_amdgcn_mfma_f32_16x16x32_bf16(a0, b0, acc00, 0, 0, 0);
        acc01 = __builtin_amdgcn_mfma_f32_16x16x32_bf16(a0, b1, acc01, 0, 0, 0);
        acc10 = __builtin_amdgcn_mfma_f32_16x16x32_bf16(a1, b0, acc10, 0, 0, 0);
        acc11 = __builtin_amdgcn_mfma_f32_16x16x32_bf16(a1, b1, acc11, 0, 0, 0);
    }
    int r0 = m0 + q * 4, c0 = n0 + ln;
#pragma unroll
    for (int r = 0; r < 4; ++r) {
        { size_t i = (size_t)(r0 + r) * 512 + c0;
          Y[i] = f2b(b2f(Y[i]) * silu(acc00[r])); }
        { size_t i = (size_t)(r0 + r) * 512 + c0 + 16;
          Y[i] = f2b(b2f(Y[i]) * silu(acc01[r])); }
        { size_t i = (size_t)(r0 + 16 + r) * 512 + c0;
          Y[i] = f2b(b2f(Y[i]) * silu(acc10[r])); }
        { size_t i = (size_t)(r0 + 16 + r) * 512 + c0 + 16;
          Y[i] = f2b(b2f(Y[i]) * silu(acc11[r])); }
    }
}
__global__ __launch_bounds__(256) void k_gate(const int* flag,
    const u16* A, const void* W, u16* Y)
{
    if (*flag) gate_body<true>(A, W, Y);
    else       gate_body<false>(A, W, Y);
}

// ---------------------------------------------------------------------------
// on-the-fly u fragment: u[row][kk0..kk0+8) = silu(causal conv3 of xm)
// ---------------------------------------------------------------------------
template<bool F32> DEVINL short8 u_frag(
    const u16* xm, int row, int kk0, const void* cw, const void* cb)
{
    int l = row & 4095;
    const u16* p = xm + (size_t)row * 512 + kk0;
    short8 zz = {0,0,0,0,0,0,0,0};
    short8 x0 = *reinterpret_cast<const short8*>(p);
    short8 x1 = (l >= 1) ? *reinterpret_cast<const short8*>(p - 512)  : zz;
    short8 x2 = (l >= 2) ? *reinterpret_cast<const short8*>(p - 1024) : zz;
    short8 r;
#pragma unroll
    for (int j = 0; j < 8; ++j) {
        int d = kk0 + j;
        float acc = LDs<F32>(cb, d)
                  + b2f((u16)x2[j]) * LDs<F32>(cw, d * 3)
                  + b2f((u16)x1[j]) * LDs<F32>(cw, d * 3 + 1)
                  + b2f((u16)x0[j]) * LDs<F32>(cw, d * 3 + 2);
        r[j] = (short)f2b(silu(acc));
    }
    return r;
}

// ---------------------------------------------------------------------------
// x_proj GEMM with conv-on-the-fly A: xd16[row][n] (bf16), N=48, K=512.
// grid (128), block 256: 4 waves x 16-row tiles = 64 rows/block.
// ---------------------------------------------------------------------------
template<bool F32> DEVINL void xproj_body(
    const u16* xm, const void* xpw, const void* cw, const void* cb, u16* xd16)
{
    int tid = threadIdx.x, lane = tid & 63, wid = tid >> 6;
    int ln = lane & 15, q = lane >> 4;
    int m0 = blockIdx.x * 64 + wid * 16;
    f32x4 acc[3];
#pragma unroll
    for (int j = 0; j < 3; ++j) acc[j] = {0.f,0.f,0.f,0.f};
    for (int k0 = 0; k0 < 512; k0 += 32) {
        int kk0 = k0 + q * 8;
        short8 a0 = u_frag<F32>(xm, m0 + ln, kk0, cw, cb);
#pragma unroll
        for (int j = 0; j < 3; ++j) {
            short8 bj = LD8<F32>(xpw, (size_t)(16 * j + ln) * 512 + kk0);
            acc[j] = __builtin_amdgcn_mfma_f32_16x16x32_bf16(a0, bj, acc[j], 0, 0, 0);
        }
    }
#pragma unroll
    for (int j = 0; j < 3; ++j)
#pragma unroll
        for (int r = 0; r < 4; ++r)
            xd16[(size_t)(m0 + q * 4 + r) * 48 + 16 * j + ln] = f2b(acc[j][r]);
}
__global__ __launch_bounds__(256) void k_xproj(const int* flag,
    const u16* xm, const void* xpw, const void* cw, const void* cb, u16* xd16)
{
    if (*flag) xproj_body<true>(xm, xpw, cw, cb, xd16);
    else       xproj_body<false>(xm, xpw, cw, cb, xd16);
}

// ---------------------------------------------------------------------------
// halo copy: rows l0-2, l0-1 of each chunk (scan3 overwrites xm in place).
// halo[b][ck][t][d]. grid (NC, B), block 512.
// ---------------------------------------------------------------------------
__global__ __launch_bounds__(512) void k_halo(const u16* __restrict__ xm,
                                              u16* __restrict__ halo, int NC, int CL)
{
    int d = threadIdx.x, ck = blockIdx.x, b = blockIdx.y;
#pragma unroll
    for (int t = 0; t < 2; ++t) {
        int l = ck * CL - 2 + t;
        u16 val = (l >= 0) ? xm[((size_t)b * 4096 + l) * 512 + d] : (u16)0;
        halo[(((size_t)b * NC + ck) * 2 + t) * 512 + d] = val;
    }
}

// dt = softplus(dot(xd[0:16], wdt) + bias)
DEVINL float dt_of(const u16* xd, const float* wdt, float bias) {
    float acc = bias;
#pragma unroll
    for (int r = 0; r < 16; ++r) acc += b2f(xd[r]) * wdt[r];
    return acc > 15.f ? acc : log1pf(__expf(acc));
}

// ---------------------------------------------------------------------------
// scan1: per-chunk local scan (conv-on-the-fly u). grid (NC, B), block 512.
// -> cA, cH bf16 [b][ck][s][512]
// ---------------------------------------------------------------------------
template<bool F32> DEVINL void scan1_body(
    const u16* xm, const u16* halo, const u16* xd16,
    const void* alog, const void* dtw, const void* dtb,
    const void* cw, const void* cb, u16* cA, u16* cH, int NC, int CL)
{
    int d = threadIdx.x, ck = blockIdx.x, b = blockIdx.y;
    float wdt[16], a[16], h[16], ap[16];
#pragma unroll
    for (int s = 0; s < 16; ++s) {
        wdt[s] = LDs<F32>(dtw, d * 16 + s);
        a[s] = -__expf(LDs<F32>(alog, d * 16 + s));
        h[s] = 0.f; ap[s] = 1.f;
    }
    float bias = LDs<F32>(dtb, d);
    float cw0 = LDs<F32>(cw, d * 3), cw1 = LDs<F32>(cw, d * 3 + 1),
          cw2 = LDs<F32>(cw, d * 3 + 2), cbv = LDs<F32>(cb, d);
    size_t hb = (((size_t)b * NC + ck) * 2) * 512 + d;
    float x2 = b2f(halo[hb]), x1 = b2f(halo[hb + 512]);
    int l0 = ck * CL;
    for (int il = 0; il < CL; ++il) {
        size_t row = (size_t)b * 4096 + l0 + il;
        float x0 = b2f(xm[row * 512 + d]);
        float uv = silu(cbv + cw0 * x2 + cw1 * x1 + cw2 * x0);
        const u16* xd = xd16 + row * 48;
        float dtv = dt_of(xd, wdt, bias);
        float du = dtv * uv;
#pragma unroll
        for (int s = 0; s < 16; ++s) {
            float dA = __expf(dtv * a[s]);
            h[s]  = dA * h[s] + du * b2f(xd[16 + s]);
            ap[s] *= dA;
        }
        x2 = x1; x1 = x0;
    }
    size_t base = (((size_t)b * NC + ck) * 16) * 512 + d;
#pragma unroll
    for (int s = 0; s < 16; ++s) {
        cA[base + (size_t)s * 512] = f2b(ap[s]);
        cH[base + (size_t)s * 512] = f2b(h[s]);
    }
}
__global__ __launch_bounds__(512) void k_scan1(const int* flag,
    const u16* xm, const u16* halo, const u16* xd16,
    const void* alog, const void* dtw, const void* dtb,
    const void* cw, const void* cb, u16* cA, u16* cH, int NC, int CL)
{
    if (*flag) scan1_body<true>(xm, halo, xd16, alog, dtw, dtb, cw, cb, cA, cH, NC, CL);
    else       scan1_body<false>(xm, halo, xd16, alog, dtw, dtb, cw, cb, cA, cH, NC, CL);
}

// ---------------------------------------------------------------------------
// scan2: cross-chunk recurrence; cH[ck] := h_in(ck).
// grid (16 = s, 4 = d-tile, B), block 128 (thread = d within tile)
// ---------------------------------------------------------------------------
__global__ __launch_bounds__(128) void k_scan2(const u16* __restrict__ cA,
                                               u16* __restrict__ cH, int NC)
{
    int d = blockIdx.y * 128 + threadIdx.x, s = blockIdx.x, b = blockIdx.z;
    float h = 0.f;
#pragma unroll 4
    for (int ck = 0; ck < NC; ++ck) {
        size_t idx = (((size_t)b * NC + ck) * 16 + s) * 512 + d;
        float aP = b2f(cA[idx]), hE = b2f(cH[idx]);
        cH[idx] = f2b(h);
        h = aP * h + hE;
    }
}

// ---------------------------------------------------------------------------
// scan3: replay chunk from h_in; yraw = h.C + u*D written IN PLACE over xm.
// grid (NC, B), block 512.
// ---------------------------------------------------------------------------
template<bool F32> DEVINL void scan3_body(
    u16* xm, const u16* halo, const u16* xd16,
    const void* alog, const void* dtw, const void* dtb,
    const void* cw, const void* cb, const void* Dw, const u16* cH,
    int NC, int CL)
{
    int d = threadIdx.x, ck = blockIdx.x, b = blockIdx.y;
    float wdt[16], a[16], h[16];
    size_t base = (((size_t)b * NC + ck) * 16) * 512 + d;
#pragma unroll
    for (int s = 0; s < 16; ++s) {
        wdt[s] = LDs<F32>(dtw, d * 16 + s);
        a[s] = -__expf(LDs<F32>(alog, d * 16 + s));
        h[s] = b2f(cH[base + (size_t)s * 512]);
    }
    float bias = LDs<F32>(dtb, d);
    float Dv = LDs<F32>(Dw, d);
    float cw0 = LDs<F32>(cw, d * 3), cw1 = LDs<F32>(cw, d * 3 + 1),
          cw2 = LDs<F32>(cw, d * 3 + 2), cbv = LDs<F32>(cb, d);
    size_t hb = (((size_t)b * NC + ck) * 2) * 512 + d;
    float x2 = b2f(halo[hb]), x1 = b2f(halo[hb + 512]);
    int l0 = ck * CL;
    for (int il = 0; il < CL; ++il) {
        size_t row = (size_t)b * 4096 + l0 + il;
        float x0 = b2f(xm[row * 512 + d]);
        float uv = silu(cbv + cw0 * x2 + cw1 * x1 + cw2 * x0);
        const u16* xd = xd16 + row * 48;
        float dtv = dt_of(xd, wdt, bias);
        float du = dtv * uv;
        float yv = 0.f;
#pragma unroll
        for (int s = 0; s < 16; ++s) {
            float dA = __expf(dtv * a[s]);
            h[s] = dA * h[s] + du * b2f(xd[16 + s]);
            yv += h[s] * b2f(xd[32 + s]);
        }
        yv += uv * Dv;
        xm[row * 512 + d] = f2b(yv);   // in-place yraw (x0 already consumed)
        x2 = x1; x1 = x0;
    }
}
__global__ __launch_bounds__(512) void k_scan3(const int* flag,
    u16* xm, const u16* halo, const u16* xd16,
    const void* alog, const void* dtw, const void* dtb,
    const void* cw, const void* cb, const void* Dw, const u16* cH,
    int NC, int CL)
{
    if (*flag) scan3_body<true>(xm, halo, xd16, alog, dtw, dtb, cw, cb, Dw, cH, NC, CL);
    else       scan3_body<false>(xm, halo, xd16, alog, dtw, dtb, cw, cb, Dw, cH, NC, CL);
}

// ---------------------------------------------------------------------------
// out_proj GEMM + fused-recompute epilogue + transposed dual store.
// A = y (8192x512 bf16), W = opw (256x512), out[b][c][h][w].
// grid (128, 4), block 256.
// ---------------------------------------------------------------------------
template<bool F32> DEVINL void out_body(
    const u16* Y, const void* opw,
    const void* resnet, const void* rg, const void* rb, const void* rm,
    const void* rv, const u16* sp16, void* outp)
{
    const int K = 512;
    int tid = threadIdx.x, lane = tid & 63, wid = tid >> 6;
    int ln = lane & 15, q = lane >> 4;
    int m0 = blockIdx.x * 64 + (wid & 1) * 32;
    int n0 = blockIdx.y * 64 + (wid >> 1) * 32;
    f32x4 acc[2][2];
    acc[0][0] = {0.f,0.f,0.f,0.f}; acc[0][1] = acc[0][0];
    acc[1][0] = acc[0][0]; acc[1][1] = acc[0][0];
    const u16* Ap0 = Y + (size_t)(m0 + ln) * K + q * 8;
    const u16* Ap1 = Ap0 + (size_t)16 * K;
#pragma unroll 4
    for (int k0 = 0; k0 < K; k0 += 32) {
        int kk = k0 + q * 8;
        short8 a0 = *reinterpret_cast<const short8*>(Ap0 + k0);
        short8 a1 = *reinterpret_cast<const short8*>(Ap1 + k0);
        short8 b0 = LD8<F32>(opw, (size_t)(n0 + ln) * K + kk);
        short8 b1 = LD8<F32>(opw, (size_t)(n0 + ln + 16) * K + kk);
        acc[0][0] = __builtin_amdgcn_mfma_f32_16x16x32_bf16(a0, b0, acc[0][0], 0, 0, 0);
        acc[0][1] = __builtin_amdgcn_mfma_f32_16x16x32_bf16(a0, b1, acc[0][1], 0, 0, 0);
        acc[1][0] = __builtin_amdgcn_mfma_f32_16x16x32_bf16(a1, b0, acc[1][0], 0, 0, 0);
        acc[1][1] = __builtin_amdgcn_mfma_f32_16x16x32_bf16(a1, b1, acc[1][1], 0, 0, 0);
    }
    int r0 = m0 + q * 4, c0 = n0 + ln;
#pragma unroll
    for (int cg = 0; cg < 2; ++cg) {
        int c = c0 + 16 * cg;
        float inv = LDs<F32>(rg, c) * rsqrtf(LDs<F32>(rv, c) + 1e-5f);
        float sh  = LDs<F32>(rb, c) - LDs<F32>(rm, c) * inv;
#pragma unroll
        for (int rg2 = 0; rg2 < 2; ++rg2) {
#pragma unroll
            for (int r = 0; r < 4; ++r) {
                int row = r0 + 16 * rg2 + r;
                int b = row >> 12, l = row & 4095;
                float accv = acc[rg2][cg][r];
                float rr = LDs<F32>(resnet, ((size_t)b * 256 + c) * 4096 + l);
                float rn = rr * inv + sh;
                int hh = l >> 6, w = l & 63;
                float xh = 0.5f * hh - 0.25f; int jh = (int)floorf(xh); float fh = xh - jh;
                float xw = 0.5f * w - 0.25f;  int jw = (int)floorf(xw); float fw = xw - jw;
                int h0 = jh < 0 ? 0 : jh, h1 = jh + 1 > 31 ? 31 : jh + 1;
                int w0 = jw < 0 ? 0 : jw, w1 = jw + 1 > 31 ? 31 : jw + 1;
                const u16* spb = sp16 + (size_t)b * 1024 * 256 + c;
                float v00 = b2f(spb[(size_t)(h0 * 32 + w0) * 256]);
                float v01 = b2f(spb[(size_t)(h0 * 32 + w1) * 256]);
                float v10 = b2f(spb[(size_t)(h1 * 32 + w0) * 256]);
                float v11 = b2f(spb[(size_t)(h1 * 32 + w1) * 256]);
                float sp = (1.f - fh) * ((1.f - fw) * v00 + fw * v01)
                         + fh * ((1.f - fw) * v10 + fw * v11);
                float val = accv + rn + sp;
                size_t oi = ((size_t)b * 256 + c) * 4096 + l;
                if constexpr (F32) ((float*)outp)[oi] = val;
                else               ((u16*)outp)[oi]  = f2b(val);
            }
        }
    }
}
__global__ __launch_bounds__(256) void k_out(const int* flag,
    const u16* Y, const void* opw,
    const void* resnet, const void* rg, const void* rb, const void* rm,
    const void* rv, const u16* sp16, void* outp)
{
    if (*flag) out_body<true>(Y, opw, resnet, rg, rb, rm, rv, sp16, outp);
    else       out_body<false>(Y, opw, resnet, rg, rb, rm, rv, sp16, outp);
}

// ---------------------------------------------------------------------------
extern "C" void kernel_launch(void* const* d_in, const int* in_sizes, int n_in,
                              void* d_out, int out_size, void* d_ws, size_t ws_size,
                              hipStream_t stream)
{
    const void* resnet = d_in[0];
    const void* scp    = d_in[1];
    const void* spw    = d_in[2];
    const void* sg     = d_in[3];
    const void* sb     = d_in[4];
    const void* sm     = d_in[5];
    const void* sv     = d_in[6];
    const void* rg     = d_in[7];
    const void* rb     = d_in[8];
    const void* rm     = d_in[9];
    const void* rv     = d_in[10];
    const void* lg     = d_in[11];
    const void* lb     = d_in[12];
    const void* inw    = d_in[13];
    const void* cw     = d_in[14];
    const void* cb     = d_in[15];
    const void* xpw    = d_in[16];
    const void* dtw    = d_in[17];
    const void* dtb    = d_in[18];
    const void* alog   = d_in[19];
    const void* Dw     = d_in[20];
    const void* opw    = d_in[21];

    // Fixed part of workspace: 14,422,016 B. Scan state (cA,cH,halo) scales
    // with chunk count NC: NC*69632 B. Pick largest NC that fits ws_size.
    // NC is a pure function of ws_size -> identical work every call (graph-safe).
    char* ws = (char*)d_ws;
    int*  flag    = (int*)(ws);
    int*  partial = (int*)(ws + 128);
    u16*  sp16    = (u16*)(ws + 4096);
    u16*  xn      = (u16*)(ws + 1052672);
    u16*  xm      = (u16*)(ws + 5246976);   // becomes yraw / y in place
    u16*  xd16    = (u16*)(ws + 13635584);
    const size_t tail0 = 14422016;

    int NC = 16;
    for (int cand = 128; cand >= 16; cand >>= 1) {
        if (tail0 + (size_t)cand * 69632 <= ws_size) { NC = cand; break; }
    }
    int CL = 4096 / NC;
    u16* cA   = (u16*)(ws + tail0);
    u16* cH   = (u16*)(ws + tail0 + (size_t)NC * 32768);
    u16* halo = (u16*)(ws + tail0 + (size_t)NC * 65536);

    k_detect1<<<dim3(64), 256, 0, stream>>>((const u16*)resnet, partial);
    k_detect2<<<dim3(1), 64, 0, stream>>>(partial, flag);
    k_scp<<<dim3(32, 4, 2), 256, 0, stream>>>(flag, scp, spw, sg, sb, sm, sv, sp16);
    k_ln<<<dim3(4096, 2), 256, 0, stream>>>(flag, resnet, rg, rb, rm, rv, lg, lb, sp16, xn);
    k_gemm_in<<<dim3(128, 8), 256, 0, stream>>>(flag, xn, inw, xm);
    k_halo<<<dim3(NC, 2), 512, 0, stream>>>(xm, halo, NC, CL);
    k_xproj<<<dim3(128), 256, 0, stream>>>(flag, xm, xpw, cw, cb, xd16);
    k_scan1<<<dim3(NC, 2), 512, 0, stream>>>(flag, xm, halo, xd16, alog, dtw, dtb, cw, cb, cA, cH, NC, CL);
    k_scan2<<<dim3(16, 4, 2), 128, 0, stream>>>(cA, cH, NC);
    k_scan3<<<dim3(NC, 2), 512, 0, stream>>>(flag, xm, halo, xd16, alog, dtw, dtb, cw, cb, Dw, cH, NC, CL);
    k_gate<<<dim3(128, 8), 256, 0, stream>>>(flag, xn, inw, xm);
    k_out<<<dim3(128, 4), 256, 0, stream>>>(flag, xm, opw, resnet, rg, rb, rm, rv, sp16, d_out);
}

// Round 5
// 359.847 us; speedup vs baseline: 2.5077x; 1.0990x over previous
//
#include <hip/hip_runtime.h>
#include <hip/hip_bf16.h>
#include <math.h>

typedef unsigned short u16;
typedef __attribute__((ext_vector_type(8))) short short8;
typedef __attribute__((ext_vector_type(4))) float f32x4;
typedef __attribute__((ext_vector_type(4))) unsigned short u16x4;

#define DEVINL static __device__ __forceinline__

DEVINL float b2f(u16 x) {
    union { unsigned u; float f; } v; v.u = ((unsigned)x) << 16; return v.f;
}
DEVINL u16 f2b(float f) {
    union { unsigned u; float f; } v; v.f = f;
    unsigned u = v.u;
    return (u16)((u + 0x7fffu + ((u >> 16) & 1u)) >> 16);
}
DEVINL float silu(float x) { return x / (1.f + __expf(-x)); }

// dual-mode scalar load: input tensors may be f32 or bf16 (runtime-detected)
template<bool F32> DEVINL float LDs(const void* p, size_t i) {
    if constexpr (F32) return ((const float*)p)[i];
    else               return b2f(((const u16*)p)[i]);
}
// dual-mode 8-element fragment load (for MFMA operands from input weights)
template<bool F32> DEVINL short8 LD8(const void* p, size_t i) {
    if constexpr (F32) {
        const float* f = (const float*)p + i;
        short8 r;
#pragma unroll
        for (int j = 0; j < 8; ++j) r[j] = (short)f2b(f[j]);
        return r;
    } else {
        return *reinterpret_cast<const short8*>((const u16*)p + i);
    }
}

// ---------------------------------------------------------------------------
// dtype detection (see round 2 notes): bf16 N(0,1) -> count 0; f32 -> >>0.
// ---------------------------------------------------------------------------
__global__ __launch_bounds__(256) void k_detect1(const u16* __restrict__ raw,
                                                 int* __restrict__ partial)
{
    int tid = threadIdx.x, bid = blockIdx.x;
    int cnt = 0;
    for (size_t i = (size_t)bid * 256 + tid; i < 2097152; i += 64 * 256) {
        float v = b2f(raw[i]);
        if (!(fabsf(v) <= 1e3f)) cnt++;
    }
#pragma unroll
    for (int off = 1; off < 64; off <<= 1) cnt += __shfl_xor(cnt, off);
    __shared__ int s4[4];
    if ((tid & 63) == 0) s4[tid >> 6] = cnt;
    __syncthreads();
    if (tid == 0) partial[bid] = s4[0] + s4[1] + s4[2] + s4[3];
}

__global__ __launch_bounds__(64) void k_detect2(const int* __restrict__ partial,
                                                int* __restrict__ flag)
{
    int c = partial[threadIdx.x];
#pragma unroll
    for (int off = 1; off < 64; off <<= 1) c += __shfl_xor(c, off);
    if (threadIdx.x == 0) flag[0] = (c > 0) ? 1 : 0;
}

// ---------------------------------------------------------------------------
// k_tr: LDS-tiled transpose src[b][R][C] -> dst[b][C][R] (dst bf16).
// grid (C/64, R/64, B), block 256. Coalesced on both sides.
// ---------------------------------------------------------------------------
template<bool F32> DEVINL void tr_body(const void* src, u16* dst, int R, int C)
{
    __shared__ u16 t[64][66];
    int tid = threadIdx.x;
    int c0 = blockIdx.x * 64, r0 = blockIdx.y * 64, b = blockIdx.z;
    int lane = tid & 63, grp = tid >> 6;
#pragma unroll
    for (int j = 0; j < 16; ++j) {
        int rl = j * 4 + grp;
        t[rl][lane] = f2b(LDs<F32>(src, ((size_t)b * R + r0 + rl) * C + c0 + lane));
    }
    __syncthreads();
#pragma unroll
    for (int j = 0; j < 16; ++j) {
        int cl = j * 4 + grp;
        dst[((size_t)b * C + c0 + cl) * R + r0 + lane] = t[lane][cl];
    }
}
__global__ __launch_bounds__(256) void k_tr(const int* flag,
    const void* src, u16* dst, int R, int C)
{
    if (*flag) tr_body<true>(src, dst, R, C);
    else       tr_body<false>(src, dst, R, C);
}

// ---------------------------------------------------------------------------
// k_scpmm: sp16[p][o] = BN(sum_c scpT[p][c] * spw[o][c]). MFMA.
// M=2048 (b*1024+p), N=256, K=512. grid (32, 4), block 256 (4 waves 2x2).
// ---------------------------------------------------------------------------
template<bool F32> DEVINL void scpmm_body(
    const u16* scpT, const void* W, const void* g, const void* bb,
    const void* m_, const void* v_, u16* sp16)
{
    const int N = 256, K = 512;
    int tid = threadIdx.x, lane = tid & 63, wid = tid >> 6;
    int ln = lane & 15, q = lane >> 4;
    int m0 = blockIdx.x * 64 + (wid & 1) * 32;
    int n0 = blockIdx.y * 64 + (wid >> 1) * 32;
    f32x4 acc00 = {0.f,0.f,0.f,0.f}, acc01 = acc00, acc10 = acc00, acc11 = acc00;
    const u16* Ap0 = scpT + (size_t)(m0 + ln) * K + q * 8;
    const u16* Ap1 = Ap0 + (size_t)16 * K;
#pragma unroll 4
    for (int k0 = 0; k0 < K; k0 += 32) {
        int kk = k0 + q * 8;
        short8 a0 = *reinterpret_cast<const short8*>(Ap0 + k0);
        short8 a1 = *reinterpret_cast<const short8*>(Ap1 + k0);
        short8 b0 = LD8<F32>(W, (size_t)(n0 + ln) * K + kk);
        short8 b1 = LD8<F32>(W, (size_t)(n0 + ln + 16) * K + kk);
        acc00 = __builtin_amdgcn_mfma_f32_16x16x32_bf16(a0, b0, acc00, 0, 0, 0);
        acc01 = __builtin_amdgcn_mfma_f32_16x16x32_bf16(a0, b1, acc01, 0, 0, 0);
        acc10 = __builtin_amdgcn_mfma_f32_16x16x32_bf16(a1, b0, acc10, 0, 0, 0);
        acc11 = __builtin_amdgcn_mfma_f32_16x16x32_bf16(a1, b1, acc11, 0, 0, 0);
    }
    int r0 = m0 + q * 4, c0 = n0 + ln;
    float inv0 = LDs<F32>(g, c0)      * rsqrtf(LDs<F32>(v_, c0)      + 1e-5f);
    float sh0  = LDs<F32>(bb, c0)      - LDs<F32>(m_, c0)      * inv0;
    float inv1 = LDs<F32>(g, c0 + 16) * rsqrtf(LDs<F32>(v_, c0 + 16) + 1e-5f);
    float sh1  = LDs<F32>(bb, c0 + 16) - LDs<F32>(m_, c0 + 16) * inv1;
#pragma unroll
    for (int r = 0; r < 4; ++r) {
        sp16[(size_t)(r0 + r) * N + c0]           = f2b(acc00[r] * inv0 + sh0);
        sp16[(size_t)(r0 + r) * N + c0 + 16]      = f2b(acc01[r] * inv1 + sh1);
        sp16[(size_t)(r0 + 16 + r) * N + c0]      = f2b(acc10[r] * inv0 + sh0);
        sp16[(size_t)(r0 + 16 + r) * N + c0 + 16] = f2b(acc11[r] * inv1 + sh1);
    }
}
__global__ __launch_bounds__(256) void k_scpmm(const int* flag,
    const u16* scpT, const void* W, const void* g, const void* bb,
    const void* m_, const void* v_, u16* sp16)
{
    if (*flag) scpmm_body<true>(scpT, W, g, bb, m_, v_, sp16);
    else       scpmm_body<false>(scpT, W, g, bb, m_, v_, sp16);
}

// ---------------------------------------------------------------------------
// K1: res-BN (from transposed resnetT, coalesced) + bilinear + add -> LN -> xn
// grid (L=4096, B), block 256 (thread = channel).
// ---------------------------------------------------------------------------
template<bool F32> DEVINL void ln_body(
    const u16* resnetT, const void* rg, const void* rb, const void* rm,
    const void* rv, const void* lg, const void* lb,
    const u16* sp16, u16* xn)
{
    int c = threadIdx.x, l = blockIdx.x, b = blockIdx.y;
    int h = l >> 6, w = l & 63;
    float rr  = b2f(resnetT[((size_t)b * 4096 + l) * 256 + c]);
    float inv = LDs<F32>(rg, c) * rsqrtf(LDs<F32>(rv, c) + 1e-5f);
    float rn  = rr * inv + (LDs<F32>(rb, c) - LDs<F32>(rm, c) * inv);

    float xh = 0.5f * h - 0.25f; int jh = (int)floorf(xh); float fh = xh - jh;
    float xw = 0.5f * w - 0.25f; int jw = (int)floorf(xw); float fw = xw - jw;
    int h0 = jh < 0 ? 0 : jh, h1 = jh + 1 > 31 ? 31 : jh + 1;
    int w0 = jw < 0 ? 0 : jw, w1 = jw + 1 > 31 ? 31 : jw + 1;
    const u16* spb = sp16 + (size_t)b * 1024 * 256 + c;
    float v00 = b2f(spb[(size_t)(h0 * 32 + w0) * 256]), v01 = b2f(spb[(size_t)(h0 * 32 + w1) * 256]);
    float v10 = b2f(spb[(size_t)(h1 * 32 + w0) * 256]), v11 = b2f(spb[(size_t)(h1 * 32 + w1) * 256]);
    float sp = (1.f - fh) * ((1.f - fw) * v00 + fw * v01)
             + fh * ((1.f - fw) * v10 + fw * v11);
    float fv = rn + sp;

    __shared__ float red[8];
    float s = fv, s2 = fv * fv;
#pragma unroll
    for (int off = 1; off < 64; off <<= 1) {
        s  += __shfl_xor(s, off);
        s2 += __shfl_xor(s2, off);
    }
    int wv = c >> 6;
    if ((c & 63) == 0) { red[wv] = s; red[4 + wv] = s2; }
    __syncthreads();
    float S  = red[0] + red[1] + red[2] + red[3];
    float S2 = red[4] + red[5] + red[6] + red[7];
    float mu   = S * (1.f / 256.f);
    float var  = S2 * (1.f / 256.f) - mu * mu;
    float rstd = rsqrtf(var + 1e-5f);
    float xnv  = (fv - mu) * rstd * LDs<F32>(lg, c) + LDs<F32>(lb, c);
    xn[((size_t)b * 4096 + l) * 256 + c] = f2b(xnv);
}
__global__ __launch_bounds__(256) void k_ln(const int* flag,
    const u16* resnetT, const void* rg, const void* rb, const void* rm,
    const void* rv, const void* lg, const void* lb,
    const u16* sp16, u16* xn)
{
    if (*flag) ln_body<true>(resnetT, rg, rb, rm, rv, lg, lb, sp16, xn);
    else       ln_body<false>(resnetT, rg, rb, rm, rv, lg, lb, sp16, xn);
}

// ---------------------------------------------------------------------------
// in_proj GEMM (xm half): M=8192, N=512, K=256. grid (128, 8), block 256.
// ---------------------------------------------------------------------------
template<bool F32> DEVINL void gemm_in_body(
    const u16* A, const void* W, u16* Out)
{
    const int N = 512, K = 256;
    int tid = threadIdx.x, lane = tid & 63, wid = tid >> 6;
    int ln = lane & 15, q = lane >> 4;
    int m0 = blockIdx.x * 64 + (wid & 1) * 32;
    int n0 = blockIdx.y * 64 + (wid >> 1) * 32;
    f32x4 acc00 = {0.f,0.f,0.f,0.f}, acc01 = acc00, acc10 = acc00, acc11 = acc00;
    const u16* Ap0 = A + (size_t)(m0 + ln) * K + q * 8;
    const u16* Ap1 = Ap0 + (size_t)16 * K;
#pragma unroll 4
    for (int k0 = 0; k0 < K; k0 += 32) {
        int kk = k0 + q * 8;
        short8 a0 = *reinterpret_cast<const short8*>(Ap0 + k0);
        short8 a1 = *reinterpret_cast<const short8*>(Ap1 + k0);
        short8 b0 = LD8<F32>(W, (size_t)(n0 + ln) * K + kk);
        short8 b1 = LD8<F32>(W, (size_t)(n0 + ln + 16) * K + kk);
        acc00 = __builtin_amdgcn_mfma_f32_16x16x32_bf16(a0, b0, acc00, 0, 0, 0);
        acc01 = __builtin_amdgcn_mfma_f32_16x16x32_bf16(a0, b1, acc01, 0, 0, 0);
        acc10 = __builtin_amdgcn_mfma_f32_16x16x32_bf16(a1, b0, acc10, 0, 0, 0);
        acc11 = __builtin_amdgcn_mfma_f32_16x16x32_bf16(a1, b1, acc11, 0, 0, 0);
    }
    int r0 = m0 + q * 4, c0 = n0 + ln;
#pragma unroll
    for (int r = 0; r < 4; ++r) {
        Out[(size_t)(r0 + r) * N + c0]           = f2b(acc00[r]);
        Out[(size_t)(r0 + r) * N + c0 + 16]      = f2b(acc01[r]);
        Out[(size_t)(r0 + 16 + r) * N + c0]      = f2b(acc10[r]);
        Out[(size_t)(r0 + 16 + r) * N + c0 + 16] = f2b(acc11[r]);
    }
}
__global__ __launch_bounds__(256) void k_gemm_in(const int* flag,
    const u16* A, const void* W, u16* Out)
{
    if (*flag) gemm_in_body<true>(A, W, Out);
    else       gemm_in_body<false>(A, W, Out);
}

// ---------------------------------------------------------------------------
// z-GEMM + gating (AFTER scan3): z = xn @ inw[512:].T ; y *= silu(z) in place.
// ---------------------------------------------------------------------------
template<bool F32> DEVINL void gate_body(
    const u16* A, const void* W, u16* Y)
{
    const int K = 256;
    int tid = threadIdx.x, lane = tid & 63, wid = tid >> 6;
    int ln = lane & 15, q = lane >> 4;
    int m0 = blockIdx.x * 64 + (wid & 1) * 32;
    int n0 = blockIdx.y * 64 + (wid >> 1) * 32;
    f32x4 acc00 = {0.f,0.f,0.f,0.f}, acc01 = acc00, acc10 = acc00, acc11 = acc00;
    const size_t woff = 512 * 256;
    const u16* Ap0 = A + (size_t)(m0 + ln) * K + q * 8;
    const u16* Ap1 = Ap0 + (size_t)16 * K;
#pragma unroll 4
    for (int k0 = 0; k0 < K; k0 += 32) {
        int kk = k0 + q * 8;
        short8 a0 = *reinterpret_cast<const short8*>(Ap0 + k0);
        short8 a1 = *reinterpret_cast<const short8*>(Ap1 + k0);
        short8 b0 = LD8<F32>(W, woff + (size_t)(n0 + ln) * K + kk);
        short8 b1 = LD8<F32>(W, woff + (size_t)(n0 + ln + 16) * K + kk);
        acc00 = __builtin_amdgcn_mfma_f32_16x16x32_bf16(a0, b0, acc00, 0, 0, 0);
        acc01 = __builtin_amdgcn_mfma_f32_16x16x32_bf16(a0, b1, acc01, 0, 0, 0);
        acc10 = __builtin_amdgcn_mfma_f32_16x16x32_bf16(a1, b0, acc10, 0, 0, 0);
        acc11 = __builtin_amdgcn_mfma_f32_16x16x32_bf16(a1, b1, acc11, 0, 0, 0);
    }
    int r0 = m0 + q * 4, c0 = n0 + ln;
#pragma unroll
    for (int r = 0; r < 4; ++r) {
        { size_t i = (size_t)(r0 + r) * 512 + c0;
          Y[i] = f2b(b2f(Y[i]) * silu(acc00[r])); }
        { size_t i = (size_t)(r0 + r) * 512 + c0 + 16;
          Y[i] = f2b(b2f(Y[i]) * silu(acc01[r])); }
        { size_t i = (size_t)(r0 + 16 + r) * 512 + c0;
          Y[i] = f2b(b2f(Y[i]) * silu(acc10[r])); }
        { size_t i = (size_t)(r0 + 16 + r) * 512 + c0 + 16;
          Y[i] = f2b(b2f(Y[i]) * silu(acc11[r])); }
    }
}
__global__ __launch_bounds__(256) void k_gate(const int* flag,
    const u16* A, const void* W, u16* Y)
{
    if (*flag) gate_body<true>(A, W, Y);
    else       gate_body<false>(A, W, Y);
}

// ---------------------------------------------------------------------------
// on-the-fly u fragment: u[row][kk0..kk0+8) = silu(causal conv3 of xm)
// ---------------------------------------------------------------------------
template<bool F32> DEVINL short8 u_frag(
    const u16* xm, int row, int kk0, const void* cw, const void* cb)
{
    int l = row & 4095;
    const u16* p = xm + (size_t)row * 512 + kk0;
    short8 zz = {0,0,0,0,0,0,0,0};
    short8 x0 = *reinterpret_cast<const short8*>(p);
    short8 x1 = (l >= 1) ? *reinterpret_cast<const short8*>(p - 512)  : zz;
    short8 x2 = (l >= 2) ? *reinterpret_cast<const short8*>(p - 1024) : zz;
    short8 r;
#pragma unroll
    for (int j = 0; j < 8; ++j) {
        int d = kk0 + j;
        float acc = LDs<F32>(cb, d)
                  + b2f((u16)x2[j]) * LDs<F32>(cw, d * 3)
                  + b2f((u16)x1[j]) * LDs<F32>(cw, d * 3 + 1)
                  + b2f((u16)x0[j]) * LDs<F32>(cw, d * 3 + 2);
        r[j] = (short)f2b(silu(acc));
    }
    return r;
}

// ---------------------------------------------------------------------------
// x_proj GEMM with conv-on-the-fly A: xd16[row][n] (bf16), N=48, K=512.
// grid (128), block 256: 4 waves x 16-row tiles.
// ---------------------------------------------------------------------------
template<bool F32> DEVINL void xproj_body(
    const u16* xm, const void* xpw, const void* cw, const void* cb, u16* xd16)
{
    int tid = threadIdx.x, lane = tid & 63, wid = tid >> 6;
    int ln = lane & 15, q = lane >> 4;
    int m0 = blockIdx.x * 64 + wid * 16;
    f32x4 acc[3];
#pragma unroll
    for (int j = 0; j < 3; ++j) acc[j] = {0.f,0.f,0.f,0.f};
    for (int k0 = 0; k0 < 512; k0 += 32) {
        int kk0 = k0 + q * 8;
        short8 a0 = u_frag<F32>(xm, m0 + ln, kk0, cw, cb);
#pragma unroll
        for (int j = 0; j < 3; ++j) {
            short8 bj = LD8<F32>(xpw, (size_t)(16 * j + ln) * 512 + kk0);
            acc[j] = __builtin_amdgcn_mfma_f32_16x16x32_bf16(a0, bj, acc[j], 0, 0, 0);
        }
    }
#pragma unroll
    for (int j = 0; j < 3; ++j)
#pragma unroll
        for (int r = 0; r < 4; ++r)
            xd16[(size_t)(m0 + q * 4 + r) * 48 + 16 * j + ln] = f2b(acc[j][r]);
}
__global__ __launch_bounds__(256) void k_xproj(const int* flag,
    const u16* xm, const void* xpw, const void* cw, const void* cb, u16* xd16)
{
    if (*flag) xproj_body<true>(xm, xpw, cw, cb, xd16);
    else       xproj_body<false>(xm, xpw, cw, cb, xd16);
}

// ---------------------------------------------------------------------------
// halo copy: rows l0-2, l0-1 of each chunk. grid (NC, B), block 512.
// ---------------------------------------------------------------------------
__global__ __launch_bounds__(512) void k_halo(const u16* __restrict__ xm,
                                              u16* __restrict__ halo, int NC, int CL)
{
    int d = threadIdx.x, ck = blockIdx.x, b = blockIdx.y;
#pragma unroll
    for (int t = 0; t < 2; ++t) {
        int l = ck * CL - 2 + t;
        u16 val = (l >= 0) ? xm[((size_t)b * 4096 + l) * 512 + d] : (u16)0;
        halo[(((size_t)b * NC + ck) * 2 + t) * 512 + d] = val;
    }
}

// dt = softplus(dot(xd[0:16], wdt) + bias)
DEVINL float dt_of(const u16* xd, const float* wdt, float bias) {
    float acc = bias;
#pragma unroll
    for (int r = 0; r < 16; ++r) acc += b2f(xd[r]) * wdt[r];
    return acc > 15.f ? acc : log1pf(__expf(acc));
}

// ---------------------------------------------------------------------------
// scan1: per-chunk local scan. grid (NC, B), block 512. -> cA, cH bf16
// ---------------------------------------------------------------------------
template<bool F32> DEVINL void scan1_body(
    const u16* xm, const u16* halo, const u16* xd16,
    const void* alog, const void* dtw, const void* dtb,
    const void* cw, const void* cb, u16* cA, u16* cH, int NC, int CL)
{
    int d = threadIdx.x, ck = blockIdx.x, b = blockIdx.y;
    float wdt[16], a[16], h[16], ap[16];
#pragma unroll
    for (int s = 0; s < 16; ++s) {
        wdt[s] = LDs<F32>(dtw, d * 16 + s);
        a[s] = -__expf(LDs<F32>(alog, d * 16 + s));
        h[s] = 0.f; ap[s] = 1.f;
    }
    float bias = LDs<F32>(dtb, d);
    float cw0 = LDs<F32>(cw, d * 3), cw1 = LDs<F32>(cw, d * 3 + 1),
          cw2 = LDs<F32>(cw, d * 3 + 2), cbv = LDs<F32>(cb, d);
    size_t hb = (((size_t)b * NC + ck) * 2) * 512 + d;
    float x2 = b2f(halo[hb]), x1 = b2f(halo[hb + 512]);
    int l0 = ck * CL;
    for (int il = 0; il < CL; ++il) {
        size_t row = (size_t)b * 4096 + l0 + il;
        float x0 = b2f(xm[row * 512 + d]);
        float uv = silu(cbv + cw0 * x2 + cw1 * x1 + cw2 * x0);
        const u16* xd = xd16 + row * 48;
        float dtv = dt_of(xd, wdt, bias);
        float du = dtv * uv;
#pragma unroll
        for (int s = 0; s < 16; ++s) {
            float dA = __expf(dtv * a[s]);
            h[s]  = dA * h[s] + du * b2f(xd[16 + s]);
            ap[s] *= dA;
        }
        x2 = x1; x1 = x0;
    }
    size_t base = (((size_t)b * NC + ck) * 16) * 512 + d;
#pragma unroll
    for (int s = 0; s < 16; ++s) {
        cA[base + (size_t)s * 512] = f2b(ap[s]);
        cH[base + (size_t)s * 512] = f2b(h[s]);
    }
}
__global__ __launch_bounds__(512) void k_scan1(const int* flag,
    const u16* xm, const u16* halo, const u16* xd16,
    const void* alog, const void* dtw, const void* dtb,
    const void* cw, const void* cb, u16* cA, u16* cH, int NC, int CL)
{
    if (*flag) scan1_body<true>(xm, halo, xd16, alog, dtw, dtb, cw, cb, cA, cH, NC, CL);
    else       scan1_body<false>(xm, halo, xd16, alog, dtw, dtb, cw, cb, cA, cH, NC, CL);
}

// ---------------------------------------------------------------------------
// scan2: cross-chunk recurrence; cH[ck] := h_in(ck).
// grid (16 = s, 4 = d-tile, B), block 128.
// ---------------------------------------------------------------------------
__global__ __launch_bounds__(128) void k_scan2(const u16* __restrict__ cA,
                                               u16* __restrict__ cH, int NC)
{
    int d = blockIdx.y * 128 + threadIdx.x, s = blockIdx.x, b = blockIdx.z;
    float h = 0.f;
#pragma unroll 4
    for (int ck = 0; ck < NC; ++ck) {
        size_t idx = (((size_t)b * NC + ck) * 16 + s) * 512 + d;
        float aP = b2f(cA[idx]), hE = b2f(cH[idx]);
        cH[idx] = f2b(h);
        h = aP * h + hE;
    }
}

// ---------------------------------------------------------------------------
// scan3: replay chunk from h_in; yraw = h.C + u*D written IN PLACE over xm.
// grid (NC, B), block 512.
// ---------------------------------------------------------------------------
template<bool F32> DEVINL void scan3_body(
    u16* xm, const u16* halo, const u16* xd16,
    const void* alog, const void* dtw, const void* dtb,
    const void* cw, const void* cb, const void* Dw, const u16* cH,
    int NC, int CL)
{
    int d = threadIdx.x, ck = blockIdx.x, b = blockIdx.y;
    float wdt[16], a[16], h[16];
    size_t base = (((size_t)b * NC + ck) * 16) * 512 + d;
#pragma unroll
    for (int s = 0; s < 16; ++s) {
        wdt[s] = LDs<F32>(dtw, d * 16 + s);
        a[s] = -__expf(LDs<F32>(alog, d * 16 + s));
        h[s] = b2f(cH[base + (size_t)s * 512]);
    }
    float bias = LDs<F32>(dtb, d);
    float Dv = LDs<F32>(Dw, d);
    float cw0 = LDs<F32>(cw, d * 3), cw1 = LDs<F32>(cw, d * 3 + 1),
          cw2 = LDs<F32>(cw, d * 3 + 2), cbv = LDs<F32>(cb, d);
    size_t hb = (((size_t)b * NC + ck) * 2) * 512 + d;
    float x2 = b2f(halo[hb]), x1 = b2f(halo[hb + 512]);
    int l0 = ck * CL;
    for (int il = 0; il < CL; ++il) {
        size_t row = (size_t)b * 4096 + l0 + il;
        float x0 = b2f(xm[row * 512 + d]);
        float uv = silu(cbv + cw0 * x2 + cw1 * x1 + cw2 * x0);
        const u16* xd = xd16 + row * 48;
        float dtv = dt_of(xd, wdt, bias);
        float du = dtv * uv;
        float yv = 0.f;
#pragma unroll
        for (int s = 0; s < 16; ++s) {
            float dA = __expf(dtv * a[s]);
            h[s] = dA * h[s] + du * b2f(xd[16 + s]);
            yv += h[s] * b2f(xd[32 + s]);
        }
        yv += uv * Dv;
        xm[row * 512 + d] = f2b(yv);
        x2 = x1; x1 = x0;
    }
}
__global__ __launch_bounds__(512) void k_scan3(const int* flag,
    u16* xm, const u16* halo, const u16* xd16,
    const void* alog, const void* dtw, const void* dtb,
    const void* cw, const void* cb, const void* Dw, const u16* cH,
    int NC, int CL)
{
    if (*flag) scan3_body<true>(xm, halo, xd16, alog, dtw, dtb, cw, cb, Dw, cH, NC, CL);
    else       scan3_body<false>(xm, halo, xd16, alog, dtw, dtb, cw, cb, Dw, cH, NC, CL);
}

// ---------------------------------------------------------------------------
// out_proj GEMM (m = channel, n = sequence) + fused-recompute epilogue.
// A-op = opw rows (o, K-contig), B-op = y rows (l, K-contig).
// Epilogue: resnet-BN + bilinear recompute + coalesced NCHW store (lanes over l).
// grid (4, 128), block 256.
// ---------------------------------------------------------------------------
template<bool F32> DEVINL void out_body(
    const u16* Y, const void* opw,
    const void* resnet, const void* rg, const void* rb, const void* rm,
    const void* rv, const u16* sp16, void* outp)
{
    const int K = 512;
    int tid = threadIdx.x, lane = tid & 63, wid = tid >> 6;
    int ln = lane & 15, q = lane >> 4;
    int m0 = blockIdx.x * 64 + (wid & 1) * 32;   // channel dim (256)
    int n0 = blockIdx.y * 64 + (wid >> 1) * 32;  // sequence dim (8192)
    f32x4 acc[2][2];
    acc[0][0] = {0.f,0.f,0.f,0.f}; acc[0][1] = acc[0][0];
    acc[1][0] = acc[0][0]; acc[1][1] = acc[0][0];
    const u16* Bp0 = Y + (size_t)(n0 + ln) * K + q * 8;
    const u16* Bp1 = Bp0 + (size_t)16 * K;
#pragma unroll 4
    for (int k0 = 0; k0 < K; k0 += 32) {
        int kk = k0 + q * 8;
        short8 b0 = *reinterpret_cast<const short8*>(Bp0 + k0);
        short8 b1 = *reinterpret_cast<const short8*>(Bp1 + k0);
        short8 a0 = LD8<F32>(opw, (size_t)(m0 + ln) * K + kk);
        short8 a1 = LD8<F32>(opw, (size_t)(m0 + ln + 16) * K + kk);
        acc[0][0] = __builtin_amdgcn_mfma_f32_16x16x32_bf16(a0, b0, acc[0][0], 0, 0, 0);
        acc[0][1] = __builtin_amdgcn_mfma_f32_16x16x32_bf16(a0, b1, acc[0][1], 0, 0, 0);
        acc[1][0] = __builtin_amdgcn_mfma_f32_16x16x32_bf16(a1, b0, acc[1][0], 0, 0, 0);
        acc[1][1] = __builtin_amdgcn_mfma_f32_16x16x32_bf16(a1, b1, acc[1][1], 0, 0, 0);
    }
    int r0 = m0 + q * 4;      // channel base (x4-aligned)
    int nb = n0 + ln;         // sequence base
    // hoist BN params for the 8 channels this lane touches
    float inv8[2][4], sh8[2][4];
#pragma unroll
    for (int im = 0; im < 2; ++im)
#pragma unroll
        for (int r = 0; r < 4; ++r) {
            int c = r0 + 16 * im + r;
            float inv = LDs<F32>(rg, c) * rsqrtf(LDs<F32>(rv, c) + 1e-5f);
            inv8[im][r] = inv;
            sh8[im][r]  = LDs<F32>(rb, c) - LDs<F32>(rm, c) * inv;
        }
#pragma unroll
    for (int jn = 0; jn < 2; ++jn) {
        int n = nb + 16 * jn;
        int b = n >> 12, l = n & 4095;
        int hh = l >> 6, w = l & 63;
        float xh = 0.5f * hh - 0.25f; int jh = (int)floorf(xh); float fh = xh - jh;
        float xw = 0.5f * w - 0.25f;  int jw = (int)floorf(xw); float fw = xw - jw;
        int h0 = jh < 0 ? 0 : jh, h1 = jh + 1 > 31 ? 31 : jh + 1;
        int w0 = jw < 0 ? 0 : jw, w1 = jw + 1 > 31 ? 31 : jw + 1;
        float w00 = (1.f - fh) * (1.f - fw), w01 = (1.f - fh) * fw;
        float w10 = fh * (1.f - fw),         w11 = fh * fw;
        const u16* spb = sp16 + (size_t)b * 1024 * 256;
#pragma unroll
        for (int im = 0; im < 2; ++im) {
            int cb = r0 + 16 * im;
            u16x4 s00 = *reinterpret_cast<const u16x4*>(spb + (size_t)(h0 * 32 + w0) * 256 + cb);
            u16x4 s01 = *reinterpret_cast<const u16x4*>(spb + (size_t)(h0 * 32 + w1) * 256 + cb);
            u16x4 s10 = *reinterpret_cast<const u16x4*>(spb + (size_t)(h1 * 32 + w0) * 256 + cb);
            u16x4 s11 = *reinterpret_cast<const u16x4*>(spb + (size_t)(h1 * 32 + w1) * 256 + cb);
#pragma unroll
            for (int r = 0; r < 4; ++r) {
                int c = cb + r;
                float rr = LDs<F32>(resnet, ((size_t)b * 256 + c) * 4096 + l);
                float sp = w00 * b2f(s00[r]) + w01 * b2f(s01[r])
                         + w10 * b2f(s10[r]) + w11 * b2f(s11[r]);
                float val = acc[im][jn][r] + rr * inv8[im][r] + sh8[im][r] + sp;
                size_t oi = ((size_t)b * 256 + c) * 4096 + l;
                if constexpr (F32) ((float*)outp)[oi] = val;
                else               ((u16*)outp)[oi]  = f2b(val);
            }
        }
    }
}
__global__ __launch_bounds__(256) void k_out(const int* flag,
    const u16* Y, const void* opw,
    const void* resnet, const void* rg, const void* rb, const void* rm,
    const void* rv, const u16* sp16, void* outp)
{
    if (*flag) out_body<true>(Y, opw, resnet, rg, rb, rm, rv, sp16, outp);
    else       out_body<false>(Y, opw, resnet, rg, rb, rm, rv, sp16, outp);
}

// ---------------------------------------------------------------------------
extern "C" void kernel_launch(void* const* d_in, const int* in_sizes, int n_in,
                              void* d_out, int out_size, void* d_ws, size_t ws_size,
                              hipStream_t stream)
{
    const void* resnet = d_in[0];
    const void* scp    = d_in[1];
    const void* spw    = d_in[2];
    const void* sg     = d_in[3];
    const void* sb     = d_in[4];
    const void* sm     = d_in[5];
    const void* sv     = d_in[6];
    const void* rg     = d_in[7];
    const void* rb     = d_in[8];
    const void* rm     = d_in[9];
    const void* rv     = d_in[10];
    const void* lg     = d_in[11];
    const void* lb     = d_in[12];
    const void* inw    = d_in[13];
    const void* cw     = d_in[14];
    const void* cb     = d_in[15];
    const void* xpw    = d_in[16];
    const void* dtw    = d_in[17];
    const void* dtb    = d_in[18];
    const void* alog   = d_in[19];
    const void* Dw     = d_in[20];
    const void* opw    = d_in[21];

    // Workspace: fixed 14,422,016 B + NC*69632 B scan state.
    // scpT (2 MB) and resnetT (4 MB) alias the xm region (consumed before
    // k_gemm_in writes xm).
    char* ws = (char*)d_ws;
    int*  flag    = (int*)(ws);
    int*  partial = (int*)(ws + 128);
    u16*  sp16    = (u16*)(ws + 4096);
    u16*  xn      = (u16*)(ws + 1052672);
    u16*  xm      = (u16*)(ws + 5246976);   // becomes yraw / y in place
    u16*  scpT    = (u16*)(ws + 5246976);             // 2 MB, dead after k_scpmm
    u16*  resnetT = (u16*)(ws + 5246976 + (2u<<20));  // 4 MB, dead after k_ln
    u16*  xd16    = (u16*)(ws + 13635584);
    const size_t tail0 = 14422016;

    int NC = 16;
    for (int cand = 128; cand >= 16; cand >>= 1) {
        if (tail0 + (size_t)cand * 69632 <= ws_size) { NC = cand; break; }
    }
    int CL = 4096 / NC;
    u16* cA   = (u16*)(ws + tail0);
    u16* cH   = (u16*)(ws + tail0 + (size_t)NC * 32768);
    u16* halo = (u16*)(ws + tail0 + (size_t)NC * 65536);

    k_detect1<<<dim3(64), 256, 0, stream>>>((const u16*)resnet, partial);
    k_detect2<<<dim3(1), 64, 0, stream>>>(partial, flag);
    // scp [b][512][1024] -> scpT [b][1024][512]
    k_tr<<<dim3(16, 8, 2), 256, 0, stream>>>(flag, scp, scpT, 512, 1024);
    k_scpmm<<<dim3(32, 4), 256, 0, stream>>>(flag, scpT, spw, sg, sb, sm, sv, sp16);
    // resnet [b][256][4096] -> resnetT [b][4096][256]
    k_tr<<<dim3(64, 4, 2), 256, 0, stream>>>(flag, resnet, resnetT, 256, 4096);
    k_ln<<<dim3(4096, 2), 256, 0, stream>>>(flag, resnetT, rg, rb, rm, rv, lg, lb, sp16, xn);
    k_gemm_in<<<dim3(128, 8), 256, 0, stream>>>(flag, xn, inw, xm);
    k_halo<<<dim3(NC, 2), 512, 0, stream>>>(xm, halo, NC, CL);
    k_xproj<<<dim3(128), 256, 0, stream>>>(flag, xm, xpw, cw, cb, xd16);
    k_scan1<<<dim3(NC, 2), 512, 0, stream>>>(flag, xm, halo, xd16, alog, dtw, dtb, cw, cb, cA, cH, NC, CL);
    k_scan2<<<dim3(16, 4, 2), 128, 0, stream>>>(cA, cH, NC);
    k_scan3<<<dim3(NC, 2), 512, 0, stream>>>(flag, xm, halo, xd16, alog, dtw, dtb, cw, cb, Dw, cH, NC, CL);
    k_gate<<<dim3(128, 8), 256, 0, stream>>>(flag, xn, inw, xm);
    k_out<<<dim3(4, 128), 256, 0, stream>>>(flag, xm, opw, resnet, rg, rb, rm, rv, sp16, d_out);
}

// Round 6
// 331.088 us; speedup vs baseline: 2.7255x; 1.0869x over previous
//
#include <hip/hip_runtime.h>
#include <hip/hip_bf16.h>
#include <math.h>

typedef unsigned short u16;
typedef __attribute__((ext_vector_type(8))) short short8;
typedef __attribute__((ext_vector_type(4))) float f32x4;
typedef __attribute__((ext_vector_type(4))) unsigned short u16x4;

#define DEVINL static __device__ __forceinline__

DEVINL float b2f(u16 x) {
    union { unsigned u; float f; } v; v.u = ((unsigned)x) << 16; return v.f;
}
DEVINL u16 f2b(float f) {
    union { unsigned u; float f; } v; v.f = f;
    unsigned u = v.u;
    return (u16)((u + 0x7fffu + ((u >> 16) & 1u)) >> 16);
}
DEVINL float silu(float x) { return x / (1.f + __expf(-x)); }

// dual-mode scalar load: input tensors may be f32 or bf16 (runtime-detected)
template<bool F32> DEVINL float LDs(const void* p, size_t i) {
    if constexpr (F32) return ((const float*)p)[i];
    else               return b2f(((const u16*)p)[i]);
}
// dual-mode 8-element fragment load (for MFMA operands from input weights)
template<bool F32> DEVINL short8 LD8(const void* p, size_t i) {
    if constexpr (F32) {
        const float* f = (const float*)p + i;
        short8 r;
#pragma unroll
        for (int j = 0; j < 8; ++j) r[j] = (short)f2b(f[j]);
        return r;
    } else {
        return *reinterpret_cast<const short8*>((const u16*)p + i);
    }
}

// ---------------------------------------------------------------------------
// dtype detection (see round 2 notes): bf16 N(0,1) -> count 0; f32 -> >>0.
// ---------------------------------------------------------------------------
__global__ __launch_bounds__(256) void k_detect1(const u16* __restrict__ raw,
                                                 int* __restrict__ partial)
{
    int tid = threadIdx.x, bid = blockIdx.x;
    int cnt = 0;
    for (size_t i = (size_t)bid * 256 + tid; i < 2097152; i += 64 * 256) {
        float v = b2f(raw[i]);
        if (!(fabsf(v) <= 1e3f)) cnt++;
    }
#pragma unroll
    for (int off = 1; off < 64; off <<= 1) cnt += __shfl_xor(cnt, off);
    __shared__ int s4[4];
    if ((tid & 63) == 0) s4[tid >> 6] = cnt;
    __syncthreads();
    if (tid == 0) partial[bid] = s4[0] + s4[1] + s4[2] + s4[3];
}

__global__ __launch_bounds__(64) void k_detect2(const int* __restrict__ partial,
                                                int* __restrict__ flag)
{
    int c = partial[threadIdx.x];
#pragma unroll
    for (int off = 1; off < 64; off <<= 1) c += __shfl_xor(c, off);
    if (threadIdx.x == 0) flag[0] = (c > 0) ? 1 : 0;
}

// ---------------------------------------------------------------------------
// k_tr: LDS-tiled transpose src[b][R][C] -> dst[b][C][R] (dst bf16).
// grid (C/64, R/64, B), block 256. Coalesced on both sides.
// ---------------------------------------------------------------------------
template<bool F32> DEVINL void tr_body(const void* src, u16* dst, int R, int C)
{
    __shared__ u16 t[64][66];
    int tid = threadIdx.x;
    int c0 = blockIdx.x * 64, r0 = blockIdx.y * 64, b = blockIdx.z;
    int lane = tid & 63, grp = tid >> 6;
#pragma unroll
    for (int j = 0; j < 16; ++j) {
        int rl = j * 4 + grp;
        t[rl][lane] = f2b(LDs<F32>(src, ((size_t)b * R + r0 + rl) * C + c0 + lane));
    }
    __syncthreads();
#pragma unroll
    for (int j = 0; j < 16; ++j) {
        int cl = j * 4 + grp;
        dst[((size_t)b * C + c0 + cl) * R + r0 + lane] = t[lane][cl];
    }
}
__global__ __launch_bounds__(256) void k_tr(const int* flag,
    const void* src, u16* dst, int R, int C)
{
    if (*flag) tr_body<true>(src, dst, R, C);
    else       tr_body<false>(src, dst, R, C);
}

// ---------------------------------------------------------------------------
// k_scpmm: sp16[p][o] = BN(sum_c scpT[p][c] * spw[o][c]). MFMA.
// M=2048 (b*1024+p), N=256, K=512. grid (32, 4), block 256 (4 waves 2x2).
// ---------------------------------------------------------------------------
template<bool F32> DEVINL void scpmm_body(
    const u16* scpT, const void* W, const void* g, const void* bb,
    const void* m_, const void* v_, u16* sp16)
{
    const int N = 256, K = 512;
    int tid = threadIdx.x, lane = tid & 63, wid = tid >> 6;
    int ln = lane & 15, q = lane >> 4;
    int m0 = blockIdx.x * 64 + (wid & 1) * 32;
    int n0 = blockIdx.y * 64 + (wid >> 1) * 32;
    f32x4 acc00 = {0.f,0.f,0.f,0.f}, acc01 = acc00, acc10 = acc00, acc11 = acc00;
    const u16* Ap0 = scpT + (size_t)(m0 + ln) * K + q * 8;
    const u16* Ap1 = Ap0 + (size_t)16 * K;
#pragma unroll 4
    for (int k0 = 0; k0 < K; k0 += 32) {
        int kk = k0 + q * 8;
        short8 a0 = *reinterpret_cast<const short8*>(Ap0 + k0);
        short8 a1 = *reinterpret_cast<const short8*>(Ap1 + k0);
        short8 b0 = LD8<F32>(W, (size_t)(n0 + ln) * K + kk);
        short8 b1 = LD8<F32>(W, (size_t)(n0 + ln + 16) * K + kk);
        acc00 = __builtin_amdgcn_mfma_f32_16x16x32_bf16(a0, b0, acc00, 0, 0, 0);
        acc01 = __builtin_amdgcn_mfma_f32_16x16x32_bf16(a0, b1, acc01, 0, 0, 0);
        acc10 = __builtin_amdgcn_mfma_f32_16x16x32_bf16(a1, b0, acc10, 0, 0, 0);
        acc11 = __builtin_amdgcn_mfma_f32_16x16x32_bf16(a1, b1, acc11, 0, 0, 0);
    }
    int r0 = m0 + q * 4, c0 = n0 + ln;
    float inv0 = LDs<F32>(g, c0)      * rsqrtf(LDs<F32>(v_, c0)      + 1e-5f);
    float sh0  = LDs<F32>(bb, c0)      - LDs<F32>(m_, c0)      * inv0;
    float inv1 = LDs<F32>(g, c0 + 16) * rsqrtf(LDs<F32>(v_, c0 + 16) + 1e-5f);
    float sh1  = LDs<F32>(bb, c0 + 16) - LDs<F32>(m_, c0 + 16) * inv1;
#pragma unroll
    for (int r = 0; r < 4; ++r) {
        sp16[(size_t)(r0 + r) * N + c0]           = f2b(acc00[r] * inv0 + sh0);
        sp16[(size_t)(r0 + r) * N + c0 + 16]      = f2b(acc01[r] * inv1 + sh1);
        sp16[(size_t)(r0 + 16 + r) * N + c0]      = f2b(acc10[r] * inv0 + sh0);
        sp16[(size_t)(r0 + 16 + r) * N + c0 + 16] = f2b(acc11[r] * inv1 + sh1);
    }
}
__global__ __launch_bounds__(256) void k_scpmm(const int* flag,
    const u16* scpT, const void* W, const void* g, const void* bb,
    const void* m_, const void* v_, u16* sp16)
{
    if (*flag) scpmm_body<true>(scpT, W, g, bb, m_, v_, sp16);
    else       scpmm_body<false>(scpT, W, g, bb, m_, v_, sp16);
}

// ---------------------------------------------------------------------------
// K1: res-BN (from transposed resnetT, coalesced) + bilinear + add -> LN -> xn
// grid (L=4096, B), block 256 (thread = channel).
// ---------------------------------------------------------------------------
template<bool F32> DEVINL void ln_body(
    const u16* resnetT, const void* rg, const void* rb, const void* rm,
    const void* rv, const void* lg, const void* lb,
    const u16* sp16, u16* xn)
{
    int c = threadIdx.x, l = blockIdx.x, b = blockIdx.y;
    int h = l >> 6, w = l & 63;
    float rr  = b2f(resnetT[((size_t)b * 4096 + l) * 256 + c]);
    float inv = LDs<F32>(rg, c) * rsqrtf(LDs<F32>(rv, c) + 1e-5f);
    float rn  = rr * inv + (LDs<F32>(rb, c) - LDs<F32>(rm, c) * inv);

    float xh = 0.5f * h - 0.25f; int jh = (int)floorf(xh); float fh = xh - jh;
    float xw = 0.5f * w - 0.25f; int jw = (int)floorf(xw); float fw = xw - jw;
    int h0 = jh < 0 ? 0 : jh, h1 = jh + 1 > 31 ? 31 : jh + 1;
    int w0 = jw < 0 ? 0 : jw, w1 = jw + 1 > 31 ? 31 : jw + 1;
    const u16* spb = sp16 + (size_t)b * 1024 * 256 + c;
    float v00 = b2f(spb[(size_t)(h0 * 32 + w0) * 256]), v01 = b2f(spb[(size_t)(h0 * 32 + w1) * 256]);
    float v10 = b2f(spb[(size_t)(h1 * 32 + w0) * 256]), v11 = b2f(spb[(size_t)(h1 * 32 + w1) * 256]);
    float sp = (1.f - fh) * ((1.f - fw) * v00 + fw * v01)
             + fh * ((1.f - fw) * v10 + fw * v11);
    float fv = rn + sp;

    __shared__ float red[8];
    float s = fv, s2 = fv * fv;
#pragma unroll
    for (int off = 1; off < 64; off <<= 1) {
        s  += __shfl_xor(s, off);
        s2 += __shfl_xor(s2, off);
    }
    int wv = c >> 6;
    if ((c & 63) == 0) { red[wv] = s; red[4 + wv] = s2; }
    __syncthreads();
    float S  = red[0] + red[1] + red[2] + red[3];
    float S2 = red[4] + red[5] + red[6] + red[7];
    float mu   = S * (1.f / 256.f);
    float var  = S2 * (1.f / 256.f) - mu * mu;
    float rstd = rsqrtf(var + 1e-5f);
    float xnv  = (fv - mu) * rstd * LDs<F32>(lg, c) + LDs<F32>(lb, c);
    xn[((size_t)b * 4096 + l) * 256 + c] = f2b(xnv);
}
__global__ __launch_bounds__(256) void k_ln(const int* flag,
    const u16* resnetT, const void* rg, const void* rb, const void* rm,
    const void* rv, const void* lg, const void* lb,
    const u16* sp16, u16* xn)
{
    if (*flag) ln_body<true>(resnetT, rg, rb, rm, rv, lg, lb, sp16, xn);
    else       ln_body<false>(resnetT, rg, rb, rm, rv, lg, lb, sp16, xn);
}

// ---------------------------------------------------------------------------
// in_proj GEMM (xm half): M=8192, N=512, K=256. grid (128, 8), block 256.
// ---------------------------------------------------------------------------
template<bool F32> DEVINL void gemm_in_body(
    const u16* A, const void* W, u16* Out)
{
    const int N = 512, K = 256;
    int tid = threadIdx.x, lane = tid & 63, wid = tid >> 6;
    int ln = lane & 15, q = lane >> 4;
    int m0 = blockIdx.x * 64 + (wid & 1) * 32;
    int n0 = blockIdx.y * 64 + (wid >> 1) * 32;
    f32x4 acc00 = {0.f,0.f,0.f,0.f}, acc01 = acc00, acc10 = acc00, acc11 = acc00;
    const u16* Ap0 = A + (size_t)(m0 + ln) * K + q * 8;
    const u16* Ap1 = Ap0 + (size_t)16 * K;
#pragma unroll 4
    for (int k0 = 0; k0 < K; k0 += 32) {
        int kk = k0 + q * 8;
        short8 a0 = *reinterpret_cast<const short8*>(Ap0 + k0);
        short8 a1 = *reinterpret_cast<const short8*>(Ap1 + k0);
        short8 b0 = LD8<F32>(W, (size_t)(n0 + ln) * K + kk);
        short8 b1 = LD8<F32>(W, (size_t)(n0 + ln + 16) * K + kk);
        acc00 = __builtin_amdgcn_mfma_f32_16x16x32_bf16(a0, b0, acc00, 0, 0, 0);
        acc01 = __builtin_amdgcn_mfma_f32_16x16x32_bf16(a0, b1, acc01, 0, 0, 0);
        acc10 = __builtin_amdgcn_mfma_f32_16x16x32_bf16(a1, b0, acc10, 0, 0, 0);
        acc11 = __builtin_amdgcn_mfma_f32_16x16x32_bf16(a1, b1, acc11, 0, 0, 0);
    }
    int r0 = m0 + q * 4, c0 = n0 + ln;
#pragma unroll
    for (int r = 0; r < 4; ++r) {
        Out[(size_t)(r0 + r) * N + c0]           = f2b(acc00[r]);
        Out[(size_t)(r0 + r) * N + c0 + 16]      = f2b(acc01[r]);
        Out[(size_t)(r0 + 16 + r) * N + c0]      = f2b(acc10[r]);
        Out[(size_t)(r0 + 16 + r) * N + c0 + 16] = f2b(acc11[r]);
    }
}
__global__ __launch_bounds__(256) void k_gemm_in(const int* flag,
    const u16* A, const void* W, u16* Out)
{
    if (*flag) gemm_in_body<true>(A, W, Out);
    else       gemm_in_body<false>(A, W, Out);
}

// ---------------------------------------------------------------------------
// z-GEMM + gating (AFTER scan3): z = xn @ inw[512:].T ; y *= silu(z) in place.
// ---------------------------------------------------------------------------
template<bool F32> DEVINL void gate_body(
    const u16* A, const void* W, u16* Y)
{
    const int K = 256;
    int tid = threadIdx.x, lane = tid & 63, wid = tid >> 6;
    int ln = lane & 15, q = lane >> 4;
    int m0 = blockIdx.x * 64 + (wid & 1) * 32;
    int n0 = blockIdx.y * 64 + (wid >> 1) * 32;
    f32x4 acc00 = {0.f,0.f,0.f,0.f}, acc01 = acc00, acc10 = acc00, acc11 = acc00;
    const size_t woff = 512 * 256;
    const u16* Ap0 = A + (size_t)(m0 + ln) * K + q * 8;
    const u16* Ap1 = Ap0 + (size_t)16 * K;
#pragma unroll 4
    for (int k0 = 0; k0 < K; k0 += 32) {
        int kk = k0 + q * 8;
        short8 a0 = *reinterpret_cast<const short8*>(Ap0 + k0);
        short8 a1 = *reinterpret_cast<const short8*>(Ap1 + k0);
        short8 b0 = LD8<F32>(W, woff + (size_t)(n0 + ln) * K + kk);
        short8 b1 = LD8<F32>(W, woff + (size_t)(n0 + ln + 16) * K + kk);
        acc00 = __builtin_amdgcn_mfma_f32_16x16x32_bf16(a0, b0, acc00, 0, 0, 0);
        acc01 = __builtin_amdgcn_mfma_f32_16x16x32_bf16(a0, b1, acc01, 0, 0, 0);
        acc10 = __builtin_amdgcn_mfma_f32_16x16x32_bf16(a1, b0, acc10, 0, 0, 0);
        acc11 = __builtin_amdgcn_mfma_f32_16x16x32_bf16(a1, b1, acc11, 0, 0, 0);
    }
    int r0 = m0 + q * 4, c0 = n0 + ln;
#pragma unroll
    for (int r = 0; r < 4; ++r) {
        { size_t i = (size_t)(r0 + r) * 512 + c0;
          Y[i] = f2b(b2f(Y[i]) * silu(acc00[r])); }
        { size_t i = (size_t)(r0 + r) * 512 + c0 + 16;
          Y[i] = f2b(b2f(Y[i]) * silu(acc01[r])); }
        { size_t i = (size_t)(r0 + 16 + r) * 512 + c0;
          Y[i] = f2b(b2f(Y[i]) * silu(acc10[r])); }
        { size_t i = (size_t)(r0 + 16 + r) * 512 + c0 + 16;
          Y[i] = f2b(b2f(Y[i]) * silu(acc11[r])); }
    }
}
__global__ __launch_bounds__(256) void k_gate(const int* flag,
    const u16* A, const void* W, u16* Y)
{
    if (*flag) gate_body<true>(A, W, Y);
    else       gate_body<false>(A, W, Y);
}

// ---------------------------------------------------------------------------
// on-the-fly u fragment: u[row][kk0..kk0+8) = silu(causal conv3 of xm)
// ---------------------------------------------------------------------------
template<bool F32> DEVINL short8 u_frag(
    const u16* xm, int row, int kk0, const void* cw, const void* cb)
{
    int l = row & 4095;
    const u16* p = xm + (size_t)row * 512 + kk0;
    short8 zz = {0,0,0,0,0,0,0,0};
    short8 x0 = *reinterpret_cast<const short8*>(p);
    short8 x1 = (l >= 1) ? *reinterpret_cast<const short8*>(p - 512)  : zz;
    short8 x2 = (l >= 2) ? *reinterpret_cast<const short8*>(p - 1024) : zz;
    short8 r;
#pragma unroll
    for (int j = 0; j < 8; ++j) {
        int d = kk0 + j;
        float acc = LDs<F32>(cb, d)
                  + b2f((u16)x2[j]) * LDs<F32>(cw, d * 3)
                  + b2f((u16)x1[j]) * LDs<F32>(cw, d * 3 + 1)
                  + b2f((u16)x0[j]) * LDs<F32>(cw, d * 3 + 2);
        r[j] = (short)f2b(silu(acc));
    }
    return r;
}

// ---------------------------------------------------------------------------
// x_proj GEMM with conv-on-the-fly A: xd16[row][n] (bf16), N=48, K=512.
// grid (128), block 256: 4 waves x 16-row tiles.
// ---------------------------------------------------------------------------
template<bool F32> DEVINL void xproj_body(
    const u16* xm, const void* xpw, const void* cw, const void* cb, u16* xd16)
{
    int tid = threadIdx.x, lane = tid & 63, wid = tid >> 6;
    int ln = lane & 15, q = lane >> 4;
    int m0 = blockIdx.x * 64 + wid * 16;
    f32x4 acc[3];
#pragma unroll
    for (int j = 0; j < 3; ++j) acc[j] = {0.f,0.f,0.f,0.f};
    for (int k0 = 0; k0 < 512; k0 += 32) {
        int kk0 = k0 + q * 8;
        short8 a0 = u_frag<F32>(xm, m0 + ln, kk0, cw, cb);
#pragma unroll
        for (int j = 0; j < 3; ++j) {
            short8 bj = LD8<F32>(xpw, (size_t)(16 * j + ln) * 512 + kk0);
            acc[j] = __builtin_amdgcn_mfma_f32_16x16x32_bf16(a0, bj, acc[j], 0, 0, 0);
        }
    }
#pragma unroll
    for (int j = 0; j < 3; ++j)
#pragma unroll
        for (int r = 0; r < 4; ++r)
            xd16[(size_t)(m0 + q * 4 + r) * 48 + 16 * j + ln] = f2b(acc[j][r]);
}
__global__ __launch_bounds__(256) void k_xproj(const int* flag,
    const u16* xm, const void* xpw, const void* cw, const void* cb, u16* xd16)
{
    if (*flag) xproj_body<true>(xm, xpw, cw, cb, xd16);
    else       xproj_body<false>(xm, xpw, cw, cb, xd16);
}

// ---------------------------------------------------------------------------
// halo copy: rows l0-2, l0-1 of each chunk. grid (NC, B), block 512.
// ---------------------------------------------------------------------------
__global__ __launch_bounds__(512) void k_halo(const u16* __restrict__ xm,
                                              u16* __restrict__ halo, int NC, int CL)
{
    int d = threadIdx.x, ck = blockIdx.x, b = blockIdx.y;
#pragma unroll
    for (int t = 0; t < 2; ++t) {
        int l = ck * CL - 2 + t;
        u16 val = (l >= 0) ? xm[((size_t)b * 4096 + l) * 512 + d] : (u16)0;
        halo[(((size_t)b * NC + ck) * 2 + t) * 512 + d] = val;
    }
}

// dt = softplus(dot(xd[0:16] (f32, LDS), wdt) + bias)
DEVINL float dt_of(const float* xd, const float* wdt, float bias) {
    float acc = bias;
#pragma unroll
    for (int r = 0; r < 16; ++r) acc += xd[r] * wdt[r];
    return acc > 15.f ? acc : __logf(1.f + __expf(acc));
}

// ---------------------------------------------------------------------------
// scan1: per-chunk local scan. grid (NC, B), block 512. -> cA, cH bf16
// xd16 rows staged through LDS (f32) in 32-row tiles: the inner loop reads
// wave-uniform broadcast ds_read_b128 instead of 48 scalar global loads.
// ---------------------------------------------------------------------------
template<bool F32> DEVINL void scan1_body(
    const u16* xm, const u16* halo, const u16* xd16,
    const void* alog, const void* dtw, const void* dtb,
    const void* cw, const void* cb, u16* cA, u16* cH, int NC, int CL)
{
    __shared__ float xds[32][48];
    int d = threadIdx.x, ck = blockIdx.x, b = blockIdx.y;
    float wdt[16], a[16], h[16], ap[16];
#pragma unroll
    for (int s = 0; s < 16; ++s) {
        wdt[s] = LDs<F32>(dtw, d * 16 + s);
        a[s] = -__expf(LDs<F32>(alog, d * 16 + s));
        h[s] = 0.f; ap[s] = 1.f;
    }
    float bias = LDs<F32>(dtb, d);
    float cw0 = LDs<F32>(cw, d * 3), cw1 = LDs<F32>(cw, d * 3 + 1),
          cw2 = LDs<F32>(cw, d * 3 + 2), cbv = LDs<F32>(cb, d);
    size_t hb = (((size_t)b * NC + ck) * 2) * 512 + d;
    float x2 = b2f(halo[hb]), x1 = b2f(halo[hb + 512]);
    int l0 = ck * CL;
    for (int t0 = 0; t0 < CL; t0 += 32) {
        __syncthreads();
#pragma unroll
        for (int k = 0; k < 3; ++k) {
            int idx = k * 512 + d;            // 0..1535 = 32*48
            int r = idx / 48, c = idx - r * 48;
            xds[r][c] = b2f(xd16[((size_t)b * 4096 + l0 + t0 + r) * 48 + c]);
        }
        __syncthreads();
        for (int il = 0; il < 32; ++il) {
            size_t row = (size_t)b * 4096 + l0 + t0 + il;
            float x0 = b2f(xm[row * 512 + d]);
            float uv = silu(cbv + cw0 * x2 + cw1 * x1 + cw2 * x0);
            const float* xd = xds[il];
            float dtv = dt_of(xd, wdt, bias);
            float du = dtv * uv;
#pragma unroll
            for (int s = 0; s < 16; ++s) {
                float dA = __expf(dtv * a[s]);
                h[s]  = dA * h[s] + du * xd[16 + s];
                ap[s] *= dA;
            }
            x2 = x1; x1 = x0;
        }
    }
    size_t base = (((size_t)b * NC + ck) * 16) * 512 + d;
#pragma unroll
    for (int s = 0; s < 16; ++s) {
        cA[base + (size_t)s * 512] = f2b(ap[s]);
        cH[base + (size_t)s * 512] = f2b(h[s]);
    }
}
__global__ __launch_bounds__(512) void k_scan1(const int* flag,
    const u16* xm, const u16* halo, const u16* xd16,
    const void* alog, const void* dtw, const void* dtb,
    const void* cw, const void* cb, u16* cA, u16* cH, int NC, int CL)
{
    if (*flag) scan1_body<true>(xm, halo, xd16, alog, dtw, dtb, cw, cb, cA, cH, NC, CL);
    else       scan1_body<false>(xm, halo, xd16, alog, dtw, dtb, cw, cb, cA, cH, NC, CL);
}

// ---------------------------------------------------------------------------
// scan2: cross-chunk recurrence; cH[ck] := h_in(ck).
// grid (16 = s, 4 = d-tile, B), block 128.
// ---------------------------------------------------------------------------
__global__ __launch_bounds__(128) void k_scan2(const u16* __restrict__ cA,
                                               u16* __restrict__ cH, int NC)
{
    int d = blockIdx.y * 128 + threadIdx.x, s = blockIdx.x, b = blockIdx.z;
    float h = 0.f;
#pragma unroll 4
    for (int ck = 0; ck < NC; ++ck) {
        size_t idx = (((size_t)b * NC + ck) * 16 + s) * 512 + d;
        float aP = b2f(cA[idx]), hE = b2f(cH[idx]);
        cH[idx] = f2b(h);
        h = aP * h + hE;
    }
}

// ---------------------------------------------------------------------------
// scan3: replay chunk from h_in; yraw = h.C + u*D written IN PLACE over xm.
// grid (NC, B), block 512. Same LDS staging as scan1.
// ---------------------------------------------------------------------------
template<bool F32> DEVINL void scan3_body(
    u16* xm, const u16* halo, const u16* xd16,
    const void* alog, const void* dtw, const void* dtb,
    const void* cw, const void* cb, const void* Dw, const u16* cH,
    int NC, int CL)
{
    __shared__ float xds[32][48];
    int d = threadIdx.x, ck = blockIdx.x, b = blockIdx.y;
    float wdt[16], a[16], h[16];
    size_t base = (((size_t)b * NC + ck) * 16) * 512 + d;
#pragma unroll
    for (int s = 0; s < 16; ++s) {
        wdt[s] = LDs<F32>(dtw, d * 16 + s);
        a[s] = -__expf(LDs<F32>(alog, d * 16 + s));
        h[s] = b2f(cH[base + (size_t)s * 512]);
    }
    float bias = LDs<F32>(dtb, d);
    float Dv = LDs<F32>(Dw, d);
    float cw0 = LDs<F32>(cw, d * 3), cw1 = LDs<F32>(cw, d * 3 + 1),
          cw2 = LDs<F32>(cw, d * 3 + 2), cbv = LDs<F32>(cb, d);
    size_t hb = (((size_t)b * NC + ck) * 2) * 512 + d;
    float x2 = b2f(halo[hb]), x1 = b2f(halo[hb + 512]);
    int l0 = ck * CL;
    for (int t0 = 0; t0 < CL; t0 += 32) {
        __syncthreads();
#pragma unroll
        for (int k = 0; k < 3; ++k) {
            int idx = k * 512 + d;
            int r = idx / 48, c = idx - r * 48;
            xds[r][c] = b2f(xd16[((size_t)b * 4096 + l0 + t0 + r) * 48 + c]);
        }
        __syncthreads();
        for (int il = 0; il < 32; ++il) {
            size_t row = (size_t)b * 4096 + l0 + t0 + il;
            float x0 = b2f(xm[row * 512 + d]);
            float uv = silu(cbv + cw0 * x2 + cw1 * x1 + cw2 * x0);
            const float* xd = xds[il];
            float dtv = dt_of(xd, wdt, bias);
            float du = dtv * uv;
            float yv = 0.f;
#pragma unroll
            for (int s = 0; s < 16; ++s) {
                float dA = __expf(dtv * a[s]);
                h[s] = dA * h[s] + du * xd[16 + s];
                yv += h[s] * xd[32 + s];
            }
            yv += uv * Dv;
            xm[row * 512 + d] = f2b(yv);
            x2 = x1; x1 = x0;
        }
    }
}
__global__ __launch_bounds__(512) void k_scan3(const int* flag,
    u16* xm, const u16* halo, const u16* xd16,
    const void* alog, const void* dtw, const void* dtb,
    const void* cw, const void* cb, const void* Dw, const u16* cH,
    int NC, int CL)
{
    if (*flag) scan3_body<true>(xm, halo, xd16, alog, dtw, dtb, cw, cb, Dw, cH, NC, CL);
    else       scan3_body<false>(xm, halo, xd16, alog, dtw, dtb, cw, cb, Dw, cH, NC, CL);
}

// ---------------------------------------------------------------------------
// out_proj GEMM (m = channel, n = sequence) + fused-recompute epilogue.
// grid (4, 128), block 256.
// ---------------------------------------------------------------------------
template<bool F32> DEVINL void out_body(
    const u16* Y, const void* opw,
    const void* resnet, const void* rg, const void* rb, const void* rm,
    const void* rv, const u16* sp16, void* outp)
{
    const int K = 512;
    int tid = threadIdx.x, lane = tid & 63, wid = tid >> 6;
    int ln = lane & 15, q = lane >> 4;
    int m0 = blockIdx.x * 64 + (wid & 1) * 32;   // channel dim (256)
    int n0 = blockIdx.y * 64 + (wid >> 1) * 32;  // sequence dim (8192)
    f32x4 acc[2][2];
    acc[0][0] = {0.f,0.f,0.f,0.f}; acc[0][1] = acc[0][0];
    acc[1][0] = acc[0][0]; acc[1][1] = acc[0][0];
    const u16* Bp0 = Y + (size_t)(n0 + ln) * K + q * 8;
    const u16* Bp1 = Bp0 + (size_t)16 * K;
#pragma unroll 4
    for (int k0 = 0; k0 < K; k0 += 32) {
        int kk = k0 + q * 8;
        short8 b0 = *reinterpret_cast<const short8*>(Bp0 + k0);
        short8 b1 = *reinterpret_cast<const short8*>(Bp1 + k0);
        short8 a0 = LD8<F32>(opw, (size_t)(m0 + ln) * K + kk);
        short8 a1 = LD8<F32>(opw, (size_t)(m0 + ln + 16) * K + kk);
        acc[0][0] = __builtin_amdgcn_mfma_f32_16x16x32_bf16(a0, b0, acc[0][0], 0, 0, 0);
        acc[0][1] = __builtin_amdgcn_mfma_f32_16x16x32_bf16(a0, b1, acc[0][1], 0, 0, 0);
        acc[1][0] = __builtin_amdgcn_mfma_f32_16x16x32_bf16(a1, b0, acc[1][0], 0, 0, 0);
        acc[1][1] = __builtin_amdgcn_mfma_f32_16x16x32_bf16(a1, b1, acc[1][1], 0, 0, 0);
    }
    int r0 = m0 + q * 4;
    int nb = n0 + ln;
    float inv8[2][4], sh8[2][4];
#pragma unroll
    for (int im = 0; im < 2; ++im)
#pragma unroll
        for (int r = 0; r < 4; ++r) {
            int c = r0 + 16 * im + r;
            float inv = LDs<F32>(rg, c) * rsqrtf(LDs<F32>(rv, c) + 1e-5f);
            inv8[im][r] = inv;
            sh8[im][r]  = LDs<F32>(rb, c) - LDs<F32>(rm, c) * inv;
        }
#pragma unroll
    for (int jn = 0; jn < 2; ++jn) {
        int n = nb + 16 * jn;
        int b = n >> 12, l = n & 4095;
        int hh = l >> 6, w = l & 63;
        float xh = 0.5f * hh - 0.25f; int jh = (int)floorf(xh); float fh = xh - jh;
        float xw = 0.5f * w - 0.25f;  int jw = (int)floorf(xw); float fw = xw - jw;
        int h0 = jh < 0 ? 0 : jh, h1 = jh + 1 > 31 ? 31 : jh + 1;
        int w0 = jw < 0 ? 0 : jw, w1 = jw + 1 > 31 ? 31 : jw + 1;
        float w00 = (1.f - fh) * (1.f - fw), w01 = (1.f - fh) * fw;
        float w10 = fh * (1.f - fw),         w11 = fh * fw;
        const u16* spb = sp16 + (size_t)b * 1024 * 256;
#pragma unroll
        for (int im = 0; im < 2; ++im) {
            int cb = r0 + 16 * im;
            u16x4 s00 = *reinterpret_cast<const u16x4*>(spb + (size_t)(h0 * 32 + w0) * 256 + cb);
            u16x4 s01 = *reinterpret_cast<const u16x4*>(spb + (size_t)(h0 * 32 + w1) * 256 + cb);
            u16x4 s10 = *reinterpret_cast<const u16x4*>(spb + (size_t)(h1 * 32 + w0) * 256 + cb);
            u16x4 s11 = *reinterpret_cast<const u16x4*>(spb + (size_t)(h1 * 32 + w1) * 256 + cb);
#pragma unroll
            for (int r = 0; r < 4; ++r) {
                int c = cb + r;
                float rr = LDs<F32>(resnet, ((size_t)b * 256 + c) * 4096 + l);
                float sp = w00 * b2f(s00[r]) + w01 * b2f(s01[r])
                         + w10 * b2f(s10[r]) + w11 * b2f(s11[r]);
                float val = acc[im][jn][r] + rr * inv8[im][r] + sh8[im][r] + sp;
                size_t oi = ((size_t)b * 256 + c) * 4096 + l;
                if constexpr (F32) ((float*)outp)[oi] = val;
                else               ((u16*)outp)[oi]  = f2b(val);
            }
        }
    }
}
__global__ __launch_bounds__(256) void k_out(const int* flag,
    const u16* Y, const void* opw,
    const void* resnet, const void* rg, const void* rb, const void* rm,
    const void* rv, const u16* sp16, void* outp)
{
    if (*flag) out_body<true>(Y, opw, resnet, rg, rb, rm, rv, sp16, outp);
    else       out_body<false>(Y, opw, resnet, rg, rb, rm, rv, sp16, outp);
}

// ---------------------------------------------------------------------------
extern "C" void kernel_launch(void* const* d_in, const int* in_sizes, int n_in,
                              void* d_out, int out_size, void* d_ws, size_t ws_size,
                              hipStream_t stream)
{
    const void* resnet = d_in[0];
    const void* scp    = d_in[1];
    const void* spw    = d_in[2];
    const void* sg     = d_in[3];
    const void* sb     = d_in[4];
    const void* sm     = d_in[5];
    const void* sv     = d_in[6];
    const void* rg     = d_in[7];
    const void* rb     = d_in[8];
    const void* rm     = d_in[9];
    const void* rv     = d_in[10];
    const void* lg     = d_in[11];
    const void* lb     = d_in[12];
    const void* inw    = d_in[13];
    const void* cw     = d_in[14];
    const void* cb     = d_in[15];
    const void* xpw    = d_in[16];
    const void* dtw    = d_in[17];
    const void* dtb    = d_in[18];
    const void* alog   = d_in[19];
    const void* Dw     = d_in[20];
    const void* opw    = d_in[21];

    // Workspace: fixed 14,422,016 B + NC*69632 B scan state.
    // scpT (2 MB) and resnetT (4 MB) alias the xm region (consumed before
    // k_gemm_in writes xm).
    char* ws = (char*)d_ws;
    int*  flag    = (int*)(ws);
    int*  partial = (int*)(ws + 128);
    u16*  sp16    = (u16*)(ws + 4096);
    u16*  xn      = (u16*)(ws + 1052672);
    u16*  xm      = (u16*)(ws + 5246976);   // becomes yraw / y in place
    u16*  scpT    = (u16*)(ws + 5246976);             // 2 MB, dead after k_scpmm
    u16*  resnetT = (u16*)(ws + 5246976 + (2u<<20));  // 4 MB, dead after k_ln
    u16*  xd16    = (u16*)(ws + 13635584);
    const size_t tail0 = 14422016;

    int NC = 16;
    for (int cand = 128; cand >= 16; cand >>= 1) {
        if (tail0 + (size_t)cand * 69632 <= ws_size) { NC = cand; break; }
    }
    int CL = 4096 / NC;
    u16* cA   = (u16*)(ws + tail0);
    u16* cH   = (u16*)(ws + tail0 + (size_t)NC * 32768);
    u16* halo = (u16*)(ws + tail0 + (size_t)NC * 65536);

    k_detect1<<<dim3(64), 256, 0, stream>>>((const u16*)resnet, partial);
    k_detect2<<<dim3(1), 64, 0, stream>>>(partial, flag);
    // scp [b][512][1024] -> scpT [b][1024][512]
    k_tr<<<dim3(16, 8, 2), 256, 0, stream>>>(flag, scp, scpT, 512, 1024);
    k_scpmm<<<dim3(32, 4), 256, 0, stream>>>(flag, scpT, spw, sg, sb, sm, sv, sp16);
    // resnet [b][256][4096] -> resnetT [b][4096][256]
    k_tr<<<dim3(64, 4, 2), 256, 0, stream>>>(flag, resnet, resnetT, 256, 4096);
    k_ln<<<dim3(4096, 2), 256, 0, stream>>>(flag, resnetT, rg, rb, rm, rv, lg, lb, sp16, xn);
    k_gemm_in<<<dim3(128, 8), 256, 0, stream>>>(flag, xn, inw, xm);
    k_halo<<<dim3(NC, 2), 512, 0, stream>>>(xm, halo, NC, CL);
    k_xproj<<<dim3(128), 256, 0, stream>>>(flag, xm, xpw, cw, cb, xd16);
    k_scan1<<<dim3(NC, 2), 512, 0, stream>>>(flag, xm, halo, xd16, alog, dtw, dtb, cw, cb, cA, cH, NC, CL);
    k_scan2<<<dim3(16, 4, 2), 128, 0, stream>>>(cA, cH, NC);
    k_scan3<<<dim3(NC, 2), 512, 0, stream>>>(flag, xm, halo, xd16, alog, dtw, dtb, cw, cb, Dw, cH, NC, CL);
    k_gate<<<dim3(128, 8), 256, 0, stream>>>(flag, xn, inw, xm);
    k_out<<<dim3(4, 128), 256, 0, stream>>>(flag, xm, opw, resnet, rg, rb, rm, rv, sp16, d_out);
}

// Round 7
// 289.928 us; speedup vs baseline: 3.1124x; 1.1420x over previous
//
#include <hip/hip_runtime.h>
#include <hip/hip_bf16.h>
#include <math.h>

typedef unsigned short u16;
typedef __attribute__((ext_vector_type(8))) short short8;
typedef __attribute__((ext_vector_type(4))) float f32x4;
typedef __attribute__((ext_vector_type(4))) unsigned short u16x4;

#define DEVINL static __device__ __forceinline__

DEVINL float b2f(u16 x) {
    union { unsigned u; float f; } v; v.u = ((unsigned)x) << 16; return v.f;
}
DEVINL u16 f2b(float f) {
    union { unsigned u; float f; } v; v.f = f;
    unsigned u = v.u;
    return (u16)((u + 0x7fffu + ((u >> 16) & 1u)) >> 16);
}
DEVINL float silu(float x) { return x / (1.f + __expf(-x)); }

// dual-mode scalar load: raw input tensors may be f32 or bf16 (runtime-detected)
template<bool F32> DEVINL float LDs(const void* p, size_t i) {
    if constexpr (F32) return ((const float*)p)[i];
    else               return b2f(((const u16*)p)[i]);
}

// --- converted-weights arena: element offsets inside w16 (bf16) ---
#define O_INW  0        /* 1024*256  in_proj (both halves) */
#define O_XPW  262144   /* 48*512 */
#define O_OPW  286720   /* 256*512 */
#define O_SPW  417792   /* 256*512 */
#define O_CW   548864   /* 512*3 */
#define O_CB   550400   /* 512 */
#define O_DTW  550912   /* 512*16 */
#define O_ALOG 559104   /* 512*16 */
#define O_DTB  567296   /* 512 */
#define O_DW   567808   /* 512 */
#define O_SG   568320
#define O_SB   568576
#define O_SM   568832
#define O_SV   569088
#define O_RG   569344
#define O_RB   569600
#define O_RM   569856
#define O_RV   570112
#define O_LG   570368
#define O_LB   570624
#define N_CVT  570880

// ---------------------------------------------------------------------------
// dtype detection: bf16 N(0,1) -> count 0; f32 viewed as bf16 -> many |v|>1e3/NaN.
// ---------------------------------------------------------------------------
__global__ __launch_bounds__(256) void k_detect1(const u16* __restrict__ raw,
                                                 int* __restrict__ partial)
{
    int tid = threadIdx.x, bid = blockIdx.x;
    int cnt = 0;
    for (size_t i = (size_t)bid * 256 + tid; i < 2097152; i += 64 * 256) {
        float v = b2f(raw[i]);
        if (!(fabsf(v) <= 1e3f)) cnt++;
    }
#pragma unroll
    for (int off = 1; off < 64; off <<= 1) cnt += __shfl_xor(cnt, off);
    __shared__ int s4[4];
    if ((tid & 63) == 0) s4[tid >> 6] = cnt;
    __syncthreads();
    if (tid == 0) partial[bid] = s4[0] + s4[1] + s4[2] + s4[3];
}

__global__ __launch_bounds__(64) void k_detect2(const int* __restrict__ partial,
                                                int* __restrict__ flag)
{
    int c = partial[threadIdx.x];
#pragma unroll
    for (int off = 1; off < 64; off <<= 1) c += __shfl_xor(c, off);
    if (threadIdx.x == 0) flag[0] = (c > 0) ? 1 : 0;
}

// ---------------------------------------------------------------------------
// k_cvt: convert all weights/params to one packed bf16 arena (once per call).
// ---------------------------------------------------------------------------
__global__ __launch_bounds__(256) void k_cvt(const int* __restrict__ flag,
    const void* inw, const void* xpw, const void* opw, const void* spw,
    const void* cw, const void* cb, const void* dtw, const void* alog,
    const void* dtb, const void* Dw,
    const void* sg, const void* sb, const void* sm, const void* sv,
    const void* rg, const void* rb, const void* rm, const void* rv,
    const void* lg, const void* lb,
    u16* __restrict__ dst)
{
    int i = blockIdx.x * 256 + threadIdx.x;
    if (i >= N_CVT) return;
    const void* src; int off = i;
    if      (i < O_XPW)  { src = inw; }
    else if (i < O_OPW)  { src = xpw;  off = i - O_XPW; }
    else if (i < O_SPW)  { src = opw;  off = i - O_OPW; }
    else if (i < O_CW)   { src = spw;  off = i - O_SPW; }
    else if (i < O_CB)   { src = cw;   off = i - O_CW; }
    else if (i < O_DTW)  { src = cb;   off = i - O_CB; }
    else if (i < O_ALOG) { src = dtw;  off = i - O_DTW; }
    else if (i < O_DTB)  { src = alog; off = i - O_ALOG; }
    else if (i < O_DW)   { src = dtb;  off = i - O_DTB; }
    else if (i < O_SG)   { src = Dw;   off = i - O_DW; }
    else if (i < O_SB)   { src = sg;   off = i - O_SG; }
    else if (i < O_SM)   { src = sb;   off = i - O_SB; }
    else if (i < O_SV)   { src = sm;   off = i - O_SM; }
    else if (i < O_RG)   { src = sv;   off = i - O_SV; }
    else if (i < O_RB)   { src = rg;   off = i - O_RG; }
    else if (i < O_RM)   { src = rb;   off = i - O_RB; }
    else if (i < O_RV)   { src = rm;   off = i - O_RM; }
    else if (i < O_LG)   { src = rv;   off = i - O_RV; }
    else if (i < O_LB)   { src = lg;   off = i - O_LG; }
    else                 { src = lb;   off = i - O_LB; }
    float v = (*flag) ? ((const float*)src)[off] : b2f(((const u16*)src)[off]);
    dst[i] = f2b(v);
}

// ---------------------------------------------------------------------------
// k_tr: LDS-tiled transpose src[b][R][C] -> dst[b][C][R] (dst bf16).
// ---------------------------------------------------------------------------
template<bool F32> DEVINL void tr_body(const void* src, u16* dst, int R, int C)
{
    __shared__ u16 t[64][66];
    int tid = threadIdx.x;
    int c0 = blockIdx.x * 64, r0 = blockIdx.y * 64, b = blockIdx.z;
    int lane = tid & 63, grp = tid >> 6;
#pragma unroll
    for (int j = 0; j < 16; ++j) {
        int rl = j * 4 + grp;
        t[rl][lane] = f2b(LDs<F32>(src, ((size_t)b * R + r0 + rl) * C + c0 + lane));
    }
    __syncthreads();
#pragma unroll
    for (int j = 0; j < 16; ++j) {
        int cl = j * 4 + grp;
        dst[((size_t)b * C + c0 + cl) * R + r0 + lane] = t[lane][cl];
    }
}
__global__ __launch_bounds__(256) void k_tr(const int* flag,
    const void* src, u16* dst, int R, int C)
{
    if (*flag) tr_body<true>(src, dst, R, C);
    else       tr_body<false>(src, dst, R, C);
}

// ---------------------------------------------------------------------------
// k_scpmm: sp16[p][o] = BN(sum_c scpT[p][c] * spw[o][c]). All bf16 now.
// M=2048, N=256, K=512. grid (32, 4), block 256 (4 waves 2x2).
// ---------------------------------------------------------------------------
__global__ __launch_bounds__(256) void k_scpmm(
    const u16* __restrict__ scpT, const u16* __restrict__ w16,
    u16* __restrict__ sp16)
{
    const int N = 256, K = 512;
    int tid = threadIdx.x, lane = tid & 63, wid = tid >> 6;
    int ln = lane & 15, q = lane >> 4;
    int m0 = blockIdx.x * 64 + (wid & 1) * 32;
    int n0 = blockIdx.y * 64 + (wid >> 1) * 32;
    f32x4 acc00 = {0.f,0.f,0.f,0.f}, acc01 = acc00, acc10 = acc00, acc11 = acc00;
    const u16* Ap0 = scpT + (size_t)(m0 + ln) * K + q * 8;
    const u16* Ap1 = Ap0 + (size_t)16 * K;
    const u16* Wp = w16 + O_SPW;
#pragma unroll 4
    for (int k0 = 0; k0 < K; k0 += 32) {
        int kk = k0 + q * 8;
        short8 a0 = *reinterpret_cast<const short8*>(Ap0 + k0);
        short8 a1 = *reinterpret_cast<const short8*>(Ap1 + k0);
        short8 b0 = *reinterpret_cast<const short8*>(Wp + (size_t)(n0 + ln) * K + kk);
        short8 b1 = *reinterpret_cast<const short8*>(Wp + (size_t)(n0 + ln + 16) * K + kk);
        acc00 = __builtin_amdgcn_mfma_f32_16x16x32_bf16(a0, b0, acc00, 0, 0, 0);
        acc01 = __builtin_amdgcn_mfma_f32_16x16x32_bf16(a0, b1, acc01, 0, 0, 0);
        acc10 = __builtin_amdgcn_mfma_f32_16x16x32_bf16(a1, b0, acc10, 0, 0, 0);
        acc11 = __builtin_amdgcn_mfma_f32_16x16x32_bf16(a1, b1, acc11, 0, 0, 0);
    }
    int r0 = m0 + q * 4, c0 = n0 + ln;
    float inv0 = b2f(w16[O_SG + c0]) * rsqrtf(b2f(w16[O_SV + c0]) + 1e-5f);
    float sh0  = b2f(w16[O_SB + c0]) - b2f(w16[O_SM + c0]) * inv0;
    float inv1 = b2f(w16[O_SG + c0 + 16]) * rsqrtf(b2f(w16[O_SV + c0 + 16]) + 1e-5f);
    float sh1  = b2f(w16[O_SB + c0 + 16]) - b2f(w16[O_SM + c0 + 16]) * inv1;
#pragma unroll
    for (int r = 0; r < 4; ++r) {
        sp16[(size_t)(r0 + r) * N + c0]           = f2b(acc00[r] * inv0 + sh0);
        sp16[(size_t)(r0 + r) * N + c0 + 16]      = f2b(acc01[r] * inv1 + sh1);
        sp16[(size_t)(r0 + 16 + r) * N + c0]      = f2b(acc10[r] * inv0 + sh0);
        sp16[(size_t)(r0 + 16 + r) * N + c0 + 16] = f2b(acc11[r] * inv1 + sh1);
    }
}

// ---------------------------------------------------------------------------
// K1: res-BN (from resnetT) + bilinear + add -> LN -> xn. All bf16.
// grid (L=4096, B), block 256 (thread = channel).
// ---------------------------------------------------------------------------
__global__ __launch_bounds__(256) void k_ln(
    const u16* __restrict__ resnetT, const u16* __restrict__ w16,
    const u16* __restrict__ sp16, u16* __restrict__ xn)
{
    int c = threadIdx.x, l = blockIdx.x, b = blockIdx.y;
    int h = l >> 6, w = l & 63;
    float rr  = b2f(resnetT[((size_t)b * 4096 + l) * 256 + c]);
    float inv = b2f(w16[O_RG + c]) * rsqrtf(b2f(w16[O_RV + c]) + 1e-5f);
    float rn  = rr * inv + (b2f(w16[O_RB + c]) - b2f(w16[O_RM + c]) * inv);

    float xh = 0.5f * h - 0.25f; int jh = (int)floorf(xh); float fh = xh - jh;
    float xw = 0.5f * w - 0.25f; int jw = (int)floorf(xw); float fw = xw - jw;
    int h0 = jh < 0 ? 0 : jh, h1 = jh + 1 > 31 ? 31 : jh + 1;
    int w0 = jw < 0 ? 0 : jw, w1 = jw + 1 > 31 ? 31 : jw + 1;
    const u16* spb = sp16 + (size_t)b * 1024 * 256 + c;
    float v00 = b2f(spb[(size_t)(h0 * 32 + w0) * 256]), v01 = b2f(spb[(size_t)(h0 * 32 + w1) * 256]);
    float v10 = b2f(spb[(size_t)(h1 * 32 + w0) * 256]), v11 = b2f(spb[(size_t)(h1 * 32 + w1) * 256]);
    float sp = (1.f - fh) * ((1.f - fw) * v00 + fw * v01)
             + fh * ((1.f - fw) * v10 + fw * v11);
    float fv = rn + sp;

    __shared__ float red[8];
    float s = fv, s2 = fv * fv;
#pragma unroll
    for (int off = 1; off < 64; off <<= 1) {
        s  += __shfl_xor(s, off);
        s2 += __shfl_xor(s2, off);
    }
    int wv = c >> 6;
    if ((c & 63) == 0) { red[wv] = s; red[4 + wv] = s2; }
    __syncthreads();
    float S  = red[0] + red[1] + red[2] + red[3];
    float S2 = red[4] + red[5] + red[6] + red[7];
    float mu   = S * (1.f / 256.f);
    float var  = S2 * (1.f / 256.f) - mu * mu;
    float rstd = rsqrtf(var + 1e-5f);
    float xnv  = (fv - mu) * rstd * b2f(w16[O_LG + c]) + b2f(w16[O_LB + c]);
    xn[((size_t)b * 4096 + l) * 256 + c] = f2b(xnv);
}

// ---------------------------------------------------------------------------
// in_proj GEMM, BOTH halves: xz[row][n] n in [0,1024). M=8192, K=256.
// grid (128, 16), block 256.
// ---------------------------------------------------------------------------
__global__ __launch_bounds__(256) void k_gemm_in(
    const u16* __restrict__ A, const u16* __restrict__ w16, u16* __restrict__ Out)
{
    const int N = 1024, K = 256;
    int tid = threadIdx.x, lane = tid & 63, wid = tid >> 6;
    int ln = lane & 15, q = lane >> 4;
    int m0 = blockIdx.x * 64 + (wid & 1) * 32;
    int n0 = blockIdx.y * 64 + (wid >> 1) * 32;
    f32x4 acc00 = {0.f,0.f,0.f,0.f}, acc01 = acc00, acc10 = acc00, acc11 = acc00;
    const u16* Ap0 = A + (size_t)(m0 + ln) * K + q * 8;
    const u16* Ap1 = Ap0 + (size_t)16 * K;
    const u16* Wp = w16 + O_INW;
#pragma unroll 4
    for (int k0 = 0; k0 < K; k0 += 32) {
        int kk = k0 + q * 8;
        short8 a0 = *reinterpret_cast<const short8*>(Ap0 + k0);
        short8 a1 = *reinterpret_cast<const short8*>(Ap1 + k0);
        short8 b0 = *reinterpret_cast<const short8*>(Wp + (size_t)(n0 + ln) * K + kk);
        short8 b1 = *reinterpret_cast<const short8*>(Wp + (size_t)(n0 + ln + 16) * K + kk);
        acc00 = __builtin_amdgcn_mfma_f32_16x16x32_bf16(a0, b0, acc00, 0, 0, 0);
        acc01 = __builtin_amdgcn_mfma_f32_16x16x32_bf16(a0, b1, acc01, 0, 0, 0);
        acc10 = __builtin_amdgcn_mfma_f32_16x16x32_bf16(a1, b0, acc10, 0, 0, 0);
        acc11 = __builtin_amdgcn_mfma_f32_16x16x32_bf16(a1, b1, acc11, 0, 0, 0);
    }
    int r0 = m0 + q * 4, c0 = n0 + ln;
#pragma unroll
    for (int r = 0; r < 4; ++r) {
        Out[(size_t)(r0 + r) * N + c0]           = f2b(acc00[r]);
        Out[(size_t)(r0 + r) * N + c0 + 16]      = f2b(acc01[r]);
        Out[(size_t)(r0 + 16 + r) * N + c0]      = f2b(acc10[r]);
        Out[(size_t)(r0 + 16 + r) * N + c0 + 16] = f2b(acc11[r]);
    }
}

// ---------------------------------------------------------------------------
// k_conv: u[l][d] = silu(causal conv3 over xm = xz[:, 0:512]). Sliding window.
// grid (256, B), block 512 (thread = d); each block 16 rows.
// ---------------------------------------------------------------------------
__global__ __launch_bounds__(512) void k_conv(
    const u16* __restrict__ xz, const u16* __restrict__ w16, u16* __restrict__ u)
{
    int d = threadIdx.x, rt = blockIdx.x, b = blockIdx.y;
    int l0 = rt * 16;
    float c0 = b2f(w16[O_CW + d * 3]), c1 = b2f(w16[O_CW + d * 3 + 1]),
          c2 = b2f(w16[O_CW + d * 3 + 2]), cbv = b2f(w16[O_CB + d]);
    size_t base = ((size_t)b * 4096 + l0) * 1024 + d;
    float x2 = (l0 >= 2) ? b2f(xz[base - 2048]) : 0.f;
    float x1 = (l0 >= 1) ? b2f(xz[base - 1024]) : 0.f;
#pragma unroll 4
    for (int il = 0; il < 16; ++il) {
        float x0 = b2f(xz[base + (size_t)il * 1024]);
        float uv = silu(cbv + c0 * x2 + c1 * x1 + c2 * x0);
        u[((size_t)b * 4096 + l0 + il) * 512 + d] = f2b(uv);
        x2 = x1; x1 = x0;
    }
}

// ---------------------------------------------------------------------------
// x_proj GEMM: xd16[row][n] (bf16), N=48, K=512, A = u rows (direct).
// grid (128), block 256: 4 waves x 16-row tiles.
// ---------------------------------------------------------------------------
__global__ __launch_bounds__(256) void k_xproj(
    const u16* __restrict__ u, const u16* __restrict__ w16, u16* __restrict__ xd16)
{
    int tid = threadIdx.x, lane = tid & 63, wid = tid >> 6;
    int ln = lane & 15, q = lane >> 4;
    int m0 = blockIdx.x * 64 + wid * 16;
    const u16* Wp = w16 + O_XPW;
    f32x4 acc[3];
#pragma unroll
    for (int j = 0; j < 3; ++j) acc[j] = {0.f,0.f,0.f,0.f};
#pragma unroll 4
    for (int k0 = 0; k0 < 512; k0 += 32) {
        int kk0 = k0 + q * 8;
        short8 a0 = *reinterpret_cast<const short8*>(u + (size_t)(m0 + ln) * 512 + kk0);
#pragma unroll
        for (int j = 0; j < 3; ++j) {
            short8 bj = *reinterpret_cast<const short8*>(Wp + (size_t)(16 * j + ln) * 512 + kk0);
            acc[j] = __builtin_amdgcn_mfma_f32_16x16x32_bf16(a0, bj, acc[j], 0, 0, 0);
        }
    }
#pragma unroll
    for (int j = 0; j < 3; ++j)
#pragma unroll
        for (int r = 0; r < 4; ++r)
            xd16[(size_t)(m0 + q * 4 + r) * 48 + 16 * j + ln] = f2b(acc[j][r]);
}

// dt = softplus(dot(xd[0:16] (f32, LDS), wdt) + bias)
DEVINL float dt_of(const float* xd, const float* wdt, float bias) {
    float acc = bias;
#pragma unroll
    for (int r = 0; r < 16; ++r) acc += xd[r] * wdt[r];
    return acc > 15.f ? acc : __logf(1.f + __expf(acc));
}

// ---------------------------------------------------------------------------
// scan1: per-chunk local scan. grid (NC, B), block 512. -> cA, cH bf16
// ---------------------------------------------------------------------------
__global__ __launch_bounds__(512) void k_scan1(
    const u16* __restrict__ u, const u16* __restrict__ xd16,
    const u16* __restrict__ w16, u16* __restrict__ cA, u16* __restrict__ cH,
    int NC, int CL)
{
    __shared__ float xds[32][48];
    int d = threadIdx.x, ck = blockIdx.x, b = blockIdx.y;
    float wdt[16], a[16], h[16], ap[16];
#pragma unroll
    for (int s = 0; s < 16; ++s) {
        wdt[s] = b2f(w16[O_DTW + d * 16 + s]);
        a[s] = -__expf(b2f(w16[O_ALOG + d * 16 + s]));
        h[s] = 0.f; ap[s] = 1.f;
    }
    float bias = b2f(w16[O_DTB + d]);
    int l0 = ck * CL;
    for (int t0 = 0; t0 < CL; t0 += 32) {
        __syncthreads();
#pragma unroll
        for (int k = 0; k < 3; ++k) {
            int idx = k * 512 + d;
            int r = idx / 48, c = idx - r * 48;
            xds[r][c] = b2f(xd16[((size_t)b * 4096 + l0 + t0 + r) * 48 + c]);
        }
        __syncthreads();
        for (int il = 0; il < 32; ++il) {
            size_t row = (size_t)b * 4096 + l0 + t0 + il;
            float uv = b2f(u[row * 512 + d]);
            const float* xd = xds[il];
            float dtv = dt_of(xd, wdt, bias);
            float du = dtv * uv;
#pragma unroll
            for (int s = 0; s < 16; ++s) {
                float dA = __expf(dtv * a[s]);
                h[s]  = dA * h[s] + du * xd[16 + s];
                ap[s] *= dA;
            }
        }
    }
    size_t base = (((size_t)b * NC + ck) * 16) * 512 + d;
#pragma unroll
    for (int s = 0; s < 16; ++s) {
        cA[base + (size_t)s * 512] = f2b(ap[s]);
        cH[base + (size_t)s * 512] = f2b(h[s]);
    }
}

// ---------------------------------------------------------------------------
// scan2: cross-chunk recurrence; cH[ck] := h_in(ck). grid (16, 4, B), block 128.
// ---------------------------------------------------------------------------
__global__ __launch_bounds__(128) void k_scan2(const u16* __restrict__ cA,
                                               u16* __restrict__ cH, int NC)
{
    int d = blockIdx.y * 128 + threadIdx.x, s = blockIdx.x, b = blockIdx.z;
    float h = 0.f;
#pragma unroll 4
    for (int ck = 0; ck < NC; ++ck) {
        size_t idx = (((size_t)b * NC + ck) * 16 + s) * 512 + d;
        float aP = b2f(cA[idx]), hE = b2f(cH[idx]);
        cH[idx] = f2b(h);
        h = aP * h + hE;
    }
}

// ---------------------------------------------------------------------------
// scan3: replay chunk from h_in; y = (h.C + u*D) * silu(z). grid (NC, B), blk 512.
// ---------------------------------------------------------------------------
__global__ __launch_bounds__(512) void k_scan3(
    const u16* __restrict__ u, const u16* __restrict__ xz,
    const u16* __restrict__ xd16, const u16* __restrict__ w16,
    const u16* __restrict__ cH, u16* __restrict__ y, int NC, int CL)
{
    __shared__ float xds[32][48];
    int d = threadIdx.x, ck = blockIdx.x, b = blockIdx.y;
    float wdt[16], a[16], h[16];
    size_t base = (((size_t)b * NC + ck) * 16) * 512 + d;
#pragma unroll
    for (int s = 0; s < 16; ++s) {
        wdt[s] = b2f(w16[O_DTW + d * 16 + s]);
        a[s] = -__expf(b2f(w16[O_ALOG + d * 16 + s]));
        h[s] = b2f(cH[base + (size_t)s * 512]);
    }
    float bias = b2f(w16[O_DTB + d]);
    float Dv = b2f(w16[O_DW + d]);
    int l0 = ck * CL;
    for (int t0 = 0; t0 < CL; t0 += 32) {
        __syncthreads();
#pragma unroll
        for (int k = 0; k < 3; ++k) {
            int idx = k * 512 + d;
            int r = idx / 48, c = idx - r * 48;
            xds[r][c] = b2f(xd16[((size_t)b * 4096 + l0 + t0 + r) * 48 + c]);
        }
        __syncthreads();
        for (int il = 0; il < 32; ++il) {
            size_t row = (size_t)b * 4096 + l0 + t0 + il;
            float uv = b2f(u[row * 512 + d]);
            const float* xd = xds[il];
            float dtv = dt_of(xd, wdt, bias);
            float du = dtv * uv;
            float yv = 0.f;
#pragma unroll
            for (int s = 0; s < 16; ++s) {
                float dA = __expf(dtv * a[s]);
                h[s] = dA * h[s] + du * xd[16 + s];
                yv += h[s] * xd[32 + s];
            }
            yv += uv * Dv;
            float zv = b2f(xz[row * 1024 + 512 + d]);
            yv *= silu(zv);
            y[row * 512 + d] = f2b(yv);
        }
    }
}

// ---------------------------------------------------------------------------
// out_proj GEMM (m = channel, n = sequence) + fused-recompute epilogue.
// grid (4, 128), block 256.
// ---------------------------------------------------------------------------
template<bool F32> DEVINL void out_body(
    const u16* Y, const u16* w16, const void* resnet,
    const u16* sp16, void* outp)
{
    const int K = 512;
    int tid = threadIdx.x, lane = tid & 63, wid = tid >> 6;
    int ln = lane & 15, q = lane >> 4;
    int m0 = blockIdx.x * 64 + (wid & 1) * 32;   // channel dim (256)
    int n0 = blockIdx.y * 64 + (wid >> 1) * 32;  // sequence dim (8192)
    f32x4 acc[2][2];
    acc[0][0] = {0.f,0.f,0.f,0.f}; acc[0][1] = acc[0][0];
    acc[1][0] = acc[0][0]; acc[1][1] = acc[0][0];
    const u16* Bp0 = Y + (size_t)(n0 + ln) * K + q * 8;
    const u16* Bp1 = Bp0 + (size_t)16 * K;
    const u16* Wp = w16 + O_OPW;
#pragma unroll 4
    for (int k0 = 0; k0 < K; k0 += 32) {
        int kk = k0 + q * 8;
        short8 b0 = *reinterpret_cast<const short8*>(Bp0 + k0);
        short8 b1 = *reinterpret_cast<const short8*>(Bp1 + k0);
        short8 a0 = *reinterpret_cast<const short8*>(Wp + (size_t)(m0 + ln) * K + kk);
        short8 a1 = *reinterpret_cast<const short8*>(Wp + (size_t)(m0 + ln + 16) * K + kk);
        acc[0][0] = __builtin_amdgcn_mfma_f32_16x16x32_bf16(a0, b0, acc[0][0], 0, 0, 0);
        acc[0][1] = __builtin_amdgcn_mfma_f32_16x16x32_bf16(a0, b1, acc[0][1], 0, 0, 0);
        acc[1][0] = __builtin_amdgcn_mfma_f32_16x16x32_bf16(a1, b0, acc[1][0], 0, 0, 0);
        acc[1][1] = __builtin_amdgcn_mfma_f32_16x16x32_bf16(a1, b1, acc[1][1], 0, 0, 0);
    }
    int r0 = m0 + q * 4;
    int nb = n0 + ln;
    float inv8[2][4], sh8[2][4];
#pragma unroll
    for (int im = 0; im < 2; ++im)
#pragma unroll
        for (int r = 0; r < 4; ++r) {
            int c = r0 + 16 * im + r;
            float inv = b2f(w16[O_RG + c]) * rsqrtf(b2f(w16[O_RV + c]) + 1e-5f);
            inv8[im][r] = inv;
            sh8[im][r]  = b2f(w16[O_RB + c]) - b2f(w16[O_RM + c]) * inv;
        }
#pragma unroll
    for (int jn = 0; jn < 2; ++jn) {
        int n = nb + 16 * jn;
        int b = n >> 12, l = n & 4095;
        int hh = l >> 6, w = l & 63;
        float xh = 0.5f * hh - 0.25f; int jh = (int)floorf(xh); float fh = xh - jh;
        float xw = 0.5f * w - 0.25f;  int jw = (int)floorf(xw); float fw = xw - jw;
        int h0 = jh < 0 ? 0 : jh, h1 = jh + 1 > 31 ? 31 : jh + 1;
        int w0 = jw < 0 ? 0 : jw, w1 = jw + 1 > 31 ? 31 : jw + 1;
        float w00 = (1.f - fh) * (1.f - fw), w01 = (1.f - fh) * fw;
        float w10 = fh * (1.f - fw),         w11 = fh * fw;
        const u16* spb = sp16 + (size_t)b * 1024 * 256;
#pragma unroll
        for (int im = 0; im < 2; ++im) {
            int cb = r0 + 16 * im;
            u16x4 s00 = *reinterpret_cast<const u16x4*>(spb + (size_t)(h0 * 32 + w0) * 256 + cb);
            u16x4 s01 = *reinterpret_cast<const u16x4*>(spb + (size_t)(h0 * 32 + w1) * 256 + cb);
            u16x4 s10 = *reinterpret_cast<const u16x4*>(spb + (size_t)(h1 * 32 + w0) * 256 + cb);
            u16x4 s11 = *reinterpret_cast<const u16x4*>(spb + (size_t)(h1 * 32 + w1) * 256 + cb);
#pragma unroll
            for (int r = 0; r < 4; ++r) {
                int c = cb + r;
                float rr = LDs<F32>(resnet, ((size_t)b * 256 + c) * 4096 + l);
                float sp = w00 * b2f(s00[r]) + w01 * b2f(s01[r])
                         + w10 * b2f(s10[r]) + w11 * b2f(s11[r]);
                float val = acc[im][jn][r] + rr * inv8[im][r] + sh8[im][r] + sp;
                size_t oi = ((size_t)b * 256 + c) * 4096 + l;
                if constexpr (F32) ((float*)outp)[oi] = val;
                else               ((u16*)outp)[oi]  = f2b(val);
            }
        }
    }
}
__global__ __launch_bounds__(256) void k_out(const int* flag,
    const u16* Y, const u16* w16, const void* resnet,
    const u16* sp16, void* outp)
{
    if (*flag) out_body<true>(Y, w16, resnet, sp16, outp);
    else       out_body<false>(Y, w16, resnet, sp16, outp);
}

// ---------------------------------------------------------------------------
extern "C" void kernel_launch(void* const* d_in, const int* in_sizes, int n_in,
                              void* d_out, int out_size, void* d_ws, size_t ws_size,
                              hipStream_t stream)
{
    const void* resnet = d_in[0];
    const void* scp    = d_in[1];
    const void* spw    = d_in[2];
    const void* sg     = d_in[3];
    const void* sb     = d_in[4];
    const void* sm     = d_in[5];
    const void* sv     = d_in[6];
    const void* rg     = d_in[7];
    const void* rb     = d_in[8];
    const void* rm     = d_in[9];
    const void* rv     = d_in[10];
    const void* lg     = d_in[11];
    const void* lb     = d_in[12];
    const void* inw    = d_in[13];
    const void* cw     = d_in[14];
    const void* cb     = d_in[15];
    const void* xpw    = d_in[16];
    const void* dtw    = d_in[17];
    const void* dtb    = d_in[18];
    const void* alog   = d_in[19];
    const void* Dw     = d_in[20];
    const void* opw    = d_in[21];

    // Workspace layout (ws_size measured at 256 MiB via fill counter; total ~56 MB)
    char* ws = (char*)d_ws;
    int*  flag    = (int*)(ws);
    int*  partial = (int*)(ws + 128);
    u16*  w16     = (u16*)(ws + 4096);        // N_CVT bf16 elts (~1.09 MB)
    u16*  sp16    = (u16*)(ws + 1310720);     // 1 MB   [b][p][256]
    u16*  scpT    = (u16*)(ws + 2359296);     // 2 MB   [b][1024][512]
    u16*  resnetT = (u16*)(ws + 4456448);     // 4 MB   [b][4096][256]
    u16*  xn      = (u16*)(ws + 8650752);     // 4 MB   [b][l][256]
    u16*  xz      = (u16*)(ws + 12845056);    // 16 MB  [b][l][1024] (xm | z)
    u16*  u       = (u16*)(ws + 29622272);    // 8 MB   [b][l][512]
    u16*  y       = (u16*)(ws + 38011008);    // 8 MB   [b][l][512]
    u16*  xd16    = (u16*)(ws + 46399488);    // 0.75 MB [b][l][48]
    const size_t tail0 = 47185920;

    int NC = 16;
    for (int cand = 128; cand >= 16; cand >>= 1) {
        if (tail0 + (size_t)cand * 65536 <= ws_size) { NC = cand; break; }
    }
    int CL = 4096 / NC;
    u16* cA = (u16*)(ws + tail0);
    u16* cH = (u16*)(ws + tail0 + (size_t)NC * 32768);

    k_detect1<<<dim3(64), 256, 0, stream>>>((const u16*)resnet, partial);
    k_detect2<<<dim3(1), 64, 0, stream>>>(partial, flag);
    k_cvt<<<dim3((N_CVT + 255) / 256), 256, 0, stream>>>(flag,
        inw, xpw, opw, spw, cw, cb, dtw, alog, dtb, Dw,
        sg, sb, sm, sv, rg, rb, rm, rv, lg, lb, w16);
    k_tr<<<dim3(16, 8, 2), 256, 0, stream>>>(flag, scp, scpT, 512, 1024);
    k_scpmm<<<dim3(32, 4), 256, 0, stream>>>(scpT, w16, sp16);
    k_tr<<<dim3(64, 4, 2), 256, 0, stream>>>(flag, resnet, resnetT, 256, 4096);
    k_ln<<<dim3(4096, 2), 256, 0, stream>>>(resnetT, w16, sp16, xn);
    k_gemm_in<<<dim3(128, 16), 256, 0, stream>>>(xn, w16, xz);
    k_conv<<<dim3(256, 2), 512, 0, stream>>>(xz, w16, u);
    k_xproj<<<dim3(128), 256, 0, stream>>>(u, w16, xd16);
    k_scan1<<<dim3(NC, 2), 512, 0, stream>>>(u, xd16, w16, cA, cH, NC, CL);
    k_scan2<<<dim3(16, 4, 2), 128, 0, stream>>>(cA, cH, NC);
    k_scan3<<<dim3(NC, 2), 512, 0, stream>>>(u, xz, xd16, w16, cH, y, NC, CL);
    k_out<<<dim3(4, 128), 256, 0, stream>>>(flag, y, w16, resnet, sp16, d_out);
}

// Round 8
// 281.578 us; speedup vs baseline: 3.2047x; 1.0297x over previous
//
#include <hip/hip_runtime.h>
#include <hip/hip_bf16.h>
#include <math.h>

typedef unsigned short u16;
typedef __attribute__((ext_vector_type(8))) short short8;
typedef __attribute__((ext_vector_type(4))) float f32x4;
typedef __attribute__((ext_vector_type(4))) unsigned short u16x4;

#define DEVINL static __device__ __forceinline__

DEVINL float b2f(u16 x) {
    union { unsigned u; float f; } v; v.u = ((unsigned)x) << 16; return v.f;
}
DEVINL u16 f2b(float f) {
    union { unsigned u; float f; } v; v.f = f;
    unsigned u = v.u;
    return (u16)((u + 0x7fffu + ((u >> 16) & 1u)) >> 16);
}
DEVINL float silu(float x) { return x / (1.f + __expf(-x)); }
DEVINL float ld_any(bool f32, const void* p, size_t i) {
    return f32 ? ((const float*)p)[i] : b2f(((const u16*)p)[i]);
}
template<bool F32> DEVINL float LDs(const void* p, size_t i) {
    if constexpr (F32) return ((const float*)p)[i];
    else               return b2f(((const u16*)p)[i]);
}

// --- converted-weights arena: element offsets inside w16 (bf16) ---
#define O_INW  0        /* 1024*256 */
#define O_XPW  262144   /* 48*512 */
#define O_OPW  286720   /* 256*512 */
#define O_SPW  417792   /* 256*512 */
#define O_CW   548864   /* 512*3 */
#define O_CB   550400   /* 512 */
#define O_DTW  550912   /* 512*16 */
#define O_ALOG 559104   /* 512*16 */
#define O_DTB  567296   /* 512 */
#define O_DW   567808   /* 512 */
#define O_SG   568320
#define O_SB   568576
#define O_SM   568832
#define O_SV   569088
#define O_RG   569344
#define O_RB   569600
#define O_RM   569856
#define O_RV   570112
#define O_LG   570368
#define O_LB   570624
#define N_CVT  570880

// ---------------------------------------------------------------------------
// k_detect: single block; samples first 131072 u16 of resnet viewed as bf16.
// bf16 N(0,1) -> 0 triggers; f32 -> low-half u16s trigger ~46%.
// ---------------------------------------------------------------------------
__global__ __launch_bounds__(1024) void k_detect(const u16* __restrict__ raw,
                                                 int* __restrict__ flag)
{
    int tid = threadIdx.x;
    int cnt = 0;
    for (int i = tid; i < 131072; i += 1024) {
        float v = b2f(raw[i]);
        if (!(fabsf(v) <= 1e3f)) cnt++;
    }
#pragma unroll
    for (int off = 1; off < 64; off <<= 1) cnt += __shfl_xor(cnt, off);
    __shared__ int s16[16];
    if ((tid & 63) == 0) s16[tid >> 6] = cnt;
    __syncthreads();
    if (tid == 0) {
        int c = 0;
#pragma unroll
        for (int w = 0; w < 16; ++w) c += s16[w];
        flag[0] = (c > 0) ? 1 : 0;
    }
}

// ---------------------------------------------------------------------------
// k_prep: one kernel = weight/param cvt (blocks 0..2229) + scp transpose
// (blocks 2230..2485) + resnet transpose (blocks 2486..2997).
// ---------------------------------------------------------------------------
DEVINL void tr_tile(bool f32, const void* src, u16* dst, int R, int C,
                    int c0, int r0, int b, int tid)
{
    __shared__ u16 t[64][66];
    int lane = tid & 63, grp = tid >> 6;
#pragma unroll
    for (int j = 0; j < 16; ++j) {
        int rl = j * 4 + grp;
        t[rl][lane] = f2b(ld_any(f32, src, ((size_t)b * R + r0 + rl) * C + c0 + lane));
    }
    __syncthreads();
#pragma unroll
    for (int j = 0; j < 16; ++j) {
        int cl = j * 4 + grp;
        dst[((size_t)b * C + c0 + cl) * R + r0 + lane] = t[lane][cl];
    }
}

__global__ __launch_bounds__(256) void k_prep(const int* __restrict__ flag,
    const void* inw, const void* xpw, const void* opw, const void* spw,
    const void* cw, const void* cb, const void* dtw, const void* alog,
    const void* dtb, const void* Dw,
    const void* sg, const void* sb, const void* sm, const void* sv,
    const void* rg, const void* rb, const void* rm, const void* rv,
    const void* lg, const void* lb,
    const void* scp, const void* resnet,
    u16* __restrict__ w16, u16* __restrict__ scpT, u16* __restrict__ resnetT)
{
    bool f32 = (*flag != 0);
    int bid = blockIdx.x, tid = threadIdx.x;
    if (bid < 2230) {
        int i = bid * 256 + tid;             // i < 570880 = N_CVT exactly
        const void* src; int off = i;
        if      (i < O_XPW)  { src = inw; }
        else if (i < O_OPW)  { src = xpw;  off = i - O_XPW; }
        else if (i < O_SPW)  { src = opw;  off = i - O_OPW; }
        else if (i < O_CW)   { src = spw;  off = i - O_SPW; }
        else if (i < O_CB)   { src = cw;   off = i - O_CW; }
        else if (i < O_DTW)  { src = cb;   off = i - O_CB; }
        else if (i < O_ALOG) { src = dtw;  off = i - O_DTW; }
        else if (i < O_DTB)  { src = alog; off = i - O_ALOG; }
        else if (i < O_DW)   { src = dtb;  off = i - O_DTB; }
        else if (i < O_SG)   { src = Dw;   off = i - O_DW; }
        else if (i < O_SB)   { src = sg;   off = i - O_SG; }
        else if (i < O_SM)   { src = sb;   off = i - O_SB; }
        else if (i < O_SV)   { src = sm;   off = i - O_SM; }
        else if (i < O_RG)   { src = sv;   off = i - O_SV; }
        else if (i < O_RB)   { src = rg;   off = i - O_RG; }
        else if (i < O_RM)   { src = rb;   off = i - O_RB; }
        else if (i < O_RV)   { src = rm;   off = i - O_RM; }
        else if (i < O_LG)   { src = rv;   off = i - O_RV; }
        else if (i < O_LB)   { src = lg;   off = i - O_LG; }
        else                 { src = lb;   off = i - O_LB; }
        w16[i] = f2b(ld_any(f32, src, off));
    } else if (bid < 2230 + 256) {
        int t = bid - 2230;                  // scp: R=512, C=1024
        tr_tile(f32, scp, scpT, 512, 1024, (t & 15) * 64, ((t >> 4) & 7) * 64, t >> 7, tid);
    } else {
        int t = bid - 2486;                  // resnet: R=256, C=4096
        tr_tile(f32, resnet, resnetT, 256, 4096, (t & 63) * 64, ((t >> 6) & 3) * 64, t >> 8, tid);
    }
}

// ---------------------------------------------------------------------------
// k_scpmm: sp16[p][o] = BN(sum_c scpT[p][c] * spw[o][c]). MFMA, all bf16.
// M=2048, N=256, K=512. grid (32, 4), block 256 (4 waves 2x2).
// ---------------------------------------------------------------------------
__global__ __launch_bounds__(256) void k_scpmm(
    const u16* __restrict__ scpT, const u16* __restrict__ w16,
    u16* __restrict__ sp16)
{
    const int N = 256, K = 512;
    int tid = threadIdx.x, lane = tid & 63, wid = tid >> 6;
    int ln = lane & 15, q = lane >> 4;
    int m0 = blockIdx.x * 64 + (wid & 1) * 32;
    int n0 = blockIdx.y * 64 + (wid >> 1) * 32;
    f32x4 acc00 = {0.f,0.f,0.f,0.f}, acc01 = acc00, acc10 = acc00, acc11 = acc00;
    const u16* Ap0 = scpT + (size_t)(m0 + ln) * K + q * 8;
    const u16* Ap1 = Ap0 + (size_t)16 * K;
    const u16* Wp = w16 + O_SPW;
#pragma unroll 4
    for (int k0 = 0; k0 < K; k0 += 32) {
        int kk = k0 + q * 8;
        short8 a0 = *reinterpret_cast<const short8*>(Ap0 + k0);
        short8 a1 = *reinterpret_cast<const short8*>(Ap1 + k0);
        short8 b0 = *reinterpret_cast<const short8*>(Wp + (size_t)(n0 + ln) * K + kk);
        short8 b1 = *reinterpret_cast<const short8*>(Wp + (size_t)(n0 + ln + 16) * K + kk);
        acc00 = __builtin_amdgcn_mfma_f32_16x16x32_bf16(a0, b0, acc00, 0, 0, 0);
        acc01 = __builtin_amdgcn_mfma_f32_16x16x32_bf16(a0, b1, acc01, 0, 0, 0);
        acc10 = __builtin_amdgcn_mfma_f32_16x16x32_bf16(a1, b0, acc10, 0, 0, 0);
        acc11 = __builtin_amdgcn_mfma_f32_16x16x32_bf16(a1, b1, acc11, 0, 0, 0);
    }
    int r0 = m0 + q * 4, c0 = n0 + ln;
    float inv0 = b2f(w16[O_SG + c0]) * rsqrtf(b2f(w16[O_SV + c0]) + 1e-5f);
    float sh0  = b2f(w16[O_SB + c0]) - b2f(w16[O_SM + c0]) * inv0;
    float inv1 = b2f(w16[O_SG + c0 + 16]) * rsqrtf(b2f(w16[O_SV + c0 + 16]) + 1e-5f);
    float sh1  = b2f(w16[O_SB + c0 + 16]) - b2f(w16[O_SM + c0 + 16]) * inv1;
#pragma unroll
    for (int r = 0; r < 4; ++r) {
        sp16[(size_t)(r0 + r) * N + c0]           = f2b(acc00[r] * inv0 + sh0);
        sp16[(size_t)(r0 + r) * N + c0 + 16]      = f2b(acc01[r] * inv1 + sh1);
        sp16[(size_t)(r0 + 16 + r) * N + c0]      = f2b(acc10[r] * inv0 + sh0);
        sp16[(size_t)(r0 + 16 + r) * N + c0 + 16] = f2b(acc11[r] * inv1 + sh1);
    }
}

// ---------------------------------------------------------------------------
// k_ln: res-BN + bilinear + add -> LayerNorm -> xn. 8 rows per block.
// grid (512, B), block 256 (thread = channel).
// ---------------------------------------------------------------------------
__global__ __launch_bounds__(256) void k_ln(
    const u16* __restrict__ resnetT, const u16* __restrict__ w16,
    const u16* __restrict__ sp16, u16* __restrict__ xn)
{
    __shared__ float red[8];
    int c = threadIdx.x, b = blockIdx.y;
    float inv = b2f(w16[O_RG + c]) * rsqrtf(b2f(w16[O_RV + c]) + 1e-5f);
    float sh  = b2f(w16[O_RB + c]) - b2f(w16[O_RM + c]) * inv;
    float lgv = b2f(w16[O_LG + c]), lbv = b2f(w16[O_LB + c]);
    const u16* spc = sp16 + (size_t)b * 1024 * 256 + c;
    for (int j = 0; j < 8; ++j) {
        int l = blockIdx.x * 8 + j;
        int h = l >> 6, w = l & 63;
        float rr = b2f(resnetT[((size_t)b * 4096 + l) * 256 + c]);
        float rn = rr * inv + sh;
        float xh = 0.5f * h - 0.25f; int jh = (int)floorf(xh); float fh = xh - jh;
        float xw = 0.5f * w - 0.25f; int jw = (int)floorf(xw); float fw = xw - jw;
        int h0 = jh < 0 ? 0 : jh, h1 = jh + 1 > 31 ? 31 : jh + 1;
        int w0 = jw < 0 ? 0 : jw, w1 = jw + 1 > 31 ? 31 : jw + 1;
        float v00 = b2f(spc[(size_t)(h0 * 32 + w0) * 256]), v01 = b2f(spc[(size_t)(h0 * 32 + w1) * 256]);
        float v10 = b2f(spc[(size_t)(h1 * 32 + w0) * 256]), v11 = b2f(spc[(size_t)(h1 * 32 + w1) * 256]);
        float sp = (1.f - fh) * ((1.f - fw) * v00 + fw * v01)
                 + fh * ((1.f - fw) * v10 + fw * v11);
        float fv = rn + sp;

        float s = fv, s2 = fv * fv;
#pragma unroll
        for (int off = 1; off < 64; off <<= 1) {
            s  += __shfl_xor(s, off);
            s2 += __shfl_xor(s2, off);
        }
        int wv = c >> 6;
        if ((c & 63) == 0) { red[wv] = s; red[4 + wv] = s2; }
        __syncthreads();
        float S  = red[0] + red[1] + red[2] + red[3];
        float S2 = red[4] + red[5] + red[6] + red[7];
        __syncthreads();
        float mu   = S * (1.f / 256.f);
        float var  = S2 * (1.f / 256.f) - mu * mu;
        float rstd = rsqrtf(var + 1e-5f);
        xn[((size_t)b * 4096 + l) * 256 + c] = f2b((fv - mu) * rstd * lgv + lbv);
    }
}

// ---------------------------------------------------------------------------
// in_proj GEMM, both halves: xz[row][n], n in [0,1024). M=8192, K=256.
// grid (128, 16), block 256.
// ---------------------------------------------------------------------------
__global__ __launch_bounds__(256) void k_gemm_in(
    const u16* __restrict__ A, const u16* __restrict__ w16, u16* __restrict__ Out)
{
    const int N = 1024, K = 256;
    int tid = threadIdx.x, lane = tid & 63, wid = tid >> 6;
    int ln = lane & 15, q = lane >> 4;
    int m0 = blockIdx.x * 64 + (wid & 1) * 32;
    int n0 = blockIdx.y * 64 + (wid >> 1) * 32;
    f32x4 acc00 = {0.f,0.f,0.f,0.f}, acc01 = acc00, acc10 = acc00, acc11 = acc00;
    const u16* Ap0 = A + (size_t)(m0 + ln) * K + q * 8;
    const u16* Ap1 = Ap0 + (size_t)16 * K;
    const u16* Wp = w16 + O_INW;
#pragma unroll 4
    for (int k0 = 0; k0 < K; k0 += 32) {
        int kk = k0 + q * 8;
        short8 a0 = *reinterpret_cast<const short8*>(Ap0 + k0);
        short8 a1 = *reinterpret_cast<const short8*>(Ap1 + k0);
        short8 b0 = *reinterpret_cast<const short8*>(Wp + (size_t)(n0 + ln) * K + kk);
        short8 b1 = *reinterpret_cast<const short8*>(Wp + (size_t)(n0 + ln + 16) * K + kk);
        acc00 = __builtin_amdgcn_mfma_f32_16x16x32_bf16(a0, b0, acc00, 0, 0, 0);
        acc01 = __builtin_amdgcn_mfma_f32_16x16x32_bf16(a0, b1, acc01, 0, 0, 0);
        acc10 = __builtin_amdgcn_mfma_f32_16x16x32_bf16(a1, b0, acc10, 0, 0, 0);
        acc11 = __builtin_amdgcn_mfma_f32_16x16x32_bf16(a1, b1, acc11, 0, 0, 0);
    }
    int r0 = m0 + q * 4, c0 = n0 + ln;
#pragma unroll
    for (int r = 0; r < 4; ++r) {
        Out[(size_t)(r0 + r) * N + c0]           = f2b(acc00[r]);
        Out[(size_t)(r0 + r) * N + c0 + 16]      = f2b(acc01[r]);
        Out[(size_t)(r0 + 16 + r) * N + c0]      = f2b(acc10[r]);
        Out[(size_t)(r0 + 16 + r) * N + c0 + 16] = f2b(acc11[r]);
    }
}

// ---------------------------------------------------------------------------
// on-the-fly u fragment: u[row][kk0..kk0+8) = silu(causal conv3 of xm half of xz)
// ---------------------------------------------------------------------------
DEVINL short8 u_frag(const u16* __restrict__ xz, const u16* __restrict__ w16,
                     int row, int kk0)
{
    int l = row & 4095;
    const u16* p = xz + (size_t)row * 1024 + kk0;
    short8 zz = {0,0,0,0,0,0,0,0};
    short8 x0 = *reinterpret_cast<const short8*>(p);
    short8 x1 = (l >= 1) ? *reinterpret_cast<const short8*>(p - 1024) : zz;
    short8 x2 = (l >= 2) ? *reinterpret_cast<const short8*>(p - 2048) : zz;
    short8 r;
#pragma unroll
    for (int j = 0; j < 8; ++j) {
        int d = kk0 + j;
        float acc = b2f(w16[O_CB + d])
                  + b2f((u16)x2[j]) * b2f(w16[O_CW + d * 3])
                  + b2f((u16)x1[j]) * b2f(w16[O_CW + d * 3 + 1])
                  + b2f((u16)x0[j]) * b2f(w16[O_CW + d * 3 + 2]);
        r[j] = (short)f2b(silu(acc));
    }
    return r;
}

// ---------------------------------------------------------------------------
// x_proj GEMM, conv-on-the-fly A: xdf[row][n] f32, N=48, K=512.
// grid (128), block 256: 4 waves x 16-row tiles.
// ---------------------------------------------------------------------------
__global__ __launch_bounds__(256) void k_xproj(
    const u16* __restrict__ xz, const u16* __restrict__ w16, float* __restrict__ xdf)
{
    int tid = threadIdx.x, lane = tid & 63, wid = tid >> 6;
    int ln = lane & 15, q = lane >> 4;
    int m0 = blockIdx.x * 64 + wid * 16;
    const u16* Wp = w16 + O_XPW;
    f32x4 acc[3];
#pragma unroll
    for (int j = 0; j < 3; ++j) acc[j] = {0.f,0.f,0.f,0.f};
    for (int k0 = 0; k0 < 512; k0 += 32) {
        int kk0 = k0 + q * 8;
        short8 a0 = u_frag(xz, w16, m0 + ln, kk0);
#pragma unroll
        for (int j = 0; j < 3; ++j) {
            short8 bj = *reinterpret_cast<const short8*>(Wp + (size_t)(16 * j + ln) * 512 + kk0);
            acc[j] = __builtin_amdgcn_mfma_f32_16x16x32_bf16(a0, bj, acc[j], 0, 0, 0);
        }
    }
#pragma unroll
    for (int j = 0; j < 3; ++j)
#pragma unroll
        for (int r = 0; r < 4; ++r)
            xdf[(size_t)(m0 + q * 4 + r) * 48 + 16 * j + ln] = acc[j][r];
}

// dt = softplus(dot(xd[0:16], wdt) + bias)
DEVINL float dt_of(const float* xd, const float* wdt, float bias) {
    float acc = bias;
#pragma unroll
    for (int r = 0; r < 16; ++r) acc += xd[r] * wdt[r];
    return acc > 15.f ? acc : __logf(1.f + __expf(acc));
}

// ---------------------------------------------------------------------------
// scan1: per-chunk local scan, conv-on-the-fly. grid (NC, B), block 512.
// ---------------------------------------------------------------------------
__global__ __launch_bounds__(512) void k_scan1(
    const u16* __restrict__ xz, const float* __restrict__ xdf,
    const u16* __restrict__ w16, u16* __restrict__ cA, u16* __restrict__ cH,
    int NC, int CL)
{
    __shared__ float xds[32][48];
    int d = threadIdx.x, ck = blockIdx.x, b = blockIdx.y;
    float wdt[16], a[16], h[16], ap[16];
#pragma unroll
    for (int s = 0; s < 16; ++s) {
        wdt[s] = b2f(w16[O_DTW + d * 16 + s]);
        a[s] = -__expf(b2f(w16[O_ALOG + d * 16 + s]));
        h[s] = 0.f; ap[s] = 1.f;
    }
    float bias = b2f(w16[O_DTB + d]);
    float cw0 = b2f(w16[O_CW + d * 3]), cw1 = b2f(w16[O_CW + d * 3 + 1]),
          cw2 = b2f(w16[O_CW + d * 3 + 2]), cbv = b2f(w16[O_CB + d]);
    int l0 = ck * CL;
    size_t xbase = ((size_t)b * 4096 + l0) * 1024 + d;
    float x2 = (l0 >= 2) ? b2f(xz[xbase - 2048]) : 0.f;
    float x1 = (l0 >= 1) ? b2f(xz[xbase - 1024]) : 0.f;
    for (int t0 = 0; t0 < CL; t0 += 32) {
        __syncthreads();
#pragma unroll
        for (int k = 0; k < 3; ++k) {
            int idx = k * 512 + d;
            int r = idx / 48, c = idx - r * 48;
            xds[r][c] = xdf[((size_t)b * 4096 + l0 + t0 + r) * 48 + c];
        }
        __syncthreads();
        for (int il = 0; il < 32; ++il) {
            float x0 = b2f(xz[xbase + (size_t)(t0 + il) * 1024]);
            float uv = silu(cbv + cw0 * x2 + cw1 * x1 + cw2 * x0);
            const float* xd = xds[il];
            float dtv = dt_of(xd, wdt, bias);
            float du = dtv * uv;
#pragma unroll
            for (int s = 0; s < 16; ++s) {
                float dA = __expf(dtv * a[s]);
                h[s]  = dA * h[s] + du * xd[16 + s];
                ap[s] *= dA;
            }
            x2 = x1; x1 = x0;
        }
    }
    size_t base = (((size_t)b * NC + ck) * 16) * 512 + d;
#pragma unroll
    for (int s = 0; s < 16; ++s) {
        cA[base + (size_t)s * 512] = f2b(ap[s]);
        cH[base + (size_t)s * 512] = f2b(h[s]);
    }
}

// ---------------------------------------------------------------------------
// scan2: cross-chunk recurrence; cH[ck] := h_in(ck). grid (16, 4, B), block 128.
// ---------------------------------------------------------------------------
__global__ __launch_bounds__(128) void k_scan2(const u16* __restrict__ cA,
                                               u16* __restrict__ cH, int NC)
{
    int d = blockIdx.y * 128 + threadIdx.x, s = blockIdx.x, b = blockIdx.z;
    float h = 0.f;
#pragma unroll 4
    for (int ck = 0; ck < NC; ++ck) {
        size_t idx = (((size_t)b * NC + ck) * 16 + s) * 512 + d;
        float aP = b2f(cA[idx]), hE = b2f(cH[idx]);
        cH[idx] = f2b(h);
        h = aP * h + hE;
    }
}

// ---------------------------------------------------------------------------
// scan3: replay from h_in, conv-on-the-fly; y = (h.C + u*D) * silu(z).
// grid (NC, B), block 512.
// ---------------------------------------------------------------------------
__global__ __launch_bounds__(512) void k_scan3(
    const u16* __restrict__ xz, const float* __restrict__ xdf,
    const u16* __restrict__ w16, const u16* __restrict__ cH,
    u16* __restrict__ y, int NC, int CL)
{
    __shared__ float xds[32][48];
    int d = threadIdx.x, ck = blockIdx.x, b = blockIdx.y;
    float wdt[16], a[16], h[16];
    size_t base = (((size_t)b * NC + ck) * 16) * 512 + d;
#pragma unroll
    for (int s = 0; s < 16; ++s) {
        wdt[s] = b2f(w16[O_DTW + d * 16 + s]);
        a[s] = -__expf(b2f(w16[O_ALOG + d * 16 + s]));
        h[s] = b2f(cH[base + (size_t)s * 512]);
    }
    float bias = b2f(w16[O_DTB + d]);
    float Dv = b2f(w16[O_DW + d]);
    float cw0 = b2f(w16[O_CW + d * 3]), cw1 = b2f(w16[O_CW + d * 3 + 1]),
          cw2 = b2f(w16[O_CW + d * 3 + 2]), cbv = b2f(w16[O_CB + d]);
    int l0 = ck * CL;
    size_t xbase = ((size_t)b * 4096 + l0) * 1024 + d;
    float x2 = (l0 >= 2) ? b2f(xz[xbase - 2048]) : 0.f;
    float x1 = (l0 >= 1) ? b2f(xz[xbase - 1024]) : 0.f;
    for (int t0 = 0; t0 < CL; t0 += 32) {
        __syncthreads();
#pragma unroll
        for (int k = 0; k < 3; ++k) {
            int idx = k * 512 + d;
            int r = idx / 48, c = idx - r * 48;
            xds[r][c] = xdf[((size_t)b * 4096 + l0 + t0 + r) * 48 + c];
        }
        __syncthreads();
        for (int il = 0; il < 32; ++il) {
            size_t row = (size_t)b * 4096 + l0 + t0 + il;
            float x0 = b2f(xz[xbase + (size_t)(t0 + il) * 1024]);
            float uv = silu(cbv + cw0 * x2 + cw1 * x1 + cw2 * x0);
            const float* xd = xds[il];
            float dtv = dt_of(xd, wdt, bias);
            float du = dtv * uv;
            float yv = 0.f;
#pragma unroll
            for (int s = 0; s < 16; ++s) {
                float dA = __expf(dtv * a[s]);
                h[s] = dA * h[s] + du * xd[16 + s];
                yv += h[s] * xd[32 + s];
            }
            yv += uv * Dv;
            float zv = b2f(xz[row * 1024 + 512 + d]);
            yv *= silu(zv);
            y[row * 512 + d] = f2b(yv);
            x2 = x1; x1 = x0;
        }
    }
}

// ---------------------------------------------------------------------------
// out_proj GEMM (m = channel, n = sequence) + fused-recompute epilogue.
// grid (4, 128), block 256.
// ---------------------------------------------------------------------------
template<bool F32> DEVINL void out_body(
    const u16* Y, const u16* w16, const void* resnet,
    const u16* sp16, void* outp)
{
    const int K = 512;
    int tid = threadIdx.x, lane = tid & 63, wid = tid >> 6;
    int ln = lane & 15, q = lane >> 4;
    int m0 = blockIdx.x * 64 + (wid & 1) * 32;   // channel dim (256)
    int n0 = blockIdx.y * 64 + (wid >> 1) * 32;  // sequence dim (8192)
    f32x4 acc[2][2];
    acc[0][0] = {0.f,0.f,0.f,0.f}; acc[0][1] = acc[0][0];
    acc[1][0] = acc[0][0]; acc[1][1] = acc[0][0];
    const u16* Bp0 = Y + (size_t)(n0 + ln) * K + q * 8;
    const u16* Bp1 = Bp0 + (size_t)16 * K;
    const u16* Wp = w16 + O_OPW;
#pragma unroll 4
    for (int k0 = 0; k0 < K; k0 += 32) {
        int kk = k0 + q * 8;
        short8 b0 = *reinterpret_cast<const short8*>(Bp0 + k0);
        short8 b1 = *reinterpret_cast<const short8*>(Bp1 + k0);
        short8 a0 = *reinterpret_cast<const short8*>(Wp + (size_t)(m0 + ln) * K + kk);
        short8 a1 = *reinterpret_cast<const short8*>(Wp + (size_t)(m0 + ln + 16) * K + kk);
        acc[0][0] = __builtin_amdgcn_mfma_f32_16x16x32_bf16(a0, b0, acc[0][0], 0, 0, 0);
        acc[0][1] = __builtin_amdgcn_mfma_f32_16x16x32_bf16(a0, b1, acc[0][1], 0, 0, 0);
        acc[1][0] = __builtin_amdgcn_mfma_f32_16x16x32_bf16(a1, b0, acc[1][0], 0, 0, 0);
        acc[1][1] = __builtin_amdgcn_mfma_f32_16x16x32_bf16(a1, b1, acc[1][1], 0, 0, 0);
    }
    int r0 = m0 + q * 4;
    int nb = n0 + ln;
    float inv8[2][4], sh8[2][4];
#pragma unroll
    for (int im = 0; im < 2; ++im)
#pragma unroll
        for (int r = 0; r < 4; ++r) {
            int c = r0 + 16 * im + r;
            float inv = b2f(w16[O_RG + c]) * rsqrtf(b2f(w16[O_RV + c]) + 1e-5f);
            inv8[im][r] = inv;
            sh8[im][r]  = b2f(w16[O_RB + c]) - b2f(w16[O_RM + c]) * inv;
        }
#pragma unroll
    for (int jn = 0; jn < 2; ++jn) {
        int n = nb + 16 * jn;
        int b = n >> 12, l = n & 4095;
        int hh = l >> 6, w = l & 63;
        float xh = 0.5f * hh - 0.25f; int jh = (int)floorf(xh); float fh = xh - jh;
        float xw = 0.5f * w - 0.25f;  int jw = (int)floorf(xw); float fw = xw - jw;
        int h0 = jh < 0 ? 0 : jh, h1 = jh + 1 > 31 ? 31 : jh + 1;
        int w0 = jw < 0 ? 0 : jw, w1 = jw + 1 > 31 ? 31 : jw + 1;
        float w00 = (1.f - fh) * (1.f - fw), w01 = (1.f - fh) * fw;
        float w10 = fh * (1.f - fw),         w11 = fh * fw;
        const u16* spb = sp16 + (size_t)b * 1024 * 256;
#pragma unroll
        for (int im = 0; im < 2; ++im) {
            int cb = r0 + 16 * im;
            u16x4 s00 = *reinterpret_cast<const u16x4*>(spb + (size_t)(h0 * 32 + w0) * 256 + cb);
            u16x4 s01 = *reinterpret_cast<const u16x4*>(spb + (size_t)(h0 * 32 + w1) * 256 + cb);
            u16x4 s10 = *reinterpret_cast<const u16x4*>(spb + (size_t)(h1 * 32 + w0) * 256 + cb);
            u16x4 s11 = *reinterpret_cast<const u16x4*>(spb + (size_t)(h1 * 32 + w1) * 256 + cb);
#pragma unroll
            for (int r = 0; r < 4; ++r) {
                int c = cb + r;
                float rr = LDs<F32>(resnet, ((size_t)b * 256 + c) * 4096 + l);
                float sp = w00 * b2f(s00[r]) + w01 * b2f(s01[r])
                         + w10 * b2f(s10[r]) + w11 * b2f(s11[r]);
                float val = acc[im][jn][r] + rr * inv8[im][r] + sh8[im][r] + sp;
                size_t oi = ((size_t)b * 256 + c) * 4096 + l;
                if constexpr (F32) ((float*)outp)[oi] = val;
                else               ((u16*)outp)[oi]  = f2b(val);
            }
        }
    }
}
__global__ __launch_bounds__(256) void k_out(const int* flag,
    const u16* Y, const u16* w16, const void* resnet,
    const u16* sp16, void* outp)
{
    if (*flag) out_body<true>(Y, w16, resnet, sp16, outp);
    else       out_body<false>(Y, w16, resnet, sp16, outp);
}

// ---------------------------------------------------------------------------
extern "C" void kernel_launch(void* const* d_in, const int* in_sizes, int n_in,
                              void* d_out, int out_size, void* d_ws, size_t ws_size,
                              hipStream_t stream)
{
    const void* resnet = d_in[0];
    const void* scp    = d_in[1];
    const void* spw    = d_in[2];
    const void* sg     = d_in[3];
    const void* sb     = d_in[4];
    const void* sm     = d_in[5];
    const void* sv     = d_in[6];
    const void* rg     = d_in[7];
    const void* rb     = d_in[8];
    const void* rm     = d_in[9];
    const void* rv     = d_in[10];
    const void* lg     = d_in[11];
    const void* lb     = d_in[12];
    const void* inw    = d_in[13];
    const void* cw     = d_in[14];
    const void* cb     = d_in[15];
    const void* xpw    = d_in[16];
    const void* dtw    = d_in[17];
    const void* dtb    = d_in[18];
    const void* alog   = d_in[19];
    const void* Dw     = d_in[20];
    const void* opw    = d_in[21];

    // Workspace layout (~52 MB of the 256 MiB ws)
    char*  ws      = (char*)d_ws;
    int*   flag    = (int*)(ws);
    u16*   w16     = (u16*)(ws + 4096);         // 1.09 MB arena
    u16*   sp16    = (u16*)(ws + 2097152);      // 1 MB
    u16*   scpT    = (u16*)(ws + 4194304);      // 2 MB
    u16*   resnetT = (u16*)(ws + 8388608);      // 4 MB
    u16*   xn      = (u16*)(ws + 12582912);     // 4 MB
    u16*   xz      = (u16*)(ws + 16777216);     // 16 MB [b][l][1024] (xm | z)
    float* xdf     = (float*)(ws + 33554432);   // 1.5 MB f32 [b][l][48]
    u16*   y       = (u16*)(ws + 35651584);     // 8 MB
    const size_t tail0 = 44040192;

    int NC = 16;
    for (int cand = 128; cand >= 16; cand >>= 1) {
        if (tail0 + (size_t)cand * 65536 <= ws_size) { NC = cand; break; }
    }
    int CL = 4096 / NC;
    u16* cA = (u16*)(ws + tail0);
    u16* cH = (u16*)(ws + tail0 + (size_t)NC * 32768);

    k_detect<<<dim3(1), 1024, 0, stream>>>((const u16*)resnet, flag);
    k_prep<<<dim3(2998), 256, 0, stream>>>(flag,
        inw, xpw, opw, spw, cw, cb, dtw, alog, dtb, Dw,
        sg, sb, sm, sv, rg, rb, rm, rv, lg, lb,
        scp, resnet, w16, scpT, resnetT);
    k_scpmm<<<dim3(32, 4), 256, 0, stream>>>(scpT, w16, sp16);
    k_ln<<<dim3(512, 2), 256, 0, stream>>>(resnetT, w16, sp16, xn);
    k_gemm_in<<<dim3(128, 16), 256, 0, stream>>>(xn, w16, xz);
    k_xproj<<<dim3(128), 256, 0, stream>>>(xz, w16, xdf);
    k_scan1<<<dim3(NC, 2), 512, 0, stream>>>(xz, xdf, w16, cA, cH, NC, CL);
    k_scan2<<<dim3(16, 4, 2), 128, 0, stream>>>(cA, cH, NC);
    k_scan3<<<dim3(NC, 2), 512, 0, stream>>>(xz, xdf, w16, cH, y, NC, CL);
    k_out<<<dim3(4, 128), 256, 0, stream>>>(flag, y, w16, resnet, sp16, d_out);
}

// Round 9
// 267.080 us; speedup vs baseline: 3.3787x; 1.0543x over previous
//
#include <hip/hip_runtime.h>
#include <hip/hip_bf16.h>
#include <math.h>

typedef unsigned short u16;
typedef __attribute__((ext_vector_type(8))) short short8;
typedef __attribute__((ext_vector_type(4))) float f32x4;
typedef __attribute__((ext_vector_type(4))) unsigned short u16x4;

#define DEVINL static __device__ __forceinline__

DEVINL float b2f(u16 x) {
    union { unsigned u; float f; } v; v.u = ((unsigned)x) << 16; return v.f;
}
DEVINL u16 f2b(float f) {
    union { unsigned u; float f; } v; v.f = f;
    unsigned u = v.u;
    return (u16)((u + 0x7fffu + ((u >> 16) & 1u)) >> 16);
}
DEVINL float silu(float x) { return x / (1.f + __expf(-x)); }
DEVINL float ld_any(bool f32, const void* p, size_t i) {
    return f32 ? ((const float*)p)[i] : b2f(((const u16*)p)[i]);
}
template<bool F32> DEVINL float LDs(const void* p, size_t i) {
    if constexpr (F32) return ((const float*)p)[i];
    else               return b2f(((const u16*)p)[i]);
}

// Inline dtype detect: sample the 64 EVEN u16s of resnet. If input is f32,
// even u16s are mantissa-low halves -> ~46% trigger each (P[none] ~ 4e-18);
// if bf16, they are genuine N(0,1) values -> 0 triggers. Uniform across blocks.
DEVINL bool detect_f32(const u16* __restrict__ raw) {
    int cnt = 0;
#pragma unroll
    for (int i = 0; i < 64; ++i) {
        float v = b2f(raw[i * 2]);
        if (!(fabsf(v) <= 1e3f)) cnt++;
    }
    return cnt > 0;
}

// --- converted-weights arena: element offsets inside w16 (bf16) ---
#define O_INW  0        /* 1024*256 */
#define O_XPW  262144   /* 48*512 */
#define O_OPW  286720   /* 256*512 */
#define O_SPW  417792   /* 256*512 */
#define O_CW   548864   /* 512*3 */
#define O_CB   550400   /* 512 */
#define O_DTW  550912   /* 512*16 */
#define O_ALOG 559104   /* 512*16 */
#define O_DTB  567296   /* 512 */
#define O_DW   567808   /* 512 */
#define O_SG   568320
#define O_SB   568576
#define O_SM   568832
#define O_SV   569088
#define O_RG   569344
#define O_RB   569600
#define O_RM   569856
#define O_RV   570112
#define O_LG   570368
#define O_LB   570624
#define N_CVT  570880

// ---------------------------------------------------------------------------
// k_prep: weight/param cvt (blocks 0..2229) + scp transpose (2230..2485)
// + resnet transpose (2486..2997). Self-detects dtype.
// ---------------------------------------------------------------------------
DEVINL void tr_tile(bool f32, const void* src, u16* dst, int R, int C,
                    int c0, int r0, int b, int tid)
{
    __shared__ u16 t[64][66];
    int lane = tid & 63, grp = tid >> 6;
#pragma unroll
    for (int j = 0; j < 16; ++j) {
        int rl = j * 4 + grp;
        t[rl][lane] = f2b(ld_any(f32, src, ((size_t)b * R + r0 + rl) * C + c0 + lane));
    }
    __syncthreads();
#pragma unroll
    for (int j = 0; j < 16; ++j) {
        int cl = j * 4 + grp;
        dst[((size_t)b * C + c0 + cl) * R + r0 + lane] = t[lane][cl];
    }
}

__global__ __launch_bounds__(256) void k_prep(
    const void* inw, const void* xpw, const void* opw, const void* spw,
    const void* cw, const void* cb, const void* dtw, const void* alog,
    const void* dtb, const void* Dw,
    const void* sg, const void* sb, const void* sm, const void* sv,
    const void* rg, const void* rb, const void* rm, const void* rv,
    const void* lg, const void* lb,
    const void* scp, const void* resnet,
    u16* __restrict__ w16, u16* __restrict__ scpT, u16* __restrict__ resnetT)
{
    bool f32 = detect_f32((const u16*)resnet);
    int bid = blockIdx.x, tid = threadIdx.x;
    if (bid < 2230) {
        int i = bid * 256 + tid;             // i < 570880 = N_CVT exactly
        const void* src; int off = i;
        if      (i < O_XPW)  { src = inw; }
        else if (i < O_OPW)  { src = xpw;  off = i - O_XPW; }
        else if (i < O_SPW)  { src = opw;  off = i - O_OPW; }
        else if (i < O_CW)   { src = spw;  off = i - O_SPW; }
        else if (i < O_CB)   { src = cw;   off = i - O_CW; }
        else if (i < O_DTW)  { src = cb;   off = i - O_CB; }
        else if (i < O_ALOG) { src = dtw;  off = i - O_DTW; }
        else if (i < O_DTB)  { src = alog; off = i - O_ALOG; }
        else if (i < O_DW)   { src = dtb;  off = i - O_DTB; }
        else if (i < O_SG)   { src = Dw;   off = i - O_DW; }
        else if (i < O_SB)   { src = sg;   off = i - O_SG; }
        else if (i < O_SM)   { src = sb;   off = i - O_SB; }
        else if (i < O_SV)   { src = sm;   off = i - O_SM; }
        else if (i < O_RG)   { src = sv;   off = i - O_SV; }
        else if (i < O_RB)   { src = rg;   off = i - O_RG; }
        else if (i < O_RM)   { src = rb;   off = i - O_RB; }
        else if (i < O_RV)   { src = rm;   off = i - O_RM; }
        else if (i < O_LG)   { src = rv;   off = i - O_RV; }
        else if (i < O_LB)   { src = lg;   off = i - O_LG; }
        else                 { src = lb;   off = i - O_LB; }
        w16[i] = f2b(ld_any(f32, src, off));
    } else if (bid < 2230 + 256) {
        int t = bid - 2230;                  // scp: R=512, C=1024
        tr_tile(f32, scp, scpT, 512, 1024, (t & 15) * 64, ((t >> 4) & 7) * 64, t >> 7, tid);
    } else {
        int t = bid - 2486;                  // resnet: R=256, C=4096
        tr_tile(f32, resnet, resnetT, 256, 4096, (t & 63) * 64, ((t >> 6) & 3) * 64, t >> 8, tid);
    }
}

// ---------------------------------------------------------------------------
// k_scpmm: sp16[p][o] = BN(sum_c scpT[p][c] * spw[o][c]). MFMA, all bf16.
// M=2048, N=256, K=512. grid (32, 4), block 256 (4 waves 2x2).
// ---------------------------------------------------------------------------
__global__ __launch_bounds__(256) void k_scpmm(
    const u16* __restrict__ scpT, const u16* __restrict__ w16,
    u16* __restrict__ sp16)
{
    const int N = 256, K = 512;
    int tid = threadIdx.x, lane = tid & 63, wid = tid >> 6;
    int ln = lane & 15, q = lane >> 4;
    int m0 = blockIdx.x * 64 + (wid & 1) * 32;
    int n0 = blockIdx.y * 64 + (wid >> 1) * 32;
    f32x4 acc00 = {0.f,0.f,0.f,0.f}, acc01 = acc00, acc10 = acc00, acc11 = acc00;
    const u16* Ap0 = scpT + (size_t)(m0 + ln) * K + q * 8;
    const u16* Ap1 = Ap0 + (size_t)16 * K;
    const u16* Wp = w16 + O_SPW;
#pragma unroll 4
    for (int k0 = 0; k0 < K; k0 += 32) {
        int kk = k0 + q * 8;
        short8 a0 = *reinterpret_cast<const short8*>(Ap0 + k0);
        short8 a1 = *reinterpret_cast<const short8*>(Ap1 + k0);
        short8 b0 = *reinterpret_cast<const short8*>(Wp + (size_t)(n0 + ln) * K + kk);
        short8 b1 = *reinterpret_cast<const short8*>(Wp + (size_t)(n0 + ln + 16) * K + kk);
        acc00 = __builtin_amdgcn_mfma_f32_16x16x32_bf16(a0, b0, acc00, 0, 0, 0);
        acc01 = __builtin_amdgcn_mfma_f32_16x16x32_bf16(a0, b1, acc01, 0, 0, 0);
        acc10 = __builtin_amdgcn_mfma_f32_16x16x32_bf16(a1, b0, acc10, 0, 0, 0);
        acc11 = __builtin_amdgcn_mfma_f32_16x16x32_bf16(a1, b1, acc11, 0, 0, 0);
    }
    int r0 = m0 + q * 4, c0 = n0 + ln;
    float inv0 = b2f(w16[O_SG + c0]) * rsqrtf(b2f(w16[O_SV + c0]) + 1e-5f);
    float sh0  = b2f(w16[O_SB + c0]) - b2f(w16[O_SM + c0]) * inv0;
    float inv1 = b2f(w16[O_SG + c0 + 16]) * rsqrtf(b2f(w16[O_SV + c0 + 16]) + 1e-5f);
    float sh1  = b2f(w16[O_SB + c0 + 16]) - b2f(w16[O_SM + c0 + 16]) * inv1;
#pragma unroll
    for (int r = 0; r < 4; ++r) {
        sp16[(size_t)(r0 + r) * N + c0]           = f2b(acc00[r] * inv0 + sh0);
        sp16[(size_t)(r0 + r) * N + c0 + 16]      = f2b(acc01[r] * inv1 + sh1);
        sp16[(size_t)(r0 + 16 + r) * N + c0]      = f2b(acc10[r] * inv0 + sh0);
        sp16[(size_t)(r0 + 16 + r) * N + c0 + 16] = f2b(acc11[r] * inv1 + sh1);
    }
}

// ---------------------------------------------------------------------------
// k_ln: res-BN + bilinear + add -> LayerNorm -> xn. 8 rows per block.
// grid (512, B), block 256 (thread = channel).
// ---------------------------------------------------------------------------
__global__ __launch_bounds__(256) void k_ln(
    const u16* __restrict__ resnetT, const u16* __restrict__ w16,
    const u16* __restrict__ sp16, u16* __restrict__ xn)
{
    __shared__ float red[8];
    int c = threadIdx.x, b = blockIdx.y;
    float inv = b2f(w16[O_RG + c]) * rsqrtf(b2f(w16[O_RV + c]) + 1e-5f);
    float sh  = b2f(w16[O_RB + c]) - b2f(w16[O_RM + c]) * inv;
    float lgv = b2f(w16[O_LG + c]), lbv = b2f(w16[O_LB + c]);
    const u16* spc = sp16 + (size_t)b * 1024 * 256 + c;
    for (int j = 0; j < 8; ++j) {
        int l = blockIdx.x * 8 + j;
        int h = l >> 6, w = l & 63;
        float rr = b2f(resnetT[((size_t)b * 4096 + l) * 256 + c]);
        float rn = rr * inv + sh;
        float xh = 0.5f * h - 0.25f; int jh = (int)floorf(xh); float fh = xh - jh;
        float xw = 0.5f * w - 0.25f; int jw = (int)floorf(xw); float fw = xw - jw;
        int h0 = jh < 0 ? 0 : jh, h1 = jh + 1 > 31 ? 31 : jh + 1;
        int w0 = jw < 0 ? 0 : jw, w1 = jw + 1 > 31 ? 31 : jw + 1;
        float v00 = b2f(spc[(size_t)(h0 * 32 + w0) * 256]), v01 = b2f(spc[(size_t)(h0 * 32 + w1) * 256]);
        float v10 = b2f(spc[(size_t)(h1 * 32 + w0) * 256]), v11 = b2f(spc[(size_t)(h1 * 32 + w1) * 256]);
        float sp = (1.f - fh) * ((1.f - fw) * v00 + fw * v01)
                 + fh * ((1.f - fw) * v10 + fw * v11);
        float fv = rn + sp;

        float s = fv, s2 = fv * fv;
#pragma unroll
        for (int off = 1; off < 64; off <<= 1) {
            s  += __shfl_xor(s, off);
            s2 += __shfl_xor(s2, off);
        }
        int wv = c >> 6;
        if ((c & 63) == 0) { red[wv] = s; red[4 + wv] = s2; }
        __syncthreads();
        float S  = red[0] + red[1] + red[2] + red[3];
        float S2 = red[4] + red[5] + red[6] + red[7];
        __syncthreads();
        float mu   = S * (1.f / 256.f);
        float var  = S2 * (1.f / 256.f) - mu * mu;
        float rstd = rsqrtf(var + 1e-5f);
        xn[((size_t)b * 4096 + l) * 256 + c] = f2b((fv - mu) * rstd * lgv + lbv);
    }
}

// ---------------------------------------------------------------------------
// in_proj GEMM, both halves: xz[row][n], n in [0,1024). M=8192, K=256.
// Block tile 64m x 128n (4 waves 2x2), wave tile 32x64 (8 MFMA/k-iter).
// grid (128, 8), block 256.
// ---------------------------------------------------------------------------
__global__ __launch_bounds__(256) void k_gemm_in(
    const u16* __restrict__ A, const u16* __restrict__ w16, u16* __restrict__ Out)
{
    const int N = 1024, K = 256;
    int tid = threadIdx.x, lane = tid & 63, wid = tid >> 6;
    int ln = lane & 15, q = lane >> 4;
    int m0 = blockIdx.x * 64 + (wid & 1) * 32;
    int n0 = blockIdx.y * 128 + (wid >> 1) * 64;
    f32x4 acc[2][4];
#pragma unroll
    for (int i = 0; i < 2; ++i)
#pragma unroll
        for (int j = 0; j < 4; ++j) acc[i][j] = {0.f,0.f,0.f,0.f};
    const u16* Ap0 = A + (size_t)(m0 + ln) * K + q * 8;
    const u16* Ap1 = Ap0 + (size_t)16 * K;
    const u16* Bp  = w16 + O_INW + (size_t)(n0 + ln) * K + q * 8;
#pragma unroll 2
    for (int k0 = 0; k0 < K; k0 += 32) {
        short8 a0 = *reinterpret_cast<const short8*>(Ap0 + k0);
        short8 a1 = *reinterpret_cast<const short8*>(Ap1 + k0);
#pragma unroll
        for (int j = 0; j < 4; ++j) {
            short8 bj = *reinterpret_cast<const short8*>(Bp + (size_t)(16 * j) * K + k0);
            acc[0][j] = __builtin_amdgcn_mfma_f32_16x16x32_bf16(a0, bj, acc[0][j], 0, 0, 0);
            acc[1][j] = __builtin_amdgcn_mfma_f32_16x16x32_bf16(a1, bj, acc[1][j], 0, 0, 0);
        }
    }
    int r0 = m0 + q * 4, c0 = n0 + ln;
#pragma unroll
    for (int i = 0; i < 2; ++i)
#pragma unroll
        for (int j = 0; j < 4; ++j)
#pragma unroll
            for (int r = 0; r < 4; ++r)
                Out[(size_t)(r0 + 16 * i + r) * N + c0 + 16 * j] = f2b(acc[i][j][r]);
}

// ---------------------------------------------------------------------------
// on-the-fly u fragment: u[row][kk0..kk0+8) = silu(causal conv3 of xm half of xz)
// ---------------------------------------------------------------------------
DEVINL short8 u_frag(const u16* __restrict__ xz, const u16* __restrict__ w16,
                     int row, int kk0)
{
    int l = row & 4095;
    const u16* p = xz + (size_t)row * 1024 + kk0;
    short8 zz = {0,0,0,0,0,0,0,0};
    short8 x0 = *reinterpret_cast<const short8*>(p);
    short8 x1 = (l >= 1) ? *reinterpret_cast<const short8*>(p - 1024) : zz;
    short8 x2 = (l >= 2) ? *reinterpret_cast<const short8*>(p - 2048) : zz;
    short8 r;
#pragma unroll
    for (int j = 0; j < 8; ++j) {
        int d = kk0 + j;
        float acc = b2f(w16[O_CB + d])
                  + b2f((u16)x2[j]) * b2f(w16[O_CW + d * 3])
                  + b2f((u16)x1[j]) * b2f(w16[O_CW + d * 3 + 1])
                  + b2f((u16)x0[j]) * b2f(w16[O_CW + d * 3 + 2]);
        r[j] = (short)f2b(silu(acc));
    }
    return r;
}

// ---------------------------------------------------------------------------
// x_proj GEMM, conv-on-the-fly A: xdf[row][n] f32, N=48, K=512.
// grid (256), block 128: 2 waves x 16-row tiles.
// ---------------------------------------------------------------------------
__global__ __launch_bounds__(128) void k_xproj(
    const u16* __restrict__ xz, const u16* __restrict__ w16, float* __restrict__ xdf)
{
    int tid = threadIdx.x, lane = tid & 63, wid = tid >> 6;
    int ln = lane & 15, q = lane >> 4;
    int m0 = blockIdx.x * 32 + wid * 16;
    const u16* Wp = w16 + O_XPW;
    f32x4 acc[3];
#pragma unroll
    for (int j = 0; j < 3; ++j) acc[j] = {0.f,0.f,0.f,0.f};
    for (int k0 = 0; k0 < 512; k0 += 32) {
        int kk0 = k0 + q * 8;
        short8 a0 = u_frag(xz, w16, m0 + ln, kk0);
#pragma unroll
        for (int j = 0; j < 3; ++j) {
            short8 bj = *reinterpret_cast<const short8*>(Wp + (size_t)(16 * j + ln) * 512 + kk0);
            acc[j] = __builtin_amdgcn_mfma_f32_16x16x32_bf16(a0, bj, acc[j], 0, 0, 0);
        }
    }
#pragma unroll
    for (int j = 0; j < 3; ++j)
#pragma unroll
        for (int r = 0; r < 4; ++r)
            xdf[(size_t)(m0 + q * 4 + r) * 48 + 16 * j + ln] = acc[j][r];
}

// dt = softplus(dot(xd[0:16], wdt) + bias)
DEVINL float dt_of(const float* xd, const float* wdt, float bias) {
    float acc = bias;
#pragma unroll
    for (int r = 0; r < 16; ++r) acc += xd[r] * wdt[r];
    return acc > 15.f ? acc : __logf(1.f + __expf(acc));
}

// ---------------------------------------------------------------------------
// scan1: per-chunk local scan, conv-on-the-fly. grid (NC, B), block 512.
// ---------------------------------------------------------------------------
__global__ __launch_bounds__(512) void k_scan1(
    const u16* __restrict__ xz, const float* __restrict__ xdf,
    const u16* __restrict__ w16, u16* __restrict__ cA, u16* __restrict__ cH,
    int NC, int CL)
{
    __shared__ float xds[32][48];
    int d = threadIdx.x, ck = blockIdx.x, b = blockIdx.y;
    float wdt[16], a[16], h[16], ap[16];
#pragma unroll
    for (int s = 0; s < 16; ++s) {
        wdt[s] = b2f(w16[O_DTW + d * 16 + s]);
        a[s] = -__expf(b2f(w16[O_ALOG + d * 16 + s]));
        h[s] = 0.f; ap[s] = 1.f;
    }
    float bias = b2f(w16[O_DTB + d]);
    float cw0 = b2f(w16[O_CW + d * 3]), cw1 = b2f(w16[O_CW + d * 3 + 1]),
          cw2 = b2f(w16[O_CW + d * 3 + 2]), cbv = b2f(w16[O_CB + d]);
    int l0 = ck * CL;
    size_t xbase = ((size_t)b * 4096 + l0) * 1024 + d;
    float x2 = (l0 >= 2) ? b2f(xz[xbase - 2048]) : 0.f;
    float x1 = (l0 >= 1) ? b2f(xz[xbase - 1024]) : 0.f;
    for (int t0 = 0; t0 < CL; t0 += 32) {
        __syncthreads();
#pragma unroll
        for (int k = 0; k < 3; ++k) {
            int idx = k * 512 + d;
            int r = idx / 48, c = idx - r * 48;
            xds[r][c] = xdf[((size_t)b * 4096 + l0 + t0 + r) * 48 + c];
        }
        __syncthreads();
        for (int il = 0; il < 32; ++il) {
            float x0 = b2f(xz[xbase + (size_t)(t0 + il) * 1024]);
            float uv = silu(cbv + cw0 * x2 + cw1 * x1 + cw2 * x0);
            const float* xd = xds[il];
            float dtv = dt_of(xd, wdt, bias);
            float du = dtv * uv;
#pragma unroll
            for (int s = 0; s < 16; ++s) {
                float dA = __expf(dtv * a[s]);
                h[s]  = dA * h[s] + du * xd[16 + s];
                ap[s] *= dA;
            }
            x2 = x1; x1 = x0;
        }
    }
    size_t base = (((size_t)b * NC + ck) * 16) * 512 + d;
#pragma unroll
    for (int s = 0; s < 16; ++s) {
        cA[base + (size_t)s * 512] = f2b(ap[s]);
        cH[base + (size_t)s * 512] = f2b(h[s]);
    }
}

// ---------------------------------------------------------------------------
// scan2: cross-chunk recurrence; cH[ck] := h_in(ck). grid (16, 4, B), block 128.
// ---------------------------------------------------------------------------
__global__ __launch_bounds__(128) void k_scan2(const u16* __restrict__ cA,
                                               u16* __restrict__ cH, int NC)
{
    int d = blockIdx.y * 128 + threadIdx.x, s = blockIdx.x, b = blockIdx.z;
    float h = 0.f;
#pragma unroll 4
    for (int ck = 0; ck < NC; ++ck) {
        size_t idx = (((size_t)b * NC + ck) * 16 + s) * 512 + d;
        float aP = b2f(cA[idx]), hE = b2f(cH[idx]);
        cH[idx] = f2b(h);
        h = aP * h + hE;
    }
}

// ---------------------------------------------------------------------------
// scan3: replay from h_in, conv-on-the-fly; y = (h.C + u*D) * silu(z).
// grid (NC, B), block 512.
// ---------------------------------------------------------------------------
__global__ __launch_bounds__(512) void k_scan3(
    const u16* __restrict__ xz, const float* __restrict__ xdf,
    const u16* __restrict__ w16, const u16* __restrict__ cH,
    u16* __restrict__ y, int NC, int CL)
{
    __shared__ float xds[32][48];
    int d = threadIdx.x, ck = blockIdx.x, b = blockIdx.y;
    float wdt[16], a[16], h[16];
    size_t base = (((size_t)b * NC + ck) * 16) * 512 + d;
#pragma unroll
    for (int s = 0; s < 16; ++s) {
        wdt[s] = b2f(w16[O_DTW + d * 16 + s]);
        a[s] = -__expf(b2f(w16[O_ALOG + d * 16 + s]));
        h[s] = b2f(cH[base + (size_t)s * 512]);
    }
    float bias = b2f(w16[O_DTB + d]);
    float Dv = b2f(w16[O_DW + d]);
    float cw0 = b2f(w16[O_CW + d * 3]), cw1 = b2f(w16[O_CW + d * 3 + 1]),
          cw2 = b2f(w16[O_CW + d * 3 + 2]), cbv = b2f(w16[O_CB + d]);
    int l0 = ck * CL;
    size_t xbase = ((size_t)b * 4096 + l0) * 1024 + d;
    float x2 = (l0 >= 2) ? b2f(xz[xbase - 2048]) : 0.f;
    float x1 = (l0 >= 1) ? b2f(xz[xbase - 1024]) : 0.f;
    for (int t0 = 0; t0 < CL; t0 += 32) {
        __syncthreads();
#pragma unroll
        for (int k = 0; k < 3; ++k) {
            int idx = k * 512 + d;
            int r = idx / 48, c = idx - r * 48;
            xds[r][c] = xdf[((size_t)b * 4096 + l0 + t0 + r) * 48 + c];
        }
        __syncthreads();
        for (int il = 0; il < 32; ++il) {
            size_t row = (size_t)b * 4096 + l0 + t0 + il;
            float x0 = b2f(xz[xbase + (size_t)(t0 + il) * 1024]);
            float uv = silu(cbv + cw0 * x2 + cw1 * x1 + cw2 * x0);
            const float* xd = xds[il];
            float dtv = dt_of(xd, wdt, bias);
            float du = dtv * uv;
            float yv = 0.f;
#pragma unroll
            for (int s = 0; s < 16; ++s) {
                float dA = __expf(dtv * a[s]);
                h[s] = dA * h[s] + du * xd[16 + s];
                yv += h[s] * xd[32 + s];
            }
            yv += uv * Dv;
            float zv = b2f(xz[row * 1024 + 512 + d]);
            yv *= silu(zv);
            y[row * 512 + d] = f2b(yv);
            x2 = x1; x1 = x0;
        }
    }
}

// ---------------------------------------------------------------------------
// out_proj GEMM (m = channel, n = sequence) + fused-recompute epilogue.
// Block tile 64chan x 128seq (4 waves 2x2), wave 32x64. grid (4, 64), block 256.
// ---------------------------------------------------------------------------
template<bool F32> DEVINL void out_body(
    const u16* Y, const u16* w16, const void* resnet,
    const u16* sp16, void* outp)
{
    const int K = 512;
    int tid = threadIdx.x, lane = tid & 63, wid = tid >> 6;
    int ln = lane & 15, q = lane >> 4;
    int m0 = blockIdx.x * 64 + (wid & 1) * 32;    // channel dim (256)
    int n0 = blockIdx.y * 128 + (wid >> 1) * 64;  // sequence dim (8192)
    f32x4 acc[2][4];
#pragma unroll
    for (int i = 0; i < 2; ++i)
#pragma unroll
        for (int j = 0; j < 4; ++j) acc[i][j] = {0.f,0.f,0.f,0.f};
    const u16* Ap0 = w16 + O_OPW + (size_t)(m0 + ln) * K + q * 8;
    const u16* Ap1 = Ap0 + (size_t)16 * K;
    const u16* Bp  = Y + (size_t)(n0 + ln) * K + q * 8;
#pragma unroll 2
    for (int k0 = 0; k0 < K; k0 += 32) {
        short8 a0 = *reinterpret_cast<const short8*>(Ap0 + k0);
        short8 a1 = *reinterpret_cast<const short8*>(Ap1 + k0);
#pragma unroll
        for (int j = 0; j < 4; ++j) {
            short8 bj = *reinterpret_cast<const short8*>(Bp + (size_t)(16 * j) * K + k0);
            acc[0][j] = __builtin_amdgcn_mfma_f32_16x16x32_bf16(a0, bj, acc[0][j], 0, 0, 0);
            acc[1][j] = __builtin_amdgcn_mfma_f32_16x16x32_bf16(a1, bj, acc[1][j], 0, 0, 0);
        }
    }
    int r0 = m0 + q * 4;
    int nb = n0 + ln;
    float inv8[2][4], sh8[2][4];
#pragma unroll
    for (int im = 0; im < 2; ++im)
#pragma unroll
        for (int r = 0; r < 4; ++r) {
            int c = r0 + 16 * im + r;
            float inv = b2f(w16[O_RG + c]) * rsqrtf(b2f(w16[O_RV + c]) + 1e-5f);
            inv8[im][r] = inv;
            sh8[im][r]  = b2f(w16[O_RB + c]) - b2f(w16[O_RM + c]) * inv;
        }
#pragma unroll
    for (int jn = 0; jn < 4; ++jn) {
        int n = nb + 16 * jn;
        int b = n >> 12, l = n & 4095;
        int hh = l >> 6, w = l & 63;
        float xh = 0.5f * hh - 0.25f; int jh = (int)floorf(xh); float fh = xh - jh;
        float xw = 0.5f * w - 0.25f;  int jw = (int)floorf(xw); float fw = xw - jw;
        int h0 = jh < 0 ? 0 : jh, h1 = jh + 1 > 31 ? 31 : jh + 1;
        int w0 = jw < 0 ? 0 : jw, w1 = jw + 1 > 31 ? 31 : jw + 1;
        float w00 = (1.f - fh) * (1.f - fw), w01 = (1.f - fh) * fw;
        float w10 = fh * (1.f - fw),         w11 = fh * fw;
        const u16* spb = sp16 + (size_t)b * 1024 * 256;
#pragma unroll
        for (int im = 0; im < 2; ++im) {
            int cb = r0 + 16 * im;
            u16x4 s00 = *reinterpret_cast<const u16x4*>(spb + (size_t)(h0 * 32 + w0) * 256 + cb);
            u16x4 s01 = *reinterpret_cast<const u16x4*>(spb + (size_t)(h0 * 32 + w1) * 256 + cb);
            u16x4 s10 = *reinterpret_cast<const u16x4*>(spb + (size_t)(h1 * 32 + w0) * 256 + cb);
            u16x4 s11 = *reinterpret_cast<const u16x4*>(spb + (size_t)(h1 * 32 + w1) * 256 + cb);
#pragma unroll
            for (int r = 0; r < 4; ++r) {
                int c = cb + r;
                float rr = LDs<F32>(resnet, ((size_t)b * 256 + c) * 4096 + l);
                float sp = w00 * b2f(s00[r]) + w01 * b2f(s01[r])
                         + w10 * b2f(s10[r]) + w11 * b2f(s11[r]);
                float val = acc[im][jn][r] + rr * inv8[im][r] + sh8[im][r] + sp;
                size_t oi = ((size_t)b * 256 + c) * 4096 + l;
                if constexpr (F32) ((float*)outp)[oi] = val;
                else               ((u16*)outp)[oi]  = f2b(val);
            }
        }
    }
}
__global__ __launch_bounds__(256) void k_out(
    const u16* Y, const u16* w16, const void* resnet,
    const u16* sp16, void* outp)
{
    if (detect_f32((const u16*)resnet)) out_body<true>(Y, w16, resnet, sp16, outp);
    else                                out_body<false>(Y, w16, resnet, sp16, outp);
}

// ---------------------------------------------------------------------------
extern "C" void kernel_launch(void* const* d_in, const int* in_sizes, int n_in,
                              void* d_out, int out_size, void* d_ws, size_t ws_size,
                              hipStream_t stream)
{
    const void* resnet = d_in[0];
    const void* scp    = d_in[1];
    const void* spw    = d_in[2];
    const void* sg     = d_in[3];
    const void* sb     = d_in[4];
    const void* sm     = d_in[5];
    const void* sv     = d_in[6];
    const void* rg     = d_in[7];
    const void* rb     = d_in[8];
    const void* rm     = d_in[9];
    const void* rv     = d_in[10];
    const void* lg     = d_in[11];
    const void* lb     = d_in[12];
    const void* inw    = d_in[13];
    const void* cw     = d_in[14];
    const void* cb     = d_in[15];
    const void* xpw    = d_in[16];
    const void* dtw    = d_in[17];
    const void* dtb    = d_in[18];
    const void* alog   = d_in[19];
    const void* Dw     = d_in[20];
    const void* opw    = d_in[21];

    // Workspace layout (~52 MB of the 256 MiB ws)
    char*  ws      = (char*)d_ws;
    u16*   w16     = (u16*)(ws + 4096);         // 1.09 MB arena
    u16*   sp16    = (u16*)(ws + 2097152);      // 1 MB
    u16*   scpT    = (u16*)(ws + 4194304);      // 2 MB
    u16*   resnetT = (u16*)(ws + 8388608);      // 4 MB
    u16*   xn      = (u16*)(ws + 12582912);     // 4 MB
    u16*   xz      = (u16*)(ws + 16777216);     // 16 MB [b][l][1024] (xm | z)
    float* xdf     = (float*)(ws + 33554432);   // 1.5 MB f32 [b][l][48]
    u16*   y       = (u16*)(ws + 35651584);     // 8 MB
    const size_t tail0 = 44040192;

    int NC = 16;
    for (int cand = 128; cand >= 16; cand >>= 1) {
        if (tail0 + (size_t)cand * 65536 <= ws_size) { NC = cand; break; }
    }
    int CL = 4096 / NC;
    u16* cA = (u16*)(ws + tail0);
    u16* cH = (u16*)(ws + tail0 + (size_t)NC * 32768);

    k_prep<<<dim3(2998), 256, 0, stream>>>(
        inw, xpw, opw, spw, cw, cb, dtw, alog, dtb, Dw,
        sg, sb, sm, sv, rg, rb, rm, rv, lg, lb,
        scp, resnet, w16, scpT, resnetT);
    k_scpmm<<<dim3(32, 4), 256, 0, stream>>>(scpT, w16, sp16);
    k_ln<<<dim3(512, 2), 256, 0, stream>>>(resnetT, w16, sp16, xn);
    k_gemm_in<<<dim3(128, 8), 256, 0, stream>>>(xn, w16, xz);
    k_xproj<<<dim3(256), 128, 0, stream>>>(xz, w16, xdf);
    k_scan1<<<dim3(NC, 2), 512, 0, stream>>>(xz, xdf, w16, cA, cH, NC, CL);
    k_scan2<<<dim3(16, 4, 2), 128, 0, stream>>>(cA, cH, NC);
    k_scan3<<<dim3(NC, 2), 512, 0, stream>>>(xz, xdf, w16, cH, y, NC, CL);
    k_out<<<dim3(4, 64), 256, 0, stream>>>(y, w16, resnet, sp16, d_out);
}